// Round 1
// baseline (10208.451 us; speedup 1.0000x reference)
//
#include <hip/hip_runtime.h>
#include <math.h>

#define BB 256   // batch
#define CC 64    // channels / graph nodes
#define LL 512   // series length
#define HH 128   // gcn hidden
#define G3 384   // 3*gru_dim
#define NC 8
#define AT 64
#define L1 519
#define L2 527
#define L3 535
#define THRESH 0.02f

__device__ inline float warp_red_sum(float v) {
  #pragma unroll
  for (int o = 32; o > 0; o >>= 1) v += __shfl_down(v, o, 64);
  return v;
}
__device__ inline float warp_allred_max(float v) {
  #pragma unroll
  for (int o = 32; o > 0; o >>= 1) v = fmaxf(v, __shfl_xor(v, o, 64));
  return v;
}
__device__ inline float warp_allred_sum(float v) {
  #pragma unroll
  for (int o = 32; o > 0; o >>= 1) v += __shfl_xor(v, o, 64);
  return v;
}

// wa = gat_W @ a  (512-vector); avoids the full x@gat_W GEMM since (x@W)@a = x@(W@a)
__global__ void k_wa(const float* __restrict__ gatW, const float* __restrict__ a1,
                     const float* __restrict__ a2, float* wa1, float* wa2) {
  int l = threadIdx.x;
  const float* row = gatW + l * LL;
  float s1 = 0.f, s2 = 0.f;
  for (int k = 0; k < LL; k++) { float w = row[k]; s1 += w * a1[k]; s2 += w * a2[k]; }
  wa1[l] = s1; wa2[l] = s2;
}

// ha1[b,c] = x[b,c,:].wa1 ; ha2 likewise. one wave per row.
__global__ void k_ha(const float* __restrict__ x, const float* __restrict__ wa1,
                     const float* __restrict__ wa2, float* ha1, float* ha2) {
  int wid = threadIdx.x >> 6, lane = threadIdx.x & 63;
  int row = blockIdx.x * 4 + wid;
  const float* xr = x + (size_t)row * LL;
  float s1 = 0.f, s2 = 0.f;
  for (int q = lane; q < LL; q += 64) { float v = xr[q]; s1 += v * wa1[q]; s2 += v * wa2[q]; }
  s1 = warp_red_sum(s1); s2 = warp_red_sum(s2);
  if (lane == 0) { ha1[row] = s1; ha2[row] = s2; }
}

// per (b,i): e_j = lrelu(ha1_i + ha2_j, 0.2); softmax over j; mask = A > 0.02
__global__ void k_softmask(const float* __restrict__ ha1, const float* __restrict__ ha2,
                           float* __restrict__ mask) {
  int wid = threadIdx.x >> 6, lane = threadIdx.x & 63;
  int row = blockIdx.x * 4 + wid;       // row = b*64+i
  int b = row >> 6;
  float e = ha1[row] + ha2[b * 64 + lane];
  e = e < 0.f ? 0.2f * e : e;
  float mx = warp_allred_max(e);
  float ex = expf(e - mx);
  float sm = warp_allred_sum(ex);
  float A = ex / sm;
  mask[(size_t)row * 64 + lane] = (A > THRESH) ? 1.0f : 0.0f;
}

// dinv[b,i] = 1/sqrt(1 + sum_j mask[b,i,j])   (A = m + I degree)
__global__ void k_dinv(const float* __restrict__ mask, float* dinv, int N) {
  int wid = threadIdx.x >> 6, lane = threadIdx.x & 63;
  int row = blockIdx.x * 4 + wid;       // b*N+i
  if (row >= BB * N) return;
  float v = (lane < N) ? mask[(size_t)row * N + lane] : 0.f;
  float s = warp_allred_sum(v);
  if (lane == 0) dinv[row] = 1.0f / sqrtf(s + 1.0f);
}

// xw[b,i,f] = sum_k gin[b,i,k] * W[k,f]   (HH=128 output)
__global__ void k_xw(const float* __restrict__ gin, const float* __restrict__ W,
                     float* __restrict__ out, int N, int K) {
  __shared__ float xs[512];
  int b = blockIdx.x / N, i = blockIdx.x % N;
  const float* grow = gin + (size_t)(b * N + i) * K;
  for (int k = threadIdx.x; k < K; k += 128) xs[k] = grow[k];
  __syncthreads();
  int f = threadIdx.x;
  float a0 = 0.f, a1 = 0.f, a2 = 0.f, a3 = 0.f;
  for (int k = 0; k < K; k += 4) {
    a0 += xs[k]     * W[(k)     * HH + f];
    a1 += xs[k + 1] * W[(k + 1) * HH + f];
    a2 += xs[k + 2] * W[(k + 2) * HH + f];
    a3 += xs[k + 3] * W[(k + 3) * HH + f];
  }
  out[(size_t)(b * N + i) * HH + f] = (a0 + a1) + (a2 + a3);
}

// g[b,i,f] = relu(dinv_i*(dinv_i*xw_if + sum_j m_ij*dinv_j*xw_jf) + bias_f)
__global__ void k_gcnagg(const float* __restrict__ xw, const float* __restrict__ mask,
                         const float* __restrict__ dinv, const float* __restrict__ bias,
                         float* __restrict__ gout, int N) {
  __shared__ float mrow[64], dv[64];
  int b = blockIdx.x / N, i = blockIdx.x % N;
  if (threadIdx.x < N) {
    mrow[threadIdx.x] = mask[(size_t)(b * N + i) * N + threadIdx.x];
    dv[threadIdx.x] = dinv[b * N + threadIdx.x];
  }
  __syncthreads();
  int f = threadIdx.x;
  float di = dv[i];
  float acc = di * xw[(size_t)(b * N + i) * HH + f];
  for (int j = 0; j < N; j++) acc += mrow[j] * dv[j] * xw[(size_t)(b * N + j) * HH + f];
  float y = di * acc + bias[f];
  gout[(size_t)(b * N + i) * HH + f] = y > 0.f ? y : 0.f;
}

// fused SAGPool: score -> top-k (jax tie-break: lowest index first) -> gather + gate -> readout accum
__global__ void k_pool(const float* __restrict__ g, const float* __restrict__ mask,
                       const float* __restrict__ w1, const float* __restrict__ w2,
                       const float* __restrict__ pb, int N, int kk,
                       float* gp, float* mnext, float* __restrict__ r) {
  __shared__ float d1[64], d2[64], sv[64], vals[32], tvs[32];
  __shared__ int idxs[32], flg[64];
  int b = blockIdx.x, tid = threadIdx.x;
  if (tid < N) {
    const float* gr = g + (size_t)(b * N + tid) * HH;
    float a = 0.f, c = 0.f;
    for (int d = 0; d < HH; d++) { float v = gr[d]; a += v * w1[d]; c += v * w2[d]; }
    d1[tid] = a; d2[tid] = c; flg[tid] = 0;
  }
  __syncthreads();
  if (tid < N) {
    const float* mr = mask + (size_t)(b * N + tid) * N;
    float s = d1[tid] + pb[0];
    for (int j = 0; j < N; j++) s += mr[j] * d2[j];
    sv[tid] = s;
  }
  __syncthreads();
  if (tid == 0) {
    for (int t = 0; t < kk; t++) {
      float best = -3.4e38f; int bi = 0;
      for (int j = 0; j < N; j++)
        if (!flg[j] && sv[j] > best) { best = sv[j]; bi = j; }
      flg[bi] = 1; idxs[t] = bi; vals[t] = best;
    }
  }
  __syncthreads();
  if (tid < kk) tvs[tid] = tanhf(vals[tid]);
  __syncthreads();
  if (tid < HH) {
    float mx = -3.4e38f, sm = 0.f;
    for (int t = 0; t < kk; t++) {
      float v = g[(size_t)(b * N + idxs[t]) * HH + tid] * tvs[t];
      if (gp) gp[(size_t)(b * kk + t) * HH + tid] = v;
      mx = fmaxf(mx, v); sm += v;
    }
    r[b * 256 + tid] += mx;
    r[b * 256 + 128 + tid] += sm / (float)kk;
  }
  if (mnext) {
    for (int q = tid; q < kk * kk; q += blockDim.x) {
      int t = q / kk, u = q % kk;
      mnext[(size_t)(b * kk + t) * kk + u] = mask[(size_t)(b * N + idxs[t]) * N + idxs[u]];
    }
  }
}

__global__ void k_tr(const float* __restrict__ in, float* __restrict__ out, int R, int Lc) {
  int idx = blockIdx.x * 256 + threadIdx.x;
  if (idx >= R * Lc) return;
  int j = idx / Lc, l = idx % Lc;
  out[l * R + j] = in[idx];
}

// gi[b,c,j] = bih[j] + sum_l x[b,c,l]*Wih[j,l]
__global__ void k_gi(const float* __restrict__ x, const float* __restrict__ wihT,
                     const float* __restrict__ bih, float* __restrict__ gi) {
  __shared__ float xs[512];
  int blk = blockIdx.x;  // b*64+c
  for (int k = threadIdx.x; k < LL; k += 384) xs[k] = x[(size_t)blk * LL + k];
  __syncthreads();
  int j = threadIdx.x;
  float acc = bih[j];
  #pragma unroll 4
  for (int l = 0; l < LL; l++) acc += xs[l] * wihT[l * G3 + j];
  gi[(size_t)blk * G3 + j] = acc;
}

// GRU recurrence: one workgroup per channel c (64 independent sequences over 256 steps)
__global__ void k_gru(const float* __restrict__ gi, const float* __restrict__ whhT,
                      const float* __restrict__ bhh, float* __restrict__ ys) {
  __shared__ float h[128], agh[384], agi[384];
  int c = blockIdx.x, j = threadIdx.x;
  if (j < 128) h[j] = 0.f;
  __syncthreads();
  for (int b = 0; b < BB; b++) {
    float g0 = bhh[j], g1 = 0.f;
    for (int k = 0; k < 128; k += 2) {
      g0 += whhT[k * G3 + j] * h[k];
      g1 += whhT[(k + 1) * G3 + j] * h[k + 1];
    }
    agh[j] = g0 + g1;
    agi[j] = gi[(size_t)(b * CC + c) * G3 + j];
    __syncthreads();
    if (j < 128) {
      float rg = 1.f / (1.f + expf(-(agi[j] + agh[j])));
      float zg = 1.f / (1.f + expf(-(agi[128 + j] + agh[128 + j])));
      float ng = tanhf(agi[256 + j] + rg * agh[256 + j]);
      float hn = (1.f - zg) * ng + zg * h[j];
      ys[(size_t)(b * CC + c) * 128 + j] = hn;
      h[j] = hn;
    }
    __syncthreads();
  }
}

__global__ void k_grumean(const float* __restrict__ ys, float* __restrict__ xgru) {
  int b = blockIdx.x, u = threadIdx.x;
  float acc = 0.f;
  for (int c = 0; c < CC; c++) acc += ys[(size_t)(b * CC + c) * 128 + u];
  xgru[b * 128 + u] = acc / 64.f;
}

// conv1: K=8 dil=1 pad=7, in [64ch,512] -> out [128ch,519], relu
__global__ void k_conv1(const float* __restrict__ x, const float* __restrict__ W,
                        const float* __restrict__ bias, float* __restrict__ out, int b0) {
  __shared__ float wrow[512];
  int pt = blockIdx.x % 3, rest = blockIdx.x / 3;
  int o = rest % 128, bb = rest / 128;
  for (int q = threadIdx.x; q < 512; q += 256) wrow[q] = W[o * 512 + q];
  __syncthreads();
  int p = pt * 256 + threadIdx.x;
  if (p >= L1) return;
  float acc = bias[o];
  const float* xb = x + (size_t)(b0 + bb) * CC * LL;
  for (int ci = 0; ci < CC; ci++) {
    const float* xr = xb + ci * LL;
    const float* wr = wrow + ci * 8;
    #pragma unroll
    for (int t = 0; t < 8; t++) {
      int idx = p + t - 7;
      if (idx >= 0 && idx < LL) acc += xr[idx] * wr[t];
    }
  }
  out[(size_t)(bb * 128 + o) * L1 + p] = acc > 0.f ? acc : 0.f;
}

// conv2: K=5 dil=2 pad=8, [128,519] -> [128,527], relu
__global__ void k_conv2(const float* __restrict__ c1, const float* __restrict__ W,
                        const float* __restrict__ bias, float* __restrict__ out) {
  __shared__ float wrow[640];
  int pt = blockIdx.x % 3, rest = blockIdx.x / 3;
  int o = rest % 128, bb = rest / 128;
  for (int q = threadIdx.x; q < 640; q += 256) wrow[q] = W[o * 640 + q];
  __syncthreads();
  int p = pt * 256 + threadIdx.x;
  if (p >= L2) return;
  float acc = bias[o];
  for (int ci = 0; ci < 128; ci++) {
    const float* rr = c1 + (size_t)(bb * 128 + ci) * L1;
    const float* wr = wrow + ci * 5;
    #pragma unroll
    for (int t = 0; t < 5; t++) {
      int idx = p + 2 * t - 8;
      if (idx >= 0 && idx < L1) acc += rr[idx] * wr[t];
    }
  }
  out[(size_t)(bb * 128 + o) * L2 + p] = acc > 0.f ? acc : 0.f;
}

// conv3 (K=3 dil=4 pad=8) + relu + mean over 535 positions
__global__ void k_conv3m(const float* __restrict__ c2, const float* __restrict__ W,
                         const float* __restrict__ bias, float* __restrict__ xconv, int b0) {
  __shared__ float wrow[384], red[256];
  int o = blockIdx.x % 128, bb = blockIdx.x / 128;
  for (int q = threadIdx.x; q < 384; q += 256) wrow[q] = W[o * 384 + q];
  __syncthreads();
  float local = 0.f;
  for (int p = threadIdx.x; p < L3; p += 256) {
    float acc = bias[o];
    for (int ci = 0; ci < 128; ci++) {
      const float* rr = c2 + (size_t)(bb * 128 + ci) * L2;
      const float* wr = wrow + ci * 3;
      #pragma unroll
      for (int t = 0; t < 3; t++) {
        int idx = p + 4 * t - 8;
        if (idx >= 0 && idx < L2) acc += rr[idx] * wr[t];
      }
    }
    local += acc > 0.f ? acc : 0.f;
  }
  red[threadIdx.x] = local; __syncthreads();
  for (int s = 128; s > 0; s >>= 1) { if (threadIdx.x < s) red[threadIdx.x] += red[threadIdx.x + s]; __syncthreads(); }
  if (threadIdx.x == 0) xconv[(size_t)(b0 + bb) * 128 + o] = red[0] / (float)L3;
}

__global__ void k_fc0(const float* __restrict__ xconv, const float* __restrict__ xgru,
                      const float* __restrict__ r, const float* __restrict__ W,
                      const float* __restrict__ bias, float* __restrict__ hm) {
  __shared__ float feat[512];
  int b = blockIdx.x, t = threadIdx.x;
  if (t < 128) { feat[t] = xconv[b * 128 + t]; feat[128 + t] = xgru[b * 128 + t]; }
  feat[256 + t] = r[b * 256 + t];
  __syncthreads();
  float acc = bias[t];
  for (int k = 0; k < 512; k++) acc += feat[k] * W[k * 256 + t];
  hm[b * 256 + t] = acc;
}

// batchnorm over batch axis (train stats, two-pass) + leaky_relu(0.01)
__global__ void k_bn(const float* __restrict__ hm, const float* __restrict__ gamma,
                     const float* __restrict__ beta, float* __restrict__ out) {
  __shared__ float red[256];
  int n = blockIdx.x, t = threadIdx.x;
  float v = hm[t * 256 + n];
  red[t] = v; __syncthreads();
  for (int s = 128; s > 0; s >>= 1) { if (t < s) red[t] += red[t + s]; __syncthreads(); }
  float mean = red[0] / 256.f; __syncthreads();
  float dv = v - mean;
  red[t] = dv * dv; __syncthreads();
  for (int s = 128; s > 0; s >>= 1) { if (t < s) red[t] += red[t + s]; __syncthreads(); }
  float var = red[0] / 256.f;
  float y = gamma[n] * dv * (1.f / sqrtf(var + 1e-5f)) + beta[n];
  out[t * 256 + n] = y < 0.f ? 0.01f * y : y;
}

__global__ void k_fc1(const float* __restrict__ hmn, const float* __restrict__ W,
                      const float* __restrict__ bias, float* __restrict__ z) {
  __shared__ float hs[256];
  int b = blockIdx.x, t = threadIdx.x;
  hs[t] = hmn[b * 256 + t]; hs[128 + t] = hmn[b * 256 + 128 + t];
  __syncthreads();
  float acc = bias[t];
  for (int k = 0; k < 256; k++) acc += hs[k] * W[k * 128 + t];
  z[b * 128 + t] = acc;
}

// per-class attention logits + masked softmax over samples + prototype
__global__ void k_att(const float* __restrict__ z, const int* __restrict__ labels,
                      const int* __restrict__ idx_train, int ntrain,
                      const float* __restrict__ W1, const float* __restrict__ b1,
                      const float* __restrict__ W2, const float* __restrict__ b2,
                      float* __restrict__ protos) {
  __shared__ float wv[256], red[256];
  __shared__ int trainm[256];
  int c = blockIdx.x, n = threadIdx.x;
  trainm[n] = 0; __syncthreads();
  if (n < ntrain) trainm[idx_train[n]] = 1;
  __syncthreads();
  const float* zr = z + n * 128;
  float acc = b2[c];
  for (int a = 0; a < AT; a++) {
    float s = b1[c * AT + a];
    const float* w1c = W1 + (size_t)c * 128 * AT + a;
    for (int d = 0; d < 128; d++) s += zr[d] * w1c[d * AT];
    acc += tanhf(s) * W2[c * AT + a];
  }
  bool keep = trainm[n] && (labels[n] == c);
  float ml = keep ? acc : -1e30f;
  red[n] = ml; __syncthreads();
  for (int s = 128; s > 0; s >>= 1) { if (n < s) red[n] = fmaxf(red[n], red[n + s]); __syncthreads(); }
  float mx = red[0]; __syncthreads();
  float e = expf(ml - mx);
  wv[n] = e; red[n] = e; __syncthreads();
  for (int s = 128; s > 0; s >>= 1) { if (n < s) red[n] += red[n + s]; __syncthreads(); }
  float ssum = red[0]; __syncthreads();
  wv[n] = wv[n] / ssum;
  __syncthreads();
  if (n < 128) {
    float p = 0.f;
    for (int q = 0; q < 256; q++) p += wv[q] * z[q * 128 + n];
    protos[c * 128 + n] = p;
  }
}

__global__ void k_dist(const float* __restrict__ z, const float* __restrict__ protos,
                       float* __restrict__ dout) {
  __shared__ float zs[128], red[128];
  int n = blockIdx.x, t = threadIdx.x;
  zs[t] = z[n * 128 + t];
  red[t] = zs[t] * zs[t]; __syncthreads();
  for (int s = 64; s > 0; s >>= 1) { if (t < s) red[t] += red[t + s]; __syncthreads(); }
  float z2 = red[0];
  if (t < NC) {
    float dot = 0.f, p2 = 0.f;
    const float* pr = protos + t * 128;
    for (int d = 0; d < 128; d++) { float pv = pr[d]; dot += pv * zs[d]; p2 += pv * pv; }
    float d2 = fmaxf(z2 + p2 - 2.f * dot, 1e-12f);
    dout[n * NC + t] = expf(-0.5f * sqrtf(d2));
  }
}

__global__ void k_pdist(const float* __restrict__ protos, float* __restrict__ dout) {
  __shared__ float red[64];
  int t = threadIdx.x, i = t / 8, j = t % 8;
  float dot = 0.f, p2i = 0.f, p2j = 0.f;
  for (int d = 0; d < 128; d++) {
    float a = protos[i * 128 + d], b = protos[j * 128 + d];
    dot += a * b; p2i += a * a; p2j += b * b;
  }
  float d2 = fmaxf(p2i + p2j - 2.f * dot, 1e-12f);
  red[t] = expf(-0.5f * sqrtf(d2));
  __syncthreads();
  for (int s = 32; s > 0; s >>= 1) { if (t < s) red[t] += red[t + s]; __syncthreads(); }
  if (t == 0) dout[2048] = red[0] / 28.f;
}

extern "C" void kernel_launch(void* const* d_in, const int* in_sizes, int n_in,
                              void* d_out, int out_size, void* d_ws, size_t ws_size,
                              hipStream_t stream) {
  const float* x = (const float*)d_in[0];
  const int* labels = (const int*)d_in[1];
  const int* idx_train = (const int*)d_in[2];
  const float* gat_W = (const float*)d_in[3];
  const float* gat_a1 = (const float*)d_in[4];
  const float* gat_a2 = (const float*)d_in[5];
  const float* gcnW[3] = {(const float*)d_in[6], (const float*)d_in[8], (const float*)d_in[10]};
  const float* gcnB[3] = {(const float*)d_in[7], (const float*)d_in[9], (const float*)d_in[11]};
  const float* pw1[3] = {(const float*)d_in[12], (const float*)d_in[15], (const float*)d_in[18]};
  const float* pw2[3] = {(const float*)d_in[13], (const float*)d_in[16], (const float*)d_in[19]};
  const float* pbb[3] = {(const float*)d_in[14], (const float*)d_in[17], (const float*)d_in[20]};
  const float* wih = (const float*)d_in[21];
  const float* whh = (const float*)d_in[22];
  const float* bih = (const float*)d_in[23];
  const float* bhh = (const float*)d_in[24];
  const float* c1W = (const float*)d_in[25]; const float* c1b = (const float*)d_in[26];
  const float* c2W = (const float*)d_in[27]; const float* c2b = (const float*)d_in[28];
  const float* c3W = (const float*)d_in[29]; const float* c3b = (const float*)d_in[30];
  const float* fc0W = (const float*)d_in[31]; const float* fc0b = (const float*)d_in[32];
  const float* bn0g = (const float*)d_in[33]; const float* bn0b = (const float*)d_in[34];
  const float* fc1W = (const float*)d_in[35]; const float* fc1b = (const float*)d_in[36];
  const float* aW1 = (const float*)d_in[37]; const float* ab1 = (const float*)d_in[38];
  const float* aW2 = (const float*)d_in[39]; const float* ab2 = (const float*)d_in[40];
  float* out = (float*)d_out;
  float* ws = (float*)d_ws;

  // ---- workspace layout (floats). Z region is reused by 3 sequential phases. ----
  size_t off = 0;
  auto take = [&](size_t n) { size_t o = off; off += (n + 63) & ~(size_t)63; return o; };
  float* wa1   = ws + take(512);
  float* wa2   = ws + take(512);
  float* ha1   = ws + take(BB * CC);
  float* ha2   = ws + take(BB * CC);
  float* dinv  = ws + take(BB * 64);
  float* rbuf  = ws + take(BB * 256);
  float* xgru  = ws + take(BB * 128);
  float* xconv = ws + take(BB * 128);
  float* hm    = ws + take(BB * 256);
  float* hmn   = ws + take(BB * 256);
  float* zb    = ws + take(BB * 128);
  float* protos = ws + take(NC * 128);
  float* wihT  = ws + take(512 * 384);
  float* whhT  = ws + take(128 * 384);
  float* Z     = ws + take(8568832);
  // GNN-phase aliases
  float* mA  = Z;
  float* mB  = Z + 1048576;
  float* xw  = Z + 2097152;
  float* gb  = Z + 4194304;
  float* gp1 = Z + 6291456;
  float* gp2 = Z + 7340032;
  // GRU-phase aliases (after GNN done)
  float* gi = Z;
  float* ys = Z + 6291456;
  // conv-phase aliases (after GRU done), chunked 64 samples at a time
  float* cv1 = Z;
  float* cv2 = Z + 4251648;

  hipMemsetAsync(rbuf, 0, BB * 256 * sizeof(float), stream);

  // ---- GAT adjacency ----
  k_wa<<<1, 512, 0, stream>>>(gat_W, gat_a1, gat_a2, wa1, wa2);
  k_ha<<<BB * CC / 4, 256, 0, stream>>>(x, wa1, wa2, ha1, ha2);
  k_softmask<<<BB * 64 / 4, 256, 0, stream>>>(ha1, ha2, mA);

  // ---- 3x (GCN + SAGPool) with jump-knowledge readout ----
  const int Ns[3] = {64, 32, 16};
  const int ks[3] = {32, 16, 8};
  const int Kin[3] = {512, 128, 128};
  const float* gins[3] = {x, gp1, gp2};
  float* mcur[3] = {mA, mB, mA};
  float* mnxt[3] = {mB, mA, nullptr};
  float* gps[3]  = {gp1, gp2, nullptr};
  for (int s = 0; s < 3; s++) {
    int N = Ns[s];
    k_dinv<<<(BB * N + 3) / 4, 256, 0, stream>>>(mcur[s], dinv, N);
    k_xw<<<BB * N, 128, 0, stream>>>(gins[s], gcnW[s], xw, N, Kin[s]);
    k_gcnagg<<<BB * N, 128, 0, stream>>>(xw, mcur[s], dinv, gcnB[s], gb, N);
    k_pool<<<BB, 256, 0, stream>>>(gb, mcur[s], pw1[s], pw2[s], pbb[s], N, ks[s],
                                   gps[s], mnxt[s], rbuf);
  }

  // ---- GRU branch (seq axis = batch, 64 independent channel rows) ----
  k_tr<<<(384 * 512 + 255) / 256, 256, 0, stream>>>(wih, wihT, 384, 512);
  k_tr<<<(384 * 128 + 255) / 256, 256, 0, stream>>>(whh, whhT, 384, 128);
  k_gi<<<BB * CC, 384, 0, stream>>>(x, wihT, bih, gi);
  k_gru<<<CC, 384, 0, stream>>>(gi, whhT, bhh, ys);
  k_grumean<<<BB, 128, 0, stream>>>(ys, xgru);

  // ---- dilated conv branch, 4 chunks of 64 samples ----
  for (int bc = 0; bc < 4; bc++) {
    int b0 = bc * 64;
    k_conv1<<<64 * 128 * 3, 256, 0, stream>>>(x, c1W, c1b, cv1, b0);
    k_conv2<<<64 * 128 * 3, 256, 0, stream>>>(cv1, c2W, c2b, cv2);
    k_conv3m<<<64 * 128, 256, 0, stream>>>(cv2, c3W, c3b, xconv, b0);
  }

  // ---- mapping MLP + BN + attention prototypes + distances ----
  k_fc0<<<BB, 256, 0, stream>>>(xconv, xgru, rbuf, fc0W, fc0b, hm);
  k_bn<<<256, 256, 0, stream>>>(hm, bn0g, bn0b, hmn);
  k_fc1<<<BB, 128, 0, stream>>>(hmn, fc1W, fc1b, zb);
  k_att<<<NC, 256, 0, stream>>>(zb, labels, idx_train, in_sizes[2], aW1, ab1, aW2, ab2, protos);
  k_dist<<<BB, 128, 0, stream>>>(zb, protos, out);
  k_pdist<<<1, 64, 0, stream>>>(protos, out);
}

// Round 2
// 3311.380 us; speedup vs baseline: 3.0828x; 3.0828x over previous
//
#include <hip/hip_runtime.h>
#include <math.h>

#define BB 256   // batch
#define CC 64    // channels / graph nodes
#define LL 512   // series length
#define HH 128   // gcn hidden
#define G3 384   // 3*gru_dim
#define NC 8
#define AT 64
#define CL1 519
#define CL2 527
#define CL3 535
#define THRESH 0.02f

__device__ inline float warp_red_sum(float v) {
  #pragma unroll
  for (int o = 32; o > 0; o >>= 1) v += __shfl_down(v, o, 64);
  return v;
}
__device__ inline float warp_allred_max(float v) {
  #pragma unroll
  for (int o = 32; o > 0; o >>= 1) v = fmaxf(v, __shfl_xor(v, o, 64));
  return v;
}
__device__ inline float warp_allred_sum(float v) {
  #pragma unroll
  for (int o = 32; o > 0; o >>= 1) v += __shfl_xor(v, o, 64);
  return v;
}

// wa = gat_W @ a  (512-vector); avoids the full x@gat_W GEMM since (x@W)@a = x@(W@a)
__global__ void k_wa(const float* __restrict__ gatW, const float* __restrict__ a1,
                     const float* __restrict__ a2, float* wa1, float* wa2) {
  int l = threadIdx.x;
  const float* row = gatW + l * LL;
  float s1 = 0.f, s2 = 0.f;
  for (int k = 0; k < LL; k++) { float w = row[k]; s1 += w * a1[k]; s2 += w * a2[k]; }
  wa1[l] = s1; wa2[l] = s2;
}

// ha1[b,c] = x[b,c,:].wa1 ; ha2 likewise. one wave per row.
__global__ void k_ha(const float* __restrict__ x, const float* __restrict__ wa1,
                     const float* __restrict__ wa2, float* ha1, float* ha2) {
  int wid = threadIdx.x >> 6, lane = threadIdx.x & 63;
  int row = blockIdx.x * 4 + wid;
  const float* xr = x + (size_t)row * LL;
  float s1 = 0.f, s2 = 0.f;
  for (int q = lane; q < LL; q += 64) { float v = xr[q]; s1 += v * wa1[q]; s2 += v * wa2[q]; }
  s1 = warp_red_sum(s1); s2 = warp_red_sum(s2);
  if (lane == 0) { ha1[row] = s1; ha2[row] = s2; }
}

// per (b,i): e_j = lrelu(ha1_i + ha2_j, 0.2); softmax over j; mask = A > 0.02
__global__ void k_softmask(const float* __restrict__ ha1, const float* __restrict__ ha2,
                           float* __restrict__ mask) {
  int wid = threadIdx.x >> 6, lane = threadIdx.x & 63;
  int row = blockIdx.x * 4 + wid;       // row = b*64+i
  int b = row >> 6;
  float e = ha1[row] + ha2[b * 64 + lane];
  e = e < 0.f ? 0.2f * e : e;
  float mx = warp_allred_max(e);
  float ex = expf(e - mx);
  float sm = warp_allred_sum(ex);
  float A = ex / sm;
  mask[(size_t)row * 64 + lane] = (A > THRESH) ? 1.0f : 0.0f;
}

// dinv[b,i] = 1/sqrt(1 + sum_j mask[b,i,j])   (A = m + I degree)
__global__ void k_dinv(const float* __restrict__ mask, float* dinv, int N) {
  int wid = threadIdx.x >> 6, lane = threadIdx.x & 63;
  int row = blockIdx.x * 4 + wid;       // b*N+i
  if (row >= BB * N) return;
  float v = (lane < N) ? mask[(size_t)row * N + lane] : 0.f;
  float s = warp_allred_sum(v);
  if (lane == 0) dinv[row] = 1.0f / sqrtf(s + 1.0f);
}

// xw[b,i,f] = sum_k gin[b,i,k] * W[k,f]   (HH=128 output)
__global__ void k_xw(const float* __restrict__ gin, const float* __restrict__ W,
                     float* __restrict__ out, int N, int K) {
  __shared__ float xs[512];
  int b = blockIdx.x / N, i = blockIdx.x % N;
  const float* grow = gin + (size_t)(b * N + i) * K;
  for (int k = threadIdx.x; k < K; k += 128) xs[k] = grow[k];
  __syncthreads();
  int f = threadIdx.x;
  float a0 = 0.f, a1 = 0.f, a2 = 0.f, a3 = 0.f;
  for (int k = 0; k < K; k += 4) {
    a0 += xs[k]     * W[(k)     * HH + f];
    a1 += xs[k + 1] * W[(k + 1) * HH + f];
    a2 += xs[k + 2] * W[(k + 2) * HH + f];
    a3 += xs[k + 3] * W[(k + 3) * HH + f];
  }
  out[(size_t)(b * N + i) * HH + f] = (a0 + a1) + (a2 + a3);
}

// g[b,i,f] = relu(dinv_i*(dinv_i*xw_if + sum_j m_ij*dinv_j*xw_jf) + bias_f)
__global__ void k_gcnagg(const float* __restrict__ xw, const float* __restrict__ mask,
                         const float* __restrict__ dinv, const float* __restrict__ bias,
                         float* __restrict__ gout, int N) {
  __shared__ float mrow[64], dv[64];
  int b = blockIdx.x / N, i = blockIdx.x % N;
  if (threadIdx.x < N) {
    mrow[threadIdx.x] = mask[(size_t)(b * N + i) * N + threadIdx.x];
    dv[threadIdx.x] = dinv[b * N + threadIdx.x];
  }
  __syncthreads();
  int f = threadIdx.x;
  float di = dv[i];
  float acc = di * xw[(size_t)(b * N + i) * HH + f];
  for (int j = 0; j < N; j++) acc += mrow[j] * dv[j] * xw[(size_t)(b * N + j) * HH + f];
  float y = di * acc + bias[f];
  gout[(size_t)(b * N + i) * HH + f] = y > 0.f ? y : 0.f;
}

// fused SAGPool: score -> top-k (jax tie-break: lowest index first) -> gather + gate -> readout accum
__global__ void k_pool(const float* __restrict__ g, const float* __restrict__ mask,
                       const float* __restrict__ w1, const float* __restrict__ w2,
                       const float* __restrict__ pb, int N, int kk,
                       float* gp, float* mnext, float* __restrict__ r) {
  __shared__ float d1[64], d2[64], sv[64], vals[32], tvs[32];
  __shared__ int idxs[32], flg[64];
  int b = blockIdx.x, tid = threadIdx.x;
  if (tid < N) {
    const float* gr = g + (size_t)(b * N + tid) * HH;
    float a = 0.f, c = 0.f;
    for (int d = 0; d < HH; d++) { float v = gr[d]; a += v * w1[d]; c += v * w2[d]; }
    d1[tid] = a; d2[tid] = c; flg[tid] = 0;
  }
  __syncthreads();
  if (tid < N) {
    const float* mr = mask + (size_t)(b * N + tid) * N;
    float s = d1[tid] + pb[0];
    for (int j = 0; j < N; j++) s += mr[j] * d2[j];
    sv[tid] = s;
  }
  __syncthreads();
  if (tid == 0) {
    for (int t = 0; t < kk; t++) {
      float best = -3.4e38f; int bi = 0;
      for (int j = 0; j < N; j++)
        if (!flg[j] && sv[j] > best) { best = sv[j]; bi = j; }
      flg[bi] = 1; idxs[t] = bi; vals[t] = best;
    }
  }
  __syncthreads();
  if (tid < kk) tvs[tid] = tanhf(vals[tid]);
  __syncthreads();
  if (tid < HH) {
    float mx = -3.4e38f, sm = 0.f;
    for (int t = 0; t < kk; t++) {
      float v = g[(size_t)(b * N + idxs[t]) * HH + tid] * tvs[t];
      if (gp) gp[(size_t)(b * kk + t) * HH + tid] = v;
      mx = fmaxf(mx, v); sm += v;
    }
    r[b * 256 + tid] += mx;
    r[b * 256 + 128 + tid] += sm / (float)kk;
  }
  if (mnext) {
    for (int q = tid; q < kk * kk; q += blockDim.x) {
      int t = q / kk, u = q % kk;
      mnext[(size_t)(b * kk + t) * kk + u] = mask[(size_t)(b * N + idxs[t]) * N + idxs[u]];
    }
  }
}

__global__ void k_tr(const float* __restrict__ in, float* __restrict__ out, int R, int Lc) {
  int idx = blockIdx.x * 256 + threadIdx.x;
  if (idx >= R * Lc) return;
  int j = idx / Lc, l = idx % Lc;
  out[l * R + j] = in[idx];
}

// gi[b,c,j] = bih[j] + sum_l x[b,c,l]*Wih[j,l]
__global__ void k_gi(const float* __restrict__ x, const float* __restrict__ wihT,
                     const float* __restrict__ bih, float* __restrict__ gi) {
  __shared__ float xs[512];
  int blk = blockIdx.x;  // b*64+c
  for (int k = threadIdx.x; k < LL; k += 384) xs[k] = x[(size_t)blk * LL + k];
  __syncthreads();
  int j = threadIdx.x;
  float acc = bih[j];
  #pragma unroll 4
  for (int l = 0; l < LL; l++) acc += xs[l] * wihT[l * G3 + j];
  gi[(size_t)blk * G3 + j] = acc;
}

// GRU recurrence: one workgroup per channel c (64 independent sequences over 256 steps)
__global__ void k_gru(const float* __restrict__ gi, const float* __restrict__ whhT,
                      const float* __restrict__ bhh, float* __restrict__ ys) {
  __shared__ float h[128], agh[384], agi[384];
  int c = blockIdx.x, j = threadIdx.x;
  if (j < 128) h[j] = 0.f;
  __syncthreads();
  for (int b = 0; b < BB; b++) {
    float g0 = bhh[j], g1 = 0.f;
    for (int k = 0; k < 128; k += 2) {
      g0 += whhT[k * G3 + j] * h[k];
      g1 += whhT[(k + 1) * G3 + j] * h[k + 1];
    }
    agh[j] = g0 + g1;
    agi[j] = gi[(size_t)(b * CC + c) * G3 + j];
    __syncthreads();
    if (j < 128) {
      float rg = 1.f / (1.f + expf(-(agi[j] + agh[j])));
      float zg = 1.f / (1.f + expf(-(agi[128 + j] + agh[128 + j])));
      float ng = tanhf(agi[256 + j] + rg * agh[256 + j]);
      float hn = (1.f - zg) * ng + zg * h[j];
      ys[(size_t)(b * CC + c) * 128 + j] = hn;
      h[j] = hn;
    }
    __syncthreads();
  }
}

__global__ void k_grumean(const float* __restrict__ ys, float* __restrict__ xgru) {
  int b = blockIdx.x, u = threadIdx.x;
  float acc = 0.f;
  for (int c = 0; c < CC; c++) acc += ys[(size_t)(b * CC + c) * 128 + u];
  xgru[b * 128 + u] = acc / 64.f;
}

// ---------------- tiled conv: block = (sample, 64-pos tile), 128 oc ----------------
// Each thread: 8 oc x 4 pos register tile. Input tile in LDS, transposed weights
// double-buffered through LDS in [16k][128oc] chunks. DOMEAN fuses relu+mean (atomic).
template<int CIN, int KS, int DIL, int PAD, int LIN, int LOUT, bool DOMEAN>
__global__ __launch_bounds__(256) void k_conv(const float* __restrict__ in,
                                              const float* __restrict__ Wt,
                                              const float* __restrict__ bias,
                                              float* __restrict__ out, int b0) {
  constexpr int KLEN = CIN * KS;
  constexpr int NCH = KLEN / 16;
  constexpr int TW = 72;                 // 64 pos + 8 left margin
  constexpr int NT = (LOUT + 63) / 64;
  __shared__ float si[CIN][TW];
  __shared__ float sw[2][16][128];
  int nb = blockIdx.x / NT;
  int p0 = (blockIdx.x % NT) * 64;
  const float* inb = in + (size_t)nb * CIN * LIN;
  for (int q = threadIdx.x; q < CIN * TW; q += 256) {
    int ci = q / TW, col = q % TW;
    int gp = p0 - 8 + col;
    si[ci][col] = (gp >= 0 && gp < LIN) ? inb[ci * LIN + gp] : 0.f;
  }
  int posg = threadIdx.x & 15;           // pos = p0 + posg*4 + j
  int ocg = threadIdx.x >> 4;            // oc  = ocg*8 + o
  float acc[8][4];
  #pragma unroll
  for (int o = 0; o < 8; o++)
    #pragma unroll
    for (int j = 0; j < 4; j++) acc[o][j] = 0.f;
  // prefetch chunk 0
  {
    const float4* src = (const float4*)Wt;
    float4 a = src[threadIdx.x * 2], b = src[threadIdx.x * 2 + 1];
    ((float4*)sw[0])[threadIdx.x * 2] = a;
    ((float4*)sw[0])[threadIdx.x * 2 + 1] = b;
  }
  __syncthreads();
  for (int ch = 0; ch < NCH; ch++) {
    float4 pa, pb;
    if (ch + 1 < NCH) {
      const float4* src = (const float4*)(Wt + (ch + 1) * 2048);
      pa = src[threadIdx.x * 2]; pb = src[threadIdx.x * 2 + 1];
    }
    int buf = ch & 1;
    #pragma unroll
    for (int kk = 0; kk < 16; kk++) {
      int k = ch * 16 + kk;
      int ci = k / KS, t = k - ci * KS;
      int off = t * DIL - PAD + 8;       // in [0,8]
      const float* ip = &si[ci][posg * 4 + off];
      float i0 = ip[0], i1 = ip[1], i2 = ip[2], i3 = ip[3];
      const float* wp = &sw[buf][kk][ocg * 8];
      #pragma unroll
      for (int o = 0; o < 8; o++) {
        float w = wp[o];
        acc[o][0] += w * i0; acc[o][1] += w * i1;
        acc[o][2] += w * i2; acc[o][3] += w * i3;
      }
    }
    __syncthreads();
    if (ch + 1 < NCH) {
      ((float4*)sw[(ch + 1) & 1])[threadIdx.x * 2] = pa;
      ((float4*)sw[(ch + 1) & 1])[threadIdx.x * 2 + 1] = pb;
      __syncthreads();
    }
  }
  if constexpr (DOMEAN) {
    #pragma unroll
    for (int o = 0; o < 8; o++) {
      int oc = ocg * 8 + o;
      float bz = bias[oc];
      float s = 0.f;
      #pragma unroll
      for (int j = 0; j < 4; j++) {
        int p = p0 + posg * 4 + j;
        if (p < LOUT) { float y = acc[o][j] + bz; s += y > 0.f ? y : 0.f; }
      }
      #pragma unroll
      for (int d = 8; d > 0; d >>= 1) s += __shfl_down(s, d, 64);
      if (posg == 0) atomicAdd(&out[(size_t)(b0 + nb) * 128 + oc], s);
    }
  } else {
    #pragma unroll
    for (int o = 0; o < 8; o++) {
      int oc = ocg * 8 + o;
      float bz = bias[oc];
      #pragma unroll
      for (int j = 0; j < 4; j++) {
        int p = p0 + posg * 4 + j;
        if (p < LOUT) {
          float y = acc[o][j] + bz;
          out[((size_t)nb * 128 + oc) * LOUT + p] = y > 0.f ? y : 0.f;
        }
      }
    }
  }
}

__global__ void k_fc0(const float* __restrict__ xconv, const float* __restrict__ xgru,
                      const float* __restrict__ r, const float* __restrict__ W,
                      const float* __restrict__ bias, float* __restrict__ hm) {
  __shared__ float feat[512];
  int b = blockIdx.x, t = threadIdx.x;
  if (t < 128) { feat[t] = xconv[b * 128 + t] * (1.f / (float)CL3); feat[128 + t] = xgru[b * 128 + t]; }
  feat[256 + t] = r[b * 256 + t];
  __syncthreads();
  float acc = bias[t];
  for (int k = 0; k < 512; k++) acc += feat[k] * W[k * 256 + t];
  hm[b * 256 + t] = acc;
}

// batchnorm over batch axis (train stats, two-pass) + leaky_relu(0.01)
__global__ void k_bn(const float* __restrict__ hm, const float* __restrict__ gamma,
                     const float* __restrict__ beta, float* __restrict__ out) {
  __shared__ float red[256];
  int n = blockIdx.x, t = threadIdx.x;
  float v = hm[t * 256 + n];
  red[t] = v; __syncthreads();
  for (int s = 128; s > 0; s >>= 1) { if (t < s) red[t] += red[t + s]; __syncthreads(); }
  float mean = red[0] / 256.f; __syncthreads();
  float dv = v - mean;
  red[t] = dv * dv; __syncthreads();
  for (int s = 128; s > 0; s >>= 1) { if (t < s) red[t] += red[t + s]; __syncthreads(); }
  float var = red[0] / 256.f;
  float y = gamma[n] * dv * (1.f / sqrtf(var + 1e-5f)) + beta[n];
  out[t * 256 + n] = y < 0.f ? 0.01f * y : y;
}

__global__ void k_fc1(const float* __restrict__ hmn, const float* __restrict__ W,
                      const float* __restrict__ bias, float* __restrict__ z) {
  __shared__ float hs[256];
  int b = blockIdx.x, t = threadIdx.x;
  hs[t] = hmn[b * 256 + t]; hs[128 + t] = hmn[b * 256 + 128 + t];
  __syncthreads();
  float acc = bias[t];
  for (int k = 0; k < 256; k++) acc += hs[k] * W[k * 128 + t];
  z[b * 128 + t] = acc;
}

// per-class attention logits + masked softmax over samples + prototype
__global__ void k_att(const float* __restrict__ z, const int* __restrict__ labels,
                      const int* __restrict__ idx_train, int ntrain,
                      const float* __restrict__ W1, const float* __restrict__ b1,
                      const float* __restrict__ W2, const float* __restrict__ b2,
                      float* __restrict__ protos) {
  __shared__ float wv[256], red[256];
  __shared__ int trainm[256];
  int c = blockIdx.x, n = threadIdx.x;
  trainm[n] = 0; __syncthreads();
  if (n < ntrain) trainm[idx_train[n]] = 1;
  __syncthreads();
  const float* zr = z + n * 128;
  float acc = b2[c];
  for (int a = 0; a < AT; a++) {
    float s = b1[c * AT + a];
    const float* w1c = W1 + (size_t)c * 128 * AT + a;
    for (int d = 0; d < 128; d++) s += zr[d] * w1c[d * AT];
    acc += tanhf(s) * W2[c * AT + a];
  }
  bool keep = trainm[n] && (labels[n] == c);
  float ml = keep ? acc : -1e30f;
  red[n] = ml; __syncthreads();
  for (int s = 128; s > 0; s >>= 1) { if (n < s) red[n] = fmaxf(red[n], red[n + s]); __syncthreads(); }
  float mx = red[0]; __syncthreads();
  float e = expf(ml - mx);
  wv[n] = e; red[n] = e; __syncthreads();
  for (int s = 128; s > 0; s >>= 1) { if (n < s) red[n] += red[n + s]; __syncthreads(); }
  float ssum = red[0]; __syncthreads();
  wv[n] = wv[n] / ssum;
  __syncthreads();
  if (n < 128) {
    float p = 0.f;
    for (int q = 0; q < 256; q++) p += wv[q] * z[q * 128 + n];
    protos[c * 128 + n] = p;
  }
}

__global__ void k_dist(const float* __restrict__ z, const float* __restrict__ protos,
                       float* __restrict__ dout) {
  __shared__ float zs[128], red[128];
  int n = blockIdx.x, t = threadIdx.x;
  zs[t] = z[n * 128 + t];
  red[t] = zs[t] * zs[t]; __syncthreads();
  for (int s = 64; s > 0; s >>= 1) { if (t < s) red[t] += red[t + s]; __syncthreads(); }
  float z2 = red[0];
  if (t < NC) {
    float dot = 0.f, p2 = 0.f;
    const float* pr = protos + t * 128;
    for (int d = 0; d < 128; d++) { float pv = pr[d]; dot += pv * zs[d]; p2 += pv * pv; }
    float d2 = fmaxf(z2 + p2 - 2.f * dot, 1e-12f);
    dout[n * NC + t] = expf(-0.5f * sqrtf(d2));
  }
}

__global__ void k_pdist(const float* __restrict__ protos, float* __restrict__ dout) {
  __shared__ float red[64];
  int t = threadIdx.x, i = t / 8, j = t % 8;
  float dot = 0.f, p2i = 0.f, p2j = 0.f;
  for (int d = 0; d < 128; d++) {
    float a = protos[i * 128 + d], b = protos[j * 128 + d];
    dot += a * b; p2i += a * a; p2j += b * b;
  }
  float d2 = fmaxf(p2i + p2j - 2.f * dot, 1e-12f);
  red[t] = expf(-0.5f * sqrtf(d2));
  __syncthreads();
  for (int s = 32; s > 0; s >>= 1) { if (t < s) red[t] += red[t + s]; __syncthreads(); }
  if (t == 0) dout[2048] = red[0] / 28.f;
}

extern "C" void kernel_launch(void* const* d_in, const int* in_sizes, int n_in,
                              void* d_out, int out_size, void* d_ws, size_t ws_size,
                              hipStream_t stream) {
  const float* x = (const float*)d_in[0];
  const int* labels = (const int*)d_in[1];
  const int* idx_train = (const int*)d_in[2];
  const float* gat_W = (const float*)d_in[3];
  const float* gat_a1 = (const float*)d_in[4];
  const float* gat_a2 = (const float*)d_in[5];
  const float* gcnW[3] = {(const float*)d_in[6], (const float*)d_in[8], (const float*)d_in[10]};
  const float* gcnB[3] = {(const float*)d_in[7], (const float*)d_in[9], (const float*)d_in[11]};
  const float* pw1[3] = {(const float*)d_in[12], (const float*)d_in[15], (const float*)d_in[18]};
  const float* pw2[3] = {(const float*)d_in[13], (const float*)d_in[16], (const float*)d_in[19]};
  const float* pbb[3] = {(const float*)d_in[14], (const float*)d_in[17], (const float*)d_in[20]};
  const float* wih = (const float*)d_in[21];
  const float* whh = (const float*)d_in[22];
  const float* bih = (const float*)d_in[23];
  const float* bhh = (const float*)d_in[24];
  const float* c1W = (const float*)d_in[25]; const float* c1b = (const float*)d_in[26];
  const float* c2W = (const float*)d_in[27]; const float* c2b = (const float*)d_in[28];
  const float* c3W = (const float*)d_in[29]; const float* c3b = (const float*)d_in[30];
  const float* fc0W = (const float*)d_in[31]; const float* fc0b = (const float*)d_in[32];
  const float* bn0g = (const float*)d_in[33]; const float* bn0b = (const float*)d_in[34];
  const float* fc1W = (const float*)d_in[35]; const float* fc1b = (const float*)d_in[36];
  const float* aW1 = (const float*)d_in[37]; const float* ab1 = (const float*)d_in[38];
  const float* aW2 = (const float*)d_in[39]; const float* ab2 = (const float*)d_in[40];
  float* out = (float*)d_out;
  float* ws = (float*)d_ws;

  // ---- workspace layout (floats). Z region reused by 3 sequential phases. ----
  size_t off = 0;
  auto take = [&](size_t n) { size_t o = off; off += (n + 63) & ~(size_t)63; return o; };
  float* wa1   = ws + take(512);
  float* wa2   = ws + take(512);
  float* ha1   = ws + take(BB * CC);
  float* ha2   = ws + take(BB * CC);
  float* dinv  = ws + take(BB * 64);
  float* rbuf  = ws + take(BB * 256);
  float* xgru  = ws + take(BB * 128);
  float* xconv = ws + take(BB * 128);
  float* hm    = ws + take(BB * 256);
  float* hmn   = ws + take(BB * 256);
  float* zb    = ws + take(BB * 128);
  float* protos = ws + take(NC * 128);
  float* wihT  = ws + take(512 * 384);   // GRU phase; conv-weight Wt aliases after GRU
  float* whhT  = ws + take(128 * 384);
  float* Z     = ws + take(8568832);
  // GNN-phase aliases
  float* mA  = Z;
  float* mB  = Z + 1048576;
  float* xw  = Z + 2097152;
  float* gb  = Z + 4194304;
  float* gp1 = Z + 6291456;
  float* gp2 = Z + 7340032;
  // GRU-phase aliases
  float* gi = Z;
  float* ys = Z + 6291456;
  // conv-phase aliases (chunks of 64 samples)
  float* cv1 = Z;
  float* cv2 = Z + 4251648;
  float* wt1 = wihT;                 // 512*128 (dead after k_gi/k_gru)
  float* wt2 = wt1 + 512 * 128;      // 640*128
  float* wt3 = wt2 + 640 * 128;      // 384*128 (fits in wihT+whhT region)

  hipMemsetAsync(rbuf, 0, BB * 256 * sizeof(float), stream);
  hipMemsetAsync(xconv, 0, BB * 128 * sizeof(float), stream);

  // ---- GAT adjacency ----
  k_wa<<<1, 512, 0, stream>>>(gat_W, gat_a1, gat_a2, wa1, wa2);
  k_ha<<<BB * CC / 4, 256, 0, stream>>>(x, wa1, wa2, ha1, ha2);
  k_softmask<<<BB * 64 / 4, 256, 0, stream>>>(ha1, ha2, mA);

  // ---- 3x (GCN + SAGPool) with jump-knowledge readout ----
  const int Ns[3] = {64, 32, 16};
  const int ks[3] = {32, 16, 8};
  const int Kin[3] = {512, 128, 128};
  const float* gins[3] = {x, gp1, gp2};
  float* mcur[3] = {mA, mB, mA};
  float* mnxt[3] = {mB, mA, nullptr};
  float* gps[3]  = {gp1, gp2, nullptr};
  for (int s = 0; s < 3; s++) {
    int N = Ns[s];
    k_dinv<<<(BB * N + 3) / 4, 256, 0, stream>>>(mcur[s], dinv, N);
    k_xw<<<BB * N, 128, 0, stream>>>(gins[s], gcnW[s], xw, N, Kin[s]);
    k_gcnagg<<<BB * N, 128, 0, stream>>>(xw, mcur[s], dinv, gcnB[s], gb, N);
    k_pool<<<BB, 256, 0, stream>>>(gb, mcur[s], pw1[s], pw2[s], pbb[s], N, ks[s],
                                   gps[s], mnxt[s], rbuf);
  }

  // ---- GRU branch ----
  k_tr<<<(384 * 512 + 255) / 256, 256, 0, stream>>>(wih, wihT, 384, 512);
  k_tr<<<(384 * 128 + 255) / 256, 256, 0, stream>>>(whh, whhT, 384, 128);
  k_gi<<<BB * CC, 384, 0, stream>>>(x, wihT, bih, gi);
  k_gru<<<CC, 384, 0, stream>>>(gi, whhT, bhh, ys);
  k_grumean<<<BB, 128, 0, stream>>>(ys, xgru);

  // ---- dilated conv branch (wihT/whhT regions are dead now; reuse for Wt) ----
  k_tr<<<(128 * 512 + 255) / 256, 256, 0, stream>>>(c1W, wt1, 128, 512);
  k_tr<<<(128 * 640 + 255) / 256, 256, 0, stream>>>(c2W, wt2, 128, 640);
  k_tr<<<(128 * 384 + 255) / 256, 256, 0, stream>>>(c3W, wt3, 128, 384);
  for (int bc = 0; bc < 4; bc++) {
    int b0 = bc * 64;
    k_conv<64, 8, 1, 7, 512, CL1, false><<<64 * 9, 256, 0, stream>>>(
        x + (size_t)b0 * CC * LL, wt1, c1b, cv1, b0);
    k_conv<128, 5, 2, 8, CL1, CL2, false><<<64 * 9, 256, 0, stream>>>(
        cv1, wt2, c2b, cv2, b0);
    k_conv<128, 3, 4, 8, CL2, CL3, true><<<64 * 9, 256, 0, stream>>>(
        cv2, wt3, c3b, xconv, b0);
  }

  // ---- mapping MLP + BN + attention prototypes + distances ----
  k_fc0<<<BB, 256, 0, stream>>>(xconv, xgru, rbuf, fc0W, fc0b, hm);
  k_bn<<<256, 256, 0, stream>>>(hm, bn0g, bn0b, hmn);
  k_fc1<<<BB, 128, 0, stream>>>(hmn, fc1W, fc1b, zb);
  k_att<<<NC, 256, 0, stream>>>(zb, labels, idx_train, in_sizes[2], aW1, ab1, aW2, ab2, protos);
  k_dist<<<BB, 128, 0, stream>>>(zb, protos, out);
  k_pdist<<<1, 64, 0, stream>>>(protos, out);
}

// Round 3
// 2607.973 us; speedup vs baseline: 3.9143x; 1.2697x over previous
//
#include <hip/hip_runtime.h>
#include <math.h>

#define BB 256   // batch
#define CC 64    // channels / graph nodes
#define LL 512   // series length
#define HH 128   // gcn hidden
#define G3 384   // 3*gru_dim
#define NC 8
#define AT 64
#define CL1 519
#define CL2 527
#define CL3 535
#define THRESH 0.02f

__device__ inline float warp_red_sum(float v) {
  #pragma unroll
  for (int o = 32; o > 0; o >>= 1) v += __shfl_down(v, o, 64);
  return v;
}
__device__ inline float warp_allred_max(float v) {
  #pragma unroll
  for (int o = 32; o > 0; o >>= 1) v = fmaxf(v, __shfl_xor(v, o, 64));
  return v;
}
__device__ inline float warp_allred_sum(float v) {
  #pragma unroll
  for (int o = 32; o > 0; o >>= 1) v += __shfl_xor(v, o, 64);
  return v;
}

// wa = gat_W @ a  (512-vector); avoids the full x@gat_W GEMM since (x@W)@a = x@(W@a)
__global__ void k_wa(const float* __restrict__ gatW, const float* __restrict__ a1,
                     const float* __restrict__ a2, float* wa1, float* wa2) {
  int l = threadIdx.x;
  const float* row = gatW + l * LL;
  float s1 = 0.f, s2 = 0.f;
  for (int k = 0; k < LL; k++) { float w = row[k]; s1 += w * a1[k]; s2 += w * a2[k]; }
  wa1[l] = s1; wa2[l] = s2;
}

// ha1[b,c] = x[b,c,:].wa1 ; ha2 likewise. one wave per row.
__global__ void k_ha(const float* __restrict__ x, const float* __restrict__ wa1,
                     const float* __restrict__ wa2, float* ha1, float* ha2) {
  int wid = threadIdx.x >> 6, lane = threadIdx.x & 63;
  int row = blockIdx.x * 4 + wid;
  const float* xr = x + (size_t)row * LL;
  float s1 = 0.f, s2 = 0.f;
  for (int q = lane; q < LL; q += 64) { float v = xr[q]; s1 += v * wa1[q]; s2 += v * wa2[q]; }
  s1 = warp_red_sum(s1); s2 = warp_red_sum(s2);
  if (lane == 0) { ha1[row] = s1; ha2[row] = s2; }
}

// per (b,i): e_j = lrelu(ha1_i + ha2_j, 0.2); softmax over j; mask = A > 0.02
__global__ void k_softmask(const float* __restrict__ ha1, const float* __restrict__ ha2,
                           float* __restrict__ mask) {
  int wid = threadIdx.x >> 6, lane = threadIdx.x & 63;
  int row = blockIdx.x * 4 + wid;       // row = b*64+i
  int b = row >> 6;
  float e = ha1[row] + ha2[b * 64 + lane];
  e = e < 0.f ? 0.2f * e : e;
  float mx = warp_allred_max(e);
  float ex = expf(e - mx);
  float sm = warp_allred_sum(ex);
  float A = ex / sm;
  mask[(size_t)row * 64 + lane] = (A > THRESH) ? 1.0f : 0.0f;
}

// dinv[b,i] = 1/sqrt(1 + sum_j mask[b,i,j])   (A = m + I degree)
__global__ void k_dinv(const float* __restrict__ mask, float* dinv, int N) {
  int wid = threadIdx.x >> 6, lane = threadIdx.x & 63;
  int row = blockIdx.x * 4 + wid;       // b*N+i
  if (row >= BB * N) return;
  float v = (lane < N) ? mask[(size_t)row * N + lane] : 0.f;
  float s = warp_allred_sum(v);
  if (lane == 0) dinv[row] = 1.0f / sqrtf(s + 1.0f);
}

// generic tiled GEMM: C[M,N] = A[M,K] @ B[K,N], all row-major.
// BM=64,BN=64,BK=32, 256 threads, 4x4 microtile. Requires M%64==0, N%64==0, K%32==0.
__global__ __launch_bounds__(256) void k_gemm(const float* __restrict__ A,
                                              const float* __restrict__ B,
                                              float* __restrict__ C,
                                              int M, int N, int K) {
  __shared__ float sa[32][64];   // [k][m]
  __shared__ float sb[32][64];   // [k][n]
  int nbn = N >> 6;
  int bm = blockIdx.x / nbn, bn = blockIdx.x % nbn;
  int m0 = bm * 64, n0 = bn * 64;
  int tx = threadIdx.x & 15, ty = threadIdx.x >> 4;   // 16x16
  float acc[4][4];
  #pragma unroll
  for (int i = 0; i < 4; i++)
    #pragma unroll
    for (int j = 0; j < 4; j++) acc[i][j] = 0.f;
  // staging indices
  int arow = threadIdx.x >> 2;            // 0..63
  int acol = (threadIdx.x & 3) * 8;       // 0,8,16,24  (two float4 each)
  int brow = threadIdx.x >> 4;            // 0..15 (x2 rows)
  int bcol = (threadIdx.x & 15) * 4;
  for (int k0 = 0; k0 < K; k0 += 32) {
    float4 av0 = *(const float4*)&A[(size_t)(m0 + arow) * K + k0 + acol];
    float4 av1 = *(const float4*)&A[(size_t)(m0 + arow) * K + k0 + acol + 4];
    float4 bv0 = *(const float4*)&B[(size_t)(k0 + brow) * N + n0 + bcol];
    float4 bv1 = *(const float4*)&B[(size_t)(k0 + brow + 16) * N + n0 + bcol];
    __syncthreads();
    sa[acol + 0][arow] = av0.x; sa[acol + 1][arow] = av0.y;
    sa[acol + 2][arow] = av0.z; sa[acol + 3][arow] = av0.w;
    sa[acol + 4][arow] = av1.x; sa[acol + 5][arow] = av1.y;
    sa[acol + 6][arow] = av1.z; sa[acol + 7][arow] = av1.w;
    *(float4*)&sb[brow][bcol] = bv0;
    *(float4*)&sb[brow + 16][bcol] = bv1;
    __syncthreads();
    #pragma unroll
    for (int kk = 0; kk < 32; kk++) {
      float4 a4 = *(const float4*)&sa[kk][ty * 4];
      float4 b4 = *(const float4*)&sb[kk][tx * 4];
      acc[0][0] += a4.x * b4.x; acc[0][1] += a4.x * b4.y; acc[0][2] += a4.x * b4.z; acc[0][3] += a4.x * b4.w;
      acc[1][0] += a4.y * b4.x; acc[1][1] += a4.y * b4.y; acc[1][2] += a4.y * b4.z; acc[1][3] += a4.y * b4.w;
      acc[2][0] += a4.z * b4.x; acc[2][1] += a4.z * b4.y; acc[2][2] += a4.z * b4.z; acc[2][3] += a4.z * b4.w;
      acc[3][0] += a4.w * b4.x; acc[3][1] += a4.w * b4.y; acc[3][2] += a4.w * b4.z; acc[3][3] += a4.w * b4.w;
    }
  }
  #pragma unroll
  for (int i = 0; i < 4; i++) {
    float4 v = make_float4(acc[i][0], acc[i][1], acc[i][2], acc[i][3]);
    *(float4*)&C[(size_t)(m0 + ty * 4 + i) * N + n0 + tx * 4] = v;
  }
}

// xw[b,i,f] = sum_k gin[b,i,k] * W[k,f]   (HH=128 output) — small stages (K=128)
__global__ void k_xw(const float* __restrict__ gin, const float* __restrict__ W,
                     float* __restrict__ out, int N, int K) {
  __shared__ float xs[512];
  int b = blockIdx.x / N, i = blockIdx.x % N;
  const float* grow = gin + (size_t)(b * N + i) * K;
  for (int k = threadIdx.x; k < K; k += 128) xs[k] = grow[k];
  __syncthreads();
  int f = threadIdx.x;
  float a0 = 0.f, a1 = 0.f, a2 = 0.f, a3 = 0.f;
  for (int k = 0; k < K; k += 4) {
    a0 += xs[k]     * W[(k)     * HH + f];
    a1 += xs[k + 1] * W[(k + 1) * HH + f];
    a2 += xs[k + 2] * W[(k + 2) * HH + f];
    a3 += xs[k + 3] * W[(k + 3) * HH + f];
  }
  out[(size_t)(b * N + i) * HH + f] = (a0 + a1) + (a2 + a3);
}

// g[b,i,f] = relu(dinv_i*(dinv_i*xw_if + sum_j m_ij*dinv_j*xw_jf) + bias_f)
__global__ void k_gcnagg(const float* __restrict__ xw, const float* __restrict__ mask,
                         const float* __restrict__ dinv, const float* __restrict__ bias,
                         float* __restrict__ gout, int N) {
  __shared__ float mrow[64], dv[64];
  int b = blockIdx.x / N, i = blockIdx.x % N;
  if (threadIdx.x < N) {
    mrow[threadIdx.x] = mask[(size_t)(b * N + i) * N + threadIdx.x];
    dv[threadIdx.x] = dinv[b * N + threadIdx.x];
  }
  __syncthreads();
  int f = threadIdx.x;
  float di = dv[i];
  float acc = di * xw[(size_t)(b * N + i) * HH + f];
  for (int j = 0; j < N; j++) acc += mrow[j] * dv[j] * xw[(size_t)(b * N + j) * HH + f];
  float y = di * acc + bias[f];
  gout[(size_t)(b * N + i) * HH + f] = y > 0.f ? y : 0.f;
}

// fused SAGPool: score -> top-k (jax tie-break: lowest index first) -> gather + gate -> readout accum
__global__ void k_pool(const float* __restrict__ g, const float* __restrict__ mask,
                       const float* __restrict__ w1, const float* __restrict__ w2,
                       const float* __restrict__ pb, int N, int kk,
                       float* gp, float* mnext, float* __restrict__ r) {
  __shared__ float d1[64], d2[64], sv[64], vals[32], tvs[32];
  __shared__ int idxs[32], flg[64];
  int b = blockIdx.x, tid = threadIdx.x;
  if (tid < N) {
    const float* gr = g + (size_t)(b * N + tid) * HH;
    float a = 0.f, c = 0.f;
    for (int d = 0; d < HH; d++) { float v = gr[d]; a += v * w1[d]; c += v * w2[d]; }
    d1[tid] = a; d2[tid] = c; flg[tid] = 0;
  }
  __syncthreads();
  if (tid < N) {
    const float* mr = mask + (size_t)(b * N + tid) * N;
    float s = d1[tid] + pb[0];
    for (int j = 0; j < N; j++) s += mr[j] * d2[j];
    sv[tid] = s;
  }
  __syncthreads();
  if (tid == 0) {
    for (int t = 0; t < kk; t++) {
      float best = -3.4e38f; int bi = 0;
      for (int j = 0; j < N; j++)
        if (!flg[j] && sv[j] > best) { best = sv[j]; bi = j; }
      flg[bi] = 1; idxs[t] = bi; vals[t] = best;
    }
  }
  __syncthreads();
  if (tid < kk) tvs[tid] = tanhf(vals[tid]);
  __syncthreads();
  if (tid < HH) {
    float mx = -3.4e38f, sm = 0.f;
    for (int t = 0; t < kk; t++) {
      float v = g[(size_t)(b * N + idxs[t]) * HH + tid] * tvs[t];
      if (gp) gp[(size_t)(b * kk + t) * HH + tid] = v;
      mx = fmaxf(mx, v); sm += v;
    }
    r[b * 256 + tid] += mx;
    r[b * 256 + 128 + tid] += sm / (float)kk;
  }
  if (mnext) {
    for (int q = tid; q < kk * kk; q += blockDim.x) {
      int t = q / kk, u = q % kk;
      mnext[(size_t)(b * kk + t) * kk + u] = mask[(size_t)(b * N + idxs[t]) * N + idxs[u]];
    }
  }
}

__global__ void k_tr(const float* __restrict__ in, float* __restrict__ out, int R, int Lc) {
  int idx = blockIdx.x * 256 + threadIdx.x;
  if (idx >= R * Lc) return;
  int j = idx / Lc, l = idx % Lc;
  out[l * R + j] = in[idx];
}

// GRU recurrence: one workgroup per channel c; whhT column held in VGPRs.
__global__ __launch_bounds__(384) void k_gru(const float* __restrict__ gi,
                                             const float* __restrict__ whhT,
                                             const float* __restrict__ bhh,
                                             const float* __restrict__ bih,
                                             float* __restrict__ ys) {
  __shared__ float h[128], agh[384], agi[384];
  int c = blockIdx.x, j = threadIdx.x;
  float w[128];
  #pragma unroll
  for (int k = 0; k < 128; k++) w[k] = whhT[k * G3 + j];
  float bh = bhh[j], bi = bih[j];
  if (j < 128) h[j] = 0.f;
  __syncthreads();
  for (int b = 0; b < BB; b++) {
    float gv = gi[(size_t)(b * CC + c) * G3 + j] + bi;   // issued early, hidden by matvec
    float a0 = 0.f, a1 = 0.f, a2 = 0.f, a3 = 0.f;
    #pragma unroll
    for (int k = 0; k < 128; k += 4) {
      float4 hv = *(const float4*)&h[k];
      a0 = fmaf(hv.x, w[k],     a0);
      a1 = fmaf(hv.y, w[k + 1], a1);
      a2 = fmaf(hv.z, w[k + 2], a2);
      a3 = fmaf(hv.w, w[k + 3], a3);
    }
    agh[j] = (a0 + a1) + (a2 + a3) + bh;
    agi[j] = gv;
    __syncthreads();
    if (j < 128) {
      float rg = 1.f / (1.f + expf(-(agi[j] + agh[j])));
      float zg = 1.f / (1.f + expf(-(agi[128 + j] + agh[128 + j])));
      float ng = tanhf(agi[256 + j] + rg * agh[256 + j]);
      float hn = (1.f - zg) * ng + zg * h[j];
      ys[(size_t)(b * CC + c) * 128 + j] = hn;
      h[j] = hn;
    }
    __syncthreads();
  }
}

__global__ void k_grumean(const float* __restrict__ ys, float* __restrict__ xgru) {
  int b = blockIdx.x, u = threadIdx.x;
  float acc = 0.f;
  for (int c = 0; c < CC; c++) acc += ys[(size_t)(b * CC + c) * 128 + u];
  xgru[b * 128 + u] = acc / 64.f;
}

// ---------------- tiled conv: block = (sample, 64-pos tile), 128 oc ----------------
template<int CIN, int KS, int DIL, int PAD, int LIN, int LOUT, bool DOMEAN>
__global__ __launch_bounds__(256) void k_conv(const float* __restrict__ in,
                                              const float* __restrict__ Wt,
                                              const float* __restrict__ bias,
                                              float* __restrict__ out, int b0) {
  constexpr int KLEN = CIN * KS;
  constexpr int NCH = KLEN / 16;
  constexpr int TW = 72;                 // 64 pos + 8 left margin
  constexpr int NT = (LOUT + 63) / 64;
  __shared__ float si[CIN][TW];
  __shared__ float sw[2][16][128];
  int nb = blockIdx.x / NT;
  int p0 = (blockIdx.x % NT) * 64;
  const float* inb = in + (size_t)nb * CIN * LIN;
  for (int q = threadIdx.x; q < CIN * TW; q += 256) {
    int ci = q / TW, col = q % TW;
    int gp = p0 - 8 + col;
    si[ci][col] = (gp >= 0 && gp < LIN) ? inb[ci * LIN + gp] : 0.f;
  }
  int posg = threadIdx.x & 15;           // pos = p0 + posg*4 + j
  int ocg = threadIdx.x >> 4;            // oc  = ocg*8 + o
  float acc[8][4];
  #pragma unroll
  for (int o = 0; o < 8; o++)
    #pragma unroll
    for (int j = 0; j < 4; j++) acc[o][j] = 0.f;
  {
    const float4* src = (const float4*)Wt;
    float4 a = src[threadIdx.x * 2], b = src[threadIdx.x * 2 + 1];
    ((float4*)sw[0])[threadIdx.x * 2] = a;
    ((float4*)sw[0])[threadIdx.x * 2 + 1] = b;
  }
  __syncthreads();
  for (int ch = 0; ch < NCH; ch++) {
    float4 pa, pb;
    if (ch + 1 < NCH) {
      const float4* src = (const float4*)(Wt + (ch + 1) * 2048);
      pa = src[threadIdx.x * 2]; pb = src[threadIdx.x * 2 + 1];
    }
    int buf = ch & 1;
    #pragma unroll
    for (int kk = 0; kk < 16; kk++) {
      int k = ch * 16 + kk;
      int ci = k / KS, t = k - ci * KS;
      int off = t * DIL - PAD + 8;       // in [0,8]
      const float* ip = &si[ci][posg * 4 + off];
      float i0 = ip[0], i1 = ip[1], i2 = ip[2], i3 = ip[3];
      const float* wp = &sw[buf][kk][ocg * 8];
      #pragma unroll
      for (int o = 0; o < 8; o++) {
        float w = wp[o];
        acc[o][0] += w * i0; acc[o][1] += w * i1;
        acc[o][2] += w * i2; acc[o][3] += w * i3;
      }
    }
    __syncthreads();
    if (ch + 1 < NCH) {
      ((float4*)sw[(ch + 1) & 1])[threadIdx.x * 2] = pa;
      ((float4*)sw[(ch + 1) & 1])[threadIdx.x * 2 + 1] = pb;
      __syncthreads();
    }
  }
  if constexpr (DOMEAN) {
    #pragma unroll
    for (int o = 0; o < 8; o++) {
      int oc = ocg * 8 + o;
      float bz = bias[oc];
      float s = 0.f;
      #pragma unroll
      for (int j = 0; j < 4; j++) {
        int p = p0 + posg * 4 + j;
        if (p < LOUT) { float y = acc[o][j] + bz; s += y > 0.f ? y : 0.f; }
      }
      #pragma unroll
      for (int d = 8; d > 0; d >>= 1) s += __shfl_down(s, d, 64);
      if (posg == 0) atomicAdd(&out[(size_t)(b0 + nb) * 128 + oc], s);
    }
  } else {
    #pragma unroll
    for (int o = 0; o < 8; o++) {
      int oc = ocg * 8 + o;
      float bz = bias[oc];
      #pragma unroll
      for (int j = 0; j < 4; j++) {
        int p = p0 + posg * 4 + j;
        if (p < LOUT) {
          float y = acc[o][j] + bz;
          out[((size_t)nb * 128 + oc) * LOUT + p] = y > 0.f ? y : 0.f;
        }
      }
    }
  }
}

__global__ void k_fc0(const float* __restrict__ xconv, const float* __restrict__ xgru,
                      const float* __restrict__ r, const float* __restrict__ W,
                      const float* __restrict__ bias, float* __restrict__ hm) {
  __shared__ float feat[512];
  int b = blockIdx.x, t = threadIdx.x;
  if (t < 128) { feat[t] = xconv[b * 128 + t] * (1.f / (float)CL3); feat[128 + t] = xgru[b * 128 + t]; }
  feat[256 + t] = r[b * 256 + t];
  __syncthreads();
  float acc = bias[t];
  for (int k = 0; k < 512; k++) acc += feat[k] * W[k * 256 + t];
  hm[b * 256 + t] = acc;
}

// batchnorm over batch axis (train stats, two-pass) + leaky_relu(0.01)
__global__ void k_bn(const float* __restrict__ hm, const float* __restrict__ gamma,
                     const float* __restrict__ beta, float* __restrict__ out) {
  __shared__ float red[256];
  int n = blockIdx.x, t = threadIdx.x;
  float v = hm[t * 256 + n];
  red[t] = v; __syncthreads();
  for (int s = 128; s > 0; s >>= 1) { if (t < s) red[t] += red[t + s]; __syncthreads(); }
  float mean = red[0] / 256.f; __syncthreads();
  float dv = v - mean;
  red[t] = dv * dv; __syncthreads();
  for (int s = 128; s > 0; s >>= 1) { if (t < s) red[t] += red[t + s]; __syncthreads(); }
  float var = red[0] / 256.f;
  float y = gamma[n] * dv * (1.f / sqrtf(var + 1e-5f)) + beta[n];
  out[t * 256 + n] = y < 0.f ? 0.01f * y : y;
}

__global__ void k_fc1(const float* __restrict__ hmn, const float* __restrict__ W,
                      const float* __restrict__ bias, float* __restrict__ z) {
  __shared__ float hs[256];
  int b = blockIdx.x, t = threadIdx.x;
  hs[t] = hmn[b * 256 + t]; hs[128 + t] = hmn[b * 256 + 128 + t];
  __syncthreads();
  float acc = bias[t];
  for (int k = 0; k < 256; k++) acc += hs[k] * W[k * 128 + t];
  z[b * 128 + t] = acc;
}

// per-class attention logits + masked softmax over samples + prototype
__global__ void k_att(const float* __restrict__ z, const int* __restrict__ labels,
                      const int* __restrict__ idx_train, int ntrain,
                      const float* __restrict__ W1, const float* __restrict__ b1,
                      const float* __restrict__ W2, const float* __restrict__ b2,
                      float* __restrict__ protos) {
  __shared__ float wv[256], red[256];
  __shared__ int trainm[256];
  int c = blockIdx.x, n = threadIdx.x;
  trainm[n] = 0; __syncthreads();
  if (n < ntrain) trainm[idx_train[n]] = 1;
  __syncthreads();
  const float* zr = z + n * 128;
  float acc = b2[c];
  for (int a = 0; a < AT; a++) {
    float s = b1[c * AT + a];
    const float* w1c = W1 + (size_t)c * 128 * AT + a;
    for (int d = 0; d < 128; d++) s += zr[d] * w1c[d * AT];
    acc += tanhf(s) * W2[c * AT + a];
  }
  bool keep = trainm[n] && (labels[n] == c);
  float ml = keep ? acc : -1e30f;
  red[n] = ml; __syncthreads();
  for (int s = 128; s > 0; s >>= 1) { if (n < s) red[n] = fmaxf(red[n], red[n + s]); __syncthreads(); }
  float mx = red[0]; __syncthreads();
  float e = expf(ml - mx);
  wv[n] = e; red[n] = e; __syncthreads();
  for (int s = 128; s > 0; s >>= 1) { if (n < s) red[n] += red[n + s]; __syncthreads(); }
  float ssum = red[0]; __syncthreads();
  wv[n] = wv[n] / ssum;
  __syncthreads();
  if (n < 128) {
    float p = 0.f;
    for (int q = 0; q < 256; q++) p += wv[q] * z[q * 128 + n];
    protos[c * 128 + n] = p;
  }
}

__global__ void k_dist(const float* __restrict__ z, const float* __restrict__ protos,
                       float* __restrict__ dout) {
  __shared__ float zs[128], red[128];
  int n = blockIdx.x, t = threadIdx.x;
  zs[t] = z[n * 128 + t];
  red[t] = zs[t] * zs[t]; __syncthreads();
  for (int s = 64; s > 0; s >>= 1) { if (t < s) red[t] += red[t + s]; __syncthreads(); }
  float z2 = red[0];
  if (t < NC) {
    float dot = 0.f, p2 = 0.f;
    const float* pr = protos + t * 128;
    for (int d = 0; d < 128; d++) { float pv = pr[d]; dot += pv * zs[d]; p2 += pv * pv; }
    float d2 = fmaxf(z2 + p2 - 2.f * dot, 1e-12f);
    dout[n * NC + t] = expf(-0.5f * sqrtf(d2));
  }
}

__global__ void k_pdist(const float* __restrict__ protos, float* __restrict__ dout) {
  __shared__ float red[64];
  int t = threadIdx.x, i = t / 8, j = t % 8;
  float dot = 0.f, p2i = 0.f, p2j = 0.f;
  for (int d = 0; d < 128; d++) {
    float a = protos[i * 128 + d], b = protos[j * 128 + d];
    dot += a * b; p2i += a * a; p2j += b * b;
  }
  float d2 = fmaxf(p2i + p2j - 2.f * dot, 1e-12f);
  red[t] = expf(-0.5f * sqrtf(d2));
  __syncthreads();
  for (int s = 32; s > 0; s >>= 1) { if (t < s) red[t] += red[t + s]; __syncthreads(); }
  if (t == 0) dout[2048] = red[0] / 28.f;
}

extern "C" void kernel_launch(void* const* d_in, const int* in_sizes, int n_in,
                              void* d_out, int out_size, void* d_ws, size_t ws_size,
                              hipStream_t stream) {
  const float* x = (const float*)d_in[0];
  const int* labels = (const int*)d_in[1];
  const int* idx_train = (const int*)d_in[2];
  const float* gat_W = (const float*)d_in[3];
  const float* gat_a1 = (const float*)d_in[4];
  const float* gat_a2 = (const float*)d_in[5];
  const float* gcnW[3] = {(const float*)d_in[6], (const float*)d_in[8], (const float*)d_in[10]};
  const float* gcnB[3] = {(const float*)d_in[7], (const float*)d_in[9], (const float*)d_in[11]};
  const float* pw1[3] = {(const float*)d_in[12], (const float*)d_in[15], (const float*)d_in[18]};
  const float* pw2[3] = {(const float*)d_in[13], (const float*)d_in[16], (const float*)d_in[19]};
  const float* pbb[3] = {(const float*)d_in[14], (const float*)d_in[17], (const float*)d_in[20]};
  const float* wih = (const float*)d_in[21];
  const float* whh = (const float*)d_in[22];
  const float* bih = (const float*)d_in[23];
  const float* bhh = (const float*)d_in[24];
  const float* c1W = (const float*)d_in[25]; const float* c1b = (const float*)d_in[26];
  const float* c2W = (const float*)d_in[27]; const float* c2b = (const float*)d_in[28];
  const float* c3W = (const float*)d_in[29]; const float* c3b = (const float*)d_in[30];
  const float* fc0W = (const float*)d_in[31]; const float* fc0b = (const float*)d_in[32];
  const float* bn0g = (const float*)d_in[33]; const float* bn0b = (const float*)d_in[34];
  const float* fc1W = (const float*)d_in[35]; const float* fc1b = (const float*)d_in[36];
  const float* aW1 = (const float*)d_in[37]; const float* ab1 = (const float*)d_in[38];
  const float* aW2 = (const float*)d_in[39]; const float* ab2 = (const float*)d_in[40];
  float* out = (float*)d_out;
  float* ws = (float*)d_ws;

  // ---- workspace layout (floats). Z region reused by 3 sequential phases. ----
  size_t off = 0;
  auto take = [&](size_t n) { size_t o = off; off += (n + 63) & ~(size_t)63; return o; };
  float* wa1   = ws + take(512);
  float* wa2   = ws + take(512);
  float* ha1   = ws + take(BB * CC);
  float* ha2   = ws + take(BB * CC);
  float* dinv  = ws + take(BB * 64);
  float* rbuf  = ws + take(BB * 256);
  float* xgru  = ws + take(BB * 128);
  float* xconv = ws + take(BB * 128);
  float* hm    = ws + take(BB * 256);
  float* hmn   = ws + take(BB * 256);
  float* zb    = ws + take(BB * 128);
  float* protos = ws + take(NC * 128);
  float* wihT  = ws + take(512 * 384);   // GRU phase; conv-weight Wt aliases after GRU
  float* whhT  = ws + take(128 * 384);
  float* Z     = ws + take(8568832);
  // GNN-phase aliases
  float* mA  = Z;
  float* mB  = Z + 1048576;
  float* xw  = Z + 2097152;
  float* gb  = Z + 4194304;
  float* gp1 = Z + 6291456;
  float* gp2 = Z + 7340032;
  // GRU-phase aliases
  float* gi = Z;
  float* ys = Z + 6291456;
  // conv-phase aliases (chunks of 64 samples)
  float* cv1 = Z;
  float* cv2 = Z + 4251648;
  float* wt1 = wihT;                 // 512*128 (dead after k_gru)
  float* wt2 = wt1 + 512 * 128;      // 640*128
  float* wt3 = wt2 + 640 * 128;      // 384*128

  hipMemsetAsync(rbuf, 0, BB * 256 * sizeof(float), stream);
  hipMemsetAsync(xconv, 0, BB * 128 * sizeof(float), stream);

  // ---- GAT adjacency ----
  k_wa<<<1, 512, 0, stream>>>(gat_W, gat_a1, gat_a2, wa1, wa2);
  k_ha<<<BB * CC / 4, 256, 0, stream>>>(x, wa1, wa2, ha1, ha2);
  k_softmask<<<BB * 64 / 4, 256, 0, stream>>>(ha1, ha2, mA);

  // ---- 3x (GCN + SAGPool) with jump-knowledge readout ----
  const int Ns[3] = {64, 32, 16};
  const int ks[3] = {32, 16, 8};
  const int Kin[3] = {512, 128, 128};
  const float* gins[3] = {x, gp1, gp2};
  float* mcur[3] = {mA, mB, mA};
  float* mnxt[3] = {mB, mA, nullptr};
  float* gps[3]  = {gp1, gp2, nullptr};
  for (int s = 0; s < 3; s++) {
    int N = Ns[s];
    k_dinv<<<(BB * N + 3) / 4, 256, 0, stream>>>(mcur[s], dinv, N);
    if (s == 0) {
      k_gemm<<<(BB * CC / 64) * (HH / 64), 256, 0, stream>>>(x, gcnW[0], xw, BB * CC, HH, LL);
    } else {
      k_xw<<<BB * N, 128, 0, stream>>>(gins[s], gcnW[s], xw, N, Kin[s]);
    }
    k_gcnagg<<<BB * N, 128, 0, stream>>>(xw, mcur[s], dinv, gcnB[s], gb, N);
    k_pool<<<BB, 256, 0, stream>>>(gb, mcur[s], pw1[s], pw2[s], pbb[s], N, ks[s],
                                   gps[s], mnxt[s], rbuf);
  }

  // ---- GRU branch: gi = x @ wihT via tiled GEMM, then register-resident recurrence ----
  k_tr<<<(384 * 512 + 255) / 256, 256, 0, stream>>>(wih, wihT, 384, 512);
  k_tr<<<(384 * 128 + 255) / 256, 256, 0, stream>>>(whh, whhT, 384, 128);
  k_gemm<<<(BB * CC / 64) * (G3 / 64), 256, 0, stream>>>(x, wihT, gi, BB * CC, G3, LL);
  k_gru<<<CC, 384, 0, stream>>>(gi, whhT, bhh, bih, ys);
  k_grumean<<<BB, 128, 0, stream>>>(ys, xgru);

  // ---- dilated conv branch (wihT/whhT regions are dead now; reuse for Wt) ----
  k_tr<<<(128 * 512 + 255) / 256, 256, 0, stream>>>(c1W, wt1, 128, 512);
  k_tr<<<(128 * 640 + 255) / 256, 256, 0, stream>>>(c2W, wt2, 128, 640);
  k_tr<<<(128 * 384 + 255) / 256, 256, 0, stream>>>(c3W, wt3, 128, 384);
  for (int bc = 0; bc < 4; bc++) {
    int b0 = bc * 64;
    k_conv<64, 8, 1, 7, 512, CL1, false><<<64 * 9, 256, 0, stream>>>(
        x + (size_t)b0 * CC * LL, wt1, c1b, cv1, b0);
    k_conv<128, 5, 2, 8, CL1, CL2, false><<<64 * 9, 256, 0, stream>>>(
        cv1, wt2, c2b, cv2, b0);
    k_conv<128, 3, 4, 8, CL2, CL3, true><<<64 * 9, 256, 0, stream>>>(
        cv2, wt3, c3b, xconv, b0);
  }

  // ---- mapping MLP + BN + attention prototypes + distances ----
  k_fc0<<<BB, 256, 0, stream>>>(xconv, xgru, rbuf, fc0W, fc0b, hm);
  k_bn<<<256, 256, 0, stream>>>(hm, bn0g, bn0b, hmn);
  k_fc1<<<BB, 128, 0, stream>>>(hmn, fc1W, fc1b, zb);
  k_att<<<NC, 256, 0, stream>>>(zb, labels, idx_train, in_sizes[2], aW1, ab1, aW2, ab2, protos);
  k_dist<<<BB, 128, 0, stream>>>(zb, protos, out);
  k_pdist<<<1, 64, 0, stream>>>(protos, out);
}

// Round 4
// 2597.325 us; speedup vs baseline: 3.9304x; 1.0041x over previous
//
#include <hip/hip_runtime.h>
#include <math.h>

#define BB 256   // batch
#define CC 64    // channels / graph nodes
#define LL 512   // series length
#define HH 128   // gcn hidden
#define G3 384   // 3*gru_dim
#define NC 8
#define AT 64
#define CL1 519
#define CL2 527
#define CL3 535
#define THRESH 0.02f

typedef _Float16 h2 __attribute__((ext_vector_type(2)));

__device__ inline float warp_red_sum(float v) {
  #pragma unroll
  for (int o = 32; o > 0; o >>= 1) v += __shfl_down(v, o, 64);
  return v;
}
__device__ inline float warp_allred_max(float v) {
  #pragma unroll
  for (int o = 32; o > 0; o >>= 1) v = fmaxf(v, __shfl_xor(v, o, 64));
  return v;
}
__device__ inline float warp_allred_sum(float v) {
  #pragma unroll
  for (int o = 32; o > 0; o >>= 1) v += __shfl_xor(v, o, 64);
  return v;
}

__device__ inline float fdot2f(h2 a, h2 b, float c) {
#if __has_builtin(__builtin_amdgcn_fdot2)
  return __builtin_amdgcn_fdot2(a, b, c, false);
#else
  float r;
  asm volatile("v_dot2_f32_f16 %0, %1, %2, %3" : "=v"(r) : "v"(a), "v"(b), "v"(c));
  return r;
#endif
}
__device__ inline h2 asH2(float f) { union { float f; h2 h; } u; u.f = f; return u.h; }

// wa = gat_W @ a  (512-vector); avoids the full x@gat_W GEMM since (x@W)@a = x@(W@a)
__global__ void k_wa(const float* __restrict__ gatW, const float* __restrict__ a1,
                     const float* __restrict__ a2, float* wa1, float* wa2) {
  int l = threadIdx.x;
  const float* row = gatW + l * LL;
  float s1 = 0.f, s2 = 0.f;
  for (int k = 0; k < LL; k++) { float w = row[k]; s1 += w * a1[k]; s2 += w * a2[k]; }
  wa1[l] = s1; wa2[l] = s2;
}

// ha1[b,c] = x[b,c,:].wa1 ; ha2 likewise. one wave per row.
__global__ void k_ha(const float* __restrict__ x, const float* __restrict__ wa1,
                     const float* __restrict__ wa2, float* ha1, float* ha2) {
  int wid = threadIdx.x >> 6, lane = threadIdx.x & 63;
  int row = blockIdx.x * 4 + wid;
  const float* xr = x + (size_t)row * LL;
  float s1 = 0.f, s2 = 0.f;
  for (int q = lane; q < LL; q += 64) { float v = xr[q]; s1 += v * wa1[q]; s2 += v * wa2[q]; }
  s1 = warp_red_sum(s1); s2 = warp_red_sum(s2);
  if (lane == 0) { ha1[row] = s1; ha2[row] = s2; }
}

// per (b,i): e_j = lrelu(ha1_i + ha2_j, 0.2); softmax over j; mask = A > 0.02
__global__ void k_softmask(const float* __restrict__ ha1, const float* __restrict__ ha2,
                           float* __restrict__ mask) {
  int wid = threadIdx.x >> 6, lane = threadIdx.x & 63;
  int row = blockIdx.x * 4 + wid;       // row = b*64+i
  int b = row >> 6;
  float e = ha1[row] + ha2[b * 64 + lane];
  e = e < 0.f ? 0.2f * e : e;
  float mx = warp_allred_max(e);
  float ex = expf(e - mx);
  float sm = warp_allred_sum(ex);
  float A = ex / sm;
  mask[(size_t)row * 64 + lane] = (A > THRESH) ? 1.0f : 0.0f;
}

// dinv[b,i] = 1/sqrt(1 + sum_j mask[b,i,j])   (A = m + I degree)
__global__ void k_dinv(const float* __restrict__ mask, float* dinv, int N) {
  int wid = threadIdx.x >> 6, lane = threadIdx.x & 63;
  int row = blockIdx.x * 4 + wid;       // b*N+i
  if (row >= BB * N) return;
  float v = (lane < N) ? mask[(size_t)row * N + lane] : 0.f;
  float s = warp_allred_sum(v);
  if (lane == 0) dinv[row] = 1.0f / sqrtf(s + 1.0f);
}

// generic tiled GEMM: C[M,N] = A[M,K] @ B[K,N], all row-major.
// BM=64,BN=64,BK=32, 256 threads, 4x4 microtile. Requires M%64==0, N%64==0, K%32==0.
__global__ __launch_bounds__(256) void k_gemm(const float* __restrict__ A,
                                              const float* __restrict__ B,
                                              float* __restrict__ C,
                                              int M, int N, int K) {
  __shared__ float sa[32][64];   // [k][m]
  __shared__ float sb[32][64];   // [k][n]
  int nbn = N >> 6;
  int bm = blockIdx.x / nbn, bn = blockIdx.x % nbn;
  int m0 = bm * 64, n0 = bn * 64;
  int tx = threadIdx.x & 15, ty = threadIdx.x >> 4;   // 16x16
  float acc[4][4];
  #pragma unroll
  for (int i = 0; i < 4; i++)
    #pragma unroll
    for (int j = 0; j < 4; j++) acc[i][j] = 0.f;
  int arow = threadIdx.x >> 2;            // 0..63
  int acol = (threadIdx.x & 3) * 8;       // 0,8,16,24
  int brow = threadIdx.x >> 4;            // 0..15 (x2 rows)
  int bcol = (threadIdx.x & 15) * 4;
  for (int k0 = 0; k0 < K; k0 += 32) {
    float4 av0 = *(const float4*)&A[(size_t)(m0 + arow) * K + k0 + acol];
    float4 av1 = *(const float4*)&A[(size_t)(m0 + arow) * K + k0 + acol + 4];
    float4 bv0 = *(const float4*)&B[(size_t)(k0 + brow) * N + n0 + bcol];
    float4 bv1 = *(const float4*)&B[(size_t)(k0 + brow + 16) * N + n0 + bcol];
    __syncthreads();
    sa[acol + 0][arow] = av0.x; sa[acol + 1][arow] = av0.y;
    sa[acol + 2][arow] = av0.z; sa[acol + 3][arow] = av0.w;
    sa[acol + 4][arow] = av1.x; sa[acol + 5][arow] = av1.y;
    sa[acol + 6][arow] = av1.z; sa[acol + 7][arow] = av1.w;
    *(float4*)&sb[brow][bcol] = bv0;
    *(float4*)&sb[brow + 16][bcol] = bv1;
    __syncthreads();
    #pragma unroll
    for (int kk = 0; kk < 32; kk++) {
      float4 a4 = *(const float4*)&sa[kk][ty * 4];
      float4 b4 = *(const float4*)&sb[kk][tx * 4];
      acc[0][0] += a4.x * b4.x; acc[0][1] += a4.x * b4.y; acc[0][2] += a4.x * b4.z; acc[0][3] += a4.x * b4.w;
      acc[1][0] += a4.y * b4.x; acc[1][1] += a4.y * b4.y; acc[1][2] += a4.y * b4.z; acc[1][3] += a4.y * b4.w;
      acc[2][0] += a4.z * b4.x; acc[2][1] += a4.z * b4.y; acc[2][2] += a4.z * b4.z; acc[2][3] += a4.z * b4.w;
      acc[3][0] += a4.w * b4.x; acc[3][1] += a4.w * b4.y; acc[3][2] += a4.w * b4.z; acc[3][3] += a4.w * b4.w;
    }
  }
  #pragma unroll
  for (int i = 0; i < 4; i++) {
    float4 v = make_float4(acc[i][0], acc[i][1], acc[i][2], acc[i][3]);
    *(float4*)&C[(size_t)(m0 + ty * 4 + i) * N + n0 + tx * 4] = v;
  }
}

// xw[b,i,f] = sum_k gin[b,i,k] * W[k,f]   (HH=128 output) — small stages (K=128)
__global__ void k_xw(const float* __restrict__ gin, const float* __restrict__ W,
                     float* __restrict__ out, int N, int K) {
  __shared__ float xs[512];
  int b = blockIdx.x / N, i = blockIdx.x % N;
  const float* grow = gin + (size_t)(b * N + i) * K;
  for (int k = threadIdx.x; k < K; k += 128) xs[k] = grow[k];
  __syncthreads();
  int f = threadIdx.x;
  float a0 = 0.f, a1 = 0.f, a2 = 0.f, a3 = 0.f;
  for (int k = 0; k < K; k += 4) {
    a0 += xs[k]     * W[(k)     * HH + f];
    a1 += xs[k + 1] * W[(k + 1) * HH + f];
    a2 += xs[k + 2] * W[(k + 2) * HH + f];
    a3 += xs[k + 3] * W[(k + 3) * HH + f];
  }
  out[(size_t)(b * N + i) * HH + f] = (a0 + a1) + (a2 + a3);
}

// g[b,i,f] = relu(dinv_i*(dinv_i*xw_if + sum_j m_ij*dinv_j*xw_jf) + bias_f)
__global__ void k_gcnagg(const float* __restrict__ xw, const float* __restrict__ mask,
                         const float* __restrict__ dinv, const float* __restrict__ bias,
                         float* __restrict__ gout, int N) {
  __shared__ float mrow[64], dv[64];
  int b = blockIdx.x / N, i = blockIdx.x % N;
  if (threadIdx.x < N) {
    mrow[threadIdx.x] = mask[(size_t)(b * N + i) * N + threadIdx.x];
    dv[threadIdx.x] = dinv[b * N + threadIdx.x];
  }
  __syncthreads();
  int f = threadIdx.x;
  float di = dv[i];
  float acc = di * xw[(size_t)(b * N + i) * HH + f];
  for (int j = 0; j < N; j++) acc += mrow[j] * dv[j] * xw[(size_t)(b * N + j) * HH + f];
  float y = di * acc + bias[f];
  gout[(size_t)(b * N + i) * HH + f] = y > 0.f ? y : 0.f;
}

// fused SAGPool: score -> top-k (wave-parallel argmax, jax tie-break lowest index)
//                -> gather + gate -> readout accum
__global__ void k_pool(const float* __restrict__ g, const float* __restrict__ mask,
                       const float* __restrict__ w1, const float* __restrict__ w2,
                       const float* __restrict__ pb, int N, int kk,
                       float* gp, float* mnext, float* __restrict__ r) {
  __shared__ float d1[64], d2[64], sv[64], vals[32], tvs[32];
  __shared__ int idxs[32];
  int b = blockIdx.x, tid = threadIdx.x;
  if (tid < N) {
    const float* gr = g + (size_t)(b * N + tid) * HH;
    float a = 0.f, c = 0.f;
    for (int d = 0; d < HH; d++) { float v = gr[d]; a += v * w1[d]; c += v * w2[d]; }
    d1[tid] = a; d2[tid] = c;
  }
  __syncthreads();
  if (tid < N) {
    const float* mr = mask + (size_t)(b * N + tid) * N;
    float s = d1[tid] + pb[0];
    for (int j = 0; j < N; j++) s += mr[j] * d2[j];
    sv[tid] = s;
  }
  __syncthreads();
  if (tid < 64) {
    float myv = (tid < N) ? sv[tid] : -3.4e38f;
    int alive = (tid < N) ? 1 : 0;
    for (int t = 0; t < kk; t++) {
      float cv = alive ? myv : -3.4e38f;
      int ci = tid;
      #pragma unroll
      for (int o = 32; o > 0; o >>= 1) {
        float ov = __shfl_xor(cv, o, 64);
        int oi = __shfl_xor(ci, o, 64);
        if (ov > cv || (ov == cv && oi < ci)) { cv = ov; ci = oi; }
      }
      if (tid == ci) alive = 0;
      if (tid == 0) { idxs[t] = ci; vals[t] = cv; }
    }
  }
  __syncthreads();
  if (tid < kk) tvs[tid] = tanhf(vals[tid]);
  __syncthreads();
  if (tid < HH) {
    float mx = -3.4e38f, sm = 0.f;
    for (int t = 0; t < kk; t++) {
      float v = g[(size_t)(b * N + idxs[t]) * HH + tid] * tvs[t];
      if (gp) gp[(size_t)(b * kk + t) * HH + tid] = v;
      mx = fmaxf(mx, v); sm += v;
    }
    r[b * 256 + tid] += mx;
    r[b * 256 + 128 + tid] += sm / (float)kk;
  }
  if (mnext) {
    for (int q = tid; q < kk * kk; q += blockDim.x) {
      int t = q / kk, u = q % kk;
      mnext[(size_t)(b * kk + t) * kk + u] = mask[(size_t)(b * N + idxs[t]) * N + idxs[u]];
    }
  }
}

__global__ void k_tr(const float* __restrict__ in, float* __restrict__ out, int R, int Lc) {
  int idx = blockIdx.x * 256 + threadIdx.x;
  if (idx >= R * Lc) return;
  int j = idx / Lc, l = idx % Lc;
  out[l * R + j] = in[idx];
}

// GRU recurrence: one workgroup per channel; whh column in packed-f16 VGPRs,
// h broadcast from LDS as f16 (16 ds_read_b128/wave/step), v_dot2_f32_f16 matvec.
__global__ __launch_bounds__(384) void k_gru(const float* __restrict__ gi,
                                             const float* __restrict__ whhT,
                                             const float* __restrict__ bhh,
                                             const float* __restrict__ bih,
                                             float* __restrict__ ys) {
  __shared__ _Float16 hh[128];
  __shared__ float agh[384], agi[384];
  int c = blockIdx.x, j = threadIdx.x;
  h2 w[64];
  #pragma unroll
  for (int k = 0; k < 64; k++) {
    h2 t;
    t.x = (_Float16)whhT[(2 * k) * G3 + j];
    t.y = (_Float16)whhT[(2 * k + 1) * G3 + j];
    w[k] = t;
  }
  float bh = bhh[j], bi = bih[j];
  float hprev = 0.f;
  if (j < 128) hh[j] = (_Float16)0.f;
  __syncthreads();
  for (int b = 0; b < BB; b++) {
    float gv = gi[(size_t)(b * CC + c) * G3 + j] + bi;
    float a0 = 0.f, a1 = 0.f, a2 = 0.f, a3 = 0.f;
    #pragma unroll
    for (int q = 0; q < 16; q++) {
      float4 hv = *(const float4*)&hh[q * 8];
      a0 = fdot2f(w[q * 4 + 0], asH2(hv.x), a0);
      a1 = fdot2f(w[q * 4 + 1], asH2(hv.y), a1);
      a2 = fdot2f(w[q * 4 + 2], asH2(hv.z), a2);
      a3 = fdot2f(w[q * 4 + 3], asH2(hv.w), a3);
    }
    agh[j] = (a0 + a1) + (a2 + a3) + bh;
    agi[j] = gv;
    __syncthreads();
    if (j < 128) {
      float rg = 1.f / (1.f + expf(-(agi[j] + agh[j])));
      float zg = 1.f / (1.f + expf(-(agi[128 + j] + agh[128 + j])));
      float ng = tanhf(agi[256 + j] + rg * agh[256 + j]);
      float hn = (1.f - zg) * ng + zg * hprev;
      ys[(size_t)(b * CC + c) * 128 + j] = hn;
      hprev = hn;
      hh[j] = (_Float16)hn;
    }
    __syncthreads();
  }
}

__global__ void k_grumean(const float* __restrict__ ys, float* __restrict__ xgru) {
  int b = blockIdx.x, u = threadIdx.x;
  float acc = 0.f;
  for (int c = 0; c < CC; c++) acc += ys[(size_t)(b * CC + c) * 128 + u];
  xgru[b * 128 + u] = acc / 64.f;
}

// ---------------- tiled conv: block = (sample, 64-pos tile), 128 oc ----------------
// ci-major chunks: per input channel, one aligned 12-float register window covers
// all taps (off = t*DIL-PAD+8 in [0,11]); weights double-buffered in ci-chunks.
template<int CIN, int KS, int DIL, int PAD, int LIN, int LOUT, bool DOMEAN, int CI_CHUNK>
__global__ __launch_bounds__(256) void k_conv(const float* __restrict__ in,
                                              const float* __restrict__ Wt,
                                              const float* __restrict__ bias,
                                              float* __restrict__ out, int b0) {
  constexpr int K_CHUNK = CI_CHUNK * KS;
  constexpr int NCH = CIN / CI_CHUNK;
  constexpr int NF4 = K_CHUNK * 32;           // float4s per weight chunk
  constexpr int PFN = (NF4 + 255) / 256;
  constexpr int TW = 72;                      // 64 pos + 8 margin
  constexpr int NT = (LOUT + 63) / 64;
  __shared__ float si[CIN][TW];
  __shared__ float sw[2][K_CHUNK][128];
  int nb = blockIdx.x / NT;
  int p0 = (blockIdx.x % NT) * 64;
  const float* inb = in + (size_t)nb * CIN * LIN;
  float4 pf[PFN];
  auto prefetch = [&](int ch) {
    const float4* src = (const float4*)(Wt + (size_t)ch * K_CHUNK * 128);
    #pragma unroll
    for (int i = 0; i < PFN; i++) {
      int idx = threadIdx.x + i * 256;
      if (idx < NF4) pf[i] = src[idx];
    }
  };
  auto commit = [&](int buf) {
    #pragma unroll
    for (int i = 0; i < PFN; i++) {
      int idx = threadIdx.x + i * 256;
      if (idx < NF4) ((float4*)sw[buf])[idx] = pf[i];
    }
  };
  prefetch(0);
  for (int q = threadIdx.x; q < CIN * TW; q += 256) {
    int ci = q / TW, col = q % TW;
    int gp = p0 - 8 + col;
    si[ci][col] = (gp >= 0 && gp < LIN) ? inb[ci * LIN + gp] : 0.f;
  }
  commit(0);
  __syncthreads();
  int posg = threadIdx.x & 15;           // pos = p0 + posg*4 + j
  int ocg = threadIdx.x >> 4;            // oc  = ocg*8 + o
  float acc[8][4];
  #pragma unroll
  for (int o = 0; o < 8; o++)
    #pragma unroll
    for (int j = 0; j < 4; j++) acc[o][j] = 0.f;
  for (int ch = 0; ch < NCH; ch++) {
    if (ch + 1 < NCH) prefetch(ch + 1);
    int buf = ch & 1;
    #pragma unroll
    for (int cl = 0; cl < CI_CHUNK; cl++) {
      int ci = ch * CI_CHUNK + cl;
      float w12[12];
      *(float4*)&w12[0] = *(const float4*)&si[ci][posg * 4];
      *(float4*)&w12[4] = *(const float4*)&si[ci][posg * 4 + 4];
      *(float4*)&w12[8] = *(const float4*)&si[ci][posg * 4 + 8];
      #pragma unroll
      for (int t = 0; t < KS; t++) {
        int off = t * DIL - PAD + 8;     // compile-time after unroll, in [0,8]
        const float* wp = &sw[buf][cl * KS + t][ocg * 8];
        float i0 = w12[off], i1 = w12[off + 1], i2 = w12[off + 2], i3 = w12[off + 3];
        #pragma unroll
        for (int o = 0; o < 8; o++) {
          float w = wp[o];
          acc[o][0] += w * i0; acc[o][1] += w * i1;
          acc[o][2] += w * i2; acc[o][3] += w * i3;
        }
      }
    }
    __syncthreads();
    if (ch + 1 < NCH) {
      commit(buf ^ 1);
      __syncthreads();
    }
  }
  if constexpr (DOMEAN) {
    #pragma unroll
    for (int o = 0; o < 8; o++) {
      int oc = ocg * 8 + o;
      float bz = bias[oc];
      float s = 0.f;
      #pragma unroll
      for (int j = 0; j < 4; j++) {
        int p = p0 + posg * 4 + j;
        if (p < LOUT) { float y = acc[o][j] + bz; s += y > 0.f ? y : 0.f; }
      }
      #pragma unroll
      for (int d = 8; d > 0; d >>= 1) s += __shfl_down(s, d, 64);
      if (posg == 0) atomicAdd(&out[(size_t)(b0 + nb) * 128 + oc], s);
    }
  } else {
    #pragma unroll
    for (int o = 0; o < 8; o++) {
      int oc = ocg * 8 + o;
      float bz = bias[oc];
      #pragma unroll
      for (int j = 0; j < 4; j++) {
        int p = p0 + posg * 4 + j;
        if (p < LOUT) {
          float y = acc[o][j] + bz;
          out[((size_t)nb * 128 + oc) * LOUT + p] = y > 0.f ? y : 0.f;
        }
      }
    }
  }
}

__global__ void k_fc0(const float* __restrict__ xconv, const float* __restrict__ xgru,
                      const float* __restrict__ r, const float* __restrict__ W,
                      const float* __restrict__ bias, float* __restrict__ hm) {
  __shared__ float feat[512];
  int b = blockIdx.x, t = threadIdx.x;
  if (t < 128) { feat[t] = xconv[b * 128 + t] * (1.f / (float)CL3); feat[128 + t] = xgru[b * 128 + t]; }
  feat[256 + t] = r[b * 256 + t];
  __syncthreads();
  float acc = bias[t];
  for (int k = 0; k < 512; k++) acc += feat[k] * W[k * 256 + t];
  hm[b * 256 + t] = acc;
}

// batchnorm over batch axis (train stats, two-pass) + leaky_relu(0.01)
__global__ void k_bn(const float* __restrict__ hm, const float* __restrict__ gamma,
                     const float* __restrict__ beta, float* __restrict__ out) {
  __shared__ float red[256];
  int n = blockIdx.x, t = threadIdx.x;
  float v = hm[t * 256 + n];
  red[t] = v; __syncthreads();
  for (int s = 128; s > 0; s >>= 1) { if (t < s) red[t] += red[t + s]; __syncthreads(); }
  float mean = red[0] / 256.f; __syncthreads();
  float dv = v - mean;
  red[t] = dv * dv; __syncthreads();
  for (int s = 128; s > 0; s >>= 1) { if (t < s) red[t] += red[t + s]; __syncthreads(); }
  float var = red[0] / 256.f;
  float y = gamma[n] * dv * (1.f / sqrtf(var + 1e-5f)) + beta[n];
  out[t * 256 + n] = y < 0.f ? 0.01f * y : y;
}

__global__ void k_fc1(const float* __restrict__ hmn, const float* __restrict__ W,
                      const float* __restrict__ bias, float* __restrict__ z) {
  __shared__ float hs[256];
  int b = blockIdx.x, t = threadIdx.x;
  hs[t] = hmn[b * 256 + t]; hs[128 + t] = hmn[b * 256 + 128 + t];
  __syncthreads();
  float acc = bias[t];
  for (int k = 0; k < 256; k++) acc += hs[k] * W[k * 128 + t];
  z[b * 128 + t] = acc;
}

// per-class attention logits + masked softmax over samples + prototype
__global__ void k_att(const float* __restrict__ z, const int* __restrict__ labels,
                      const int* __restrict__ idx_train, int ntrain,
                      const float* __restrict__ W1, const float* __restrict__ b1,
                      const float* __restrict__ W2, const float* __restrict__ b2,
                      float* __restrict__ protos) {
  __shared__ float wv[256], red[256];
  __shared__ int trainm[256];
  int c = blockIdx.x, n = threadIdx.x;
  trainm[n] = 0; __syncthreads();
  if (n < ntrain) trainm[idx_train[n]] = 1;
  __syncthreads();
  const float* zr = z + n * 128;
  float acc = b2[c];
  for (int a = 0; a < AT; a++) {
    float s = b1[c * AT + a];
    const float* w1c = W1 + (size_t)c * 128 * AT + a;
    for (int d = 0; d < 128; d++) s += zr[d] * w1c[d * AT];
    acc += tanhf(s) * W2[c * AT + a];
  }
  bool keep = trainm[n] && (labels[n] == c);
  float ml = keep ? acc : -1e30f;
  red[n] = ml; __syncthreads();
  for (int s = 128; s > 0; s >>= 1) { if (n < s) red[n] = fmaxf(red[n], red[n + s]); __syncthreads(); }
  float mx = red[0]; __syncthreads();
  float e = expf(ml - mx);
  wv[n] = e; red[n] = e; __syncthreads();
  for (int s = 128; s > 0; s >>= 1) { if (n < s) red[n] += red[n + s]; __syncthreads(); }
  float ssum = red[0]; __syncthreads();
  wv[n] = wv[n] / ssum;
  __syncthreads();
  if (n < 128) {
    float p = 0.f;
    for (int q = 0; q < 256; q++) p += wv[q] * z[q * 128 + n];
    protos[c * 128 + n] = p;
  }
}

__global__ void k_dist(const float* __restrict__ z, const float* __restrict__ protos,
                       float* __restrict__ dout) {
  __shared__ float zs[128], red[128];
  int n = blockIdx.x, t = threadIdx.x;
  zs[t] = z[n * 128 + t];
  red[t] = zs[t] * zs[t]; __syncthreads();
  for (int s = 64; s > 0; s >>= 1) { if (t < s) red[t] += red[t + s]; __syncthreads(); }
  float z2 = red[0];
  if (t < NC) {
    float dot = 0.f, p2 = 0.f;
    const float* pr = protos + t * 128;
    for (int d = 0; d < 128; d++) { float pv = pr[d]; dot += pv * zs[d]; p2 += pv * pv; }
    float d2 = fmaxf(z2 + p2 - 2.f * dot, 1e-12f);
    dout[n * NC + t] = expf(-0.5f * sqrtf(d2));
  }
}

__global__ void k_pdist(const float* __restrict__ protos, float* __restrict__ dout) {
  __shared__ float red[64];
  int t = threadIdx.x, i = t / 8, j = t % 8;
  float dot = 0.f, p2i = 0.f, p2j = 0.f;
  for (int d = 0; d < 128; d++) {
    float a = protos[i * 128 + d], b = protos[j * 128 + d];
    dot += a * b; p2i += a * a; p2j += b * b;
  }
  float d2 = fmaxf(p2i + p2j - 2.f * dot, 1e-12f);
  red[t] = expf(-0.5f * sqrtf(d2));
  __syncthreads();
  for (int s = 32; s > 0; s >>= 1) { if (t < s) red[t] += red[t + s]; __syncthreads(); }
  if (t == 0) dout[2048] = red[0] / 28.f;
}

extern "C" void kernel_launch(void* const* d_in, const int* in_sizes, int n_in,
                              void* d_out, int out_size, void* d_ws, size_t ws_size,
                              hipStream_t stream) {
  const float* x = (const float*)d_in[0];
  const int* labels = (const int*)d_in[1];
  const int* idx_train = (const int*)d_in[2];
  const float* gat_W = (const float*)d_in[3];
  const float* gat_a1 = (const float*)d_in[4];
  const float* gat_a2 = (const float*)d_in[5];
  const float* gcnW[3] = {(const float*)d_in[6], (const float*)d_in[8], (const float*)d_in[10]};
  const float* gcnB[3] = {(const float*)d_in[7], (const float*)d_in[9], (const float*)d_in[11]};
  const float* pw1[3] = {(const float*)d_in[12], (const float*)d_in[15], (const float*)d_in[18]};
  const float* pw2[3] = {(const float*)d_in[13], (const float*)d_in[16], (const float*)d_in[19]};
  const float* pbb[3] = {(const float*)d_in[14], (const float*)d_in[17], (const float*)d_in[20]};
  const float* wih = (const float*)d_in[21];
  const float* whh = (const float*)d_in[22];
  const float* bih = (const float*)d_in[23];
  const float* bhh = (const float*)d_in[24];
  const float* c1W = (const float*)d_in[25]; const float* c1b = (const float*)d_in[26];
  const float* c2W = (const float*)d_in[27]; const float* c2b = (const float*)d_in[28];
  const float* c3W = (const float*)d_in[29]; const float* c3b = (const float*)d_in[30];
  const float* fc0W = (const float*)d_in[31]; const float* fc0b = (const float*)d_in[32];
  const float* bn0g = (const float*)d_in[33]; const float* bn0b = (const float*)d_in[34];
  const float* fc1W = (const float*)d_in[35]; const float* fc1b = (const float*)d_in[36];
  const float* aW1 = (const float*)d_in[37]; const float* ab1 = (const float*)d_in[38];
  const float* aW2 = (const float*)d_in[39]; const float* ab2 = (const float*)d_in[40];
  float* out = (float*)d_out;
  float* ws = (float*)d_ws;

  // ---- workspace layout (floats). Z region reused by 3 sequential phases. ----
  size_t off = 0;
  auto take = [&](size_t n) { size_t o = off; off += (n + 63) & ~(size_t)63; return o; };
  float* wa1   = ws + take(512);
  float* wa2   = ws + take(512);
  float* ha1   = ws + take(BB * CC);
  float* ha2   = ws + take(BB * CC);
  float* dinv  = ws + take(BB * 64);
  float* rbuf  = ws + take(BB * 256);
  float* xgru  = ws + take(BB * 128);
  float* xconv = ws + take(BB * 128);
  float* hm    = ws + take(BB * 256);
  float* hmn   = ws + take(BB * 256);
  float* zb    = ws + take(BB * 128);
  float* protos = ws + take(NC * 128);
  float* wihT  = ws + take(512 * 384);   // GRU phase; conv-weight Wt aliases after GRU
  float* whhT  = ws + take(128 * 384);
  float* Z     = ws + take(8568832);
  // GNN-phase aliases
  float* mA  = Z;
  float* mB  = Z + 1048576;
  float* xw  = Z + 2097152;
  float* gb  = Z + 4194304;
  float* gp1 = Z + 6291456;
  float* gp2 = Z + 7340032;
  // GRU-phase aliases
  float* gi = Z;
  float* ys = Z + 6291456;
  // conv-phase aliases (chunks of 64 samples)
  float* cv1 = Z;
  float* cv2 = Z + 4251648;
  float* wt1 = wihT;                 // 512*128 (dead after k_gru)
  float* wt2 = wt1 + 512 * 128;      // 640*128
  float* wt3 = wt2 + 640 * 128;      // 384*128

  hipMemsetAsync(rbuf, 0, BB * 256 * sizeof(float), stream);
  hipMemsetAsync(xconv, 0, BB * 128 * sizeof(float), stream);

  // ---- GAT adjacency ----
  k_wa<<<1, 512, 0, stream>>>(gat_W, gat_a1, gat_a2, wa1, wa2);
  k_ha<<<BB * CC / 4, 256, 0, stream>>>(x, wa1, wa2, ha1, ha2);
  k_softmask<<<BB * 64 / 4, 256, 0, stream>>>(ha1, ha2, mA);

  // ---- 3x (GCN + SAGPool) with jump-knowledge readout ----
  const int Ns[3] = {64, 32, 16};
  const int ks[3] = {32, 16, 8};
  const float* gins[3] = {x, gp1, gp2};
  float* mcur[3] = {mA, mB, mA};
  float* mnxt[3] = {mB, mA, nullptr};
  float* gps[3]  = {gp1, gp2, nullptr};
  for (int s = 0; s < 3; s++) {
    int N = Ns[s];
    k_dinv<<<(BB * N + 3) / 4, 256, 0, stream>>>(mcur[s], dinv, N);
    if (s == 0) {
      k_gemm<<<(BB * CC / 64) * (HH / 64), 256, 0, stream>>>(x, gcnW[0], xw, BB * CC, HH, LL);
    } else {
      k_xw<<<BB * N, 128, 0, stream>>>(gins[s], gcnW[s], xw, N, 128);
    }
    k_gcnagg<<<BB * N, 128, 0, stream>>>(xw, mcur[s], dinv, gcnB[s], gb, N);
    k_pool<<<BB, 256, 0, stream>>>(gb, mcur[s], pw1[s], pw2[s], pbb[s], N, ks[s],
                                   gps[s], mnxt[s], rbuf);
  }

  // ---- GRU branch: gi = x @ wihT via tiled GEMM, then f16-dot2 recurrence ----
  k_tr<<<(384 * 512 + 255) / 256, 256, 0, stream>>>(wih, wihT, 384, 512);
  k_tr<<<(384 * 128 + 255) / 256, 256, 0, stream>>>(whh, whhT, 384, 128);
  k_gemm<<<(BB * CC / 64) * (G3 / 64), 256, 0, stream>>>(x, wihT, gi, BB * CC, G3, LL);
  k_gru<<<CC, 384, 0, stream>>>(gi, whhT, bhh, bih, ys);
  k_grumean<<<BB, 128, 0, stream>>>(ys, xgru);

  // ---- dilated conv branch (wihT/whhT regions are dead now; reuse for Wt) ----
  k_tr<<<(128 * 512 + 255) / 256, 256, 0, stream>>>(c1W, wt1, 128, 512);
  k_tr<<<(128 * 640 + 255) / 256, 256, 0, stream>>>(c2W, wt2, 128, 640);
  k_tr<<<(128 * 384 + 255) / 256, 256, 0, stream>>>(c3W, wt3, 128, 384);
  for (int bc = 0; bc < 4; bc++) {
    int b0 = bc * 64;
    k_conv<64, 8, 1, 7, 512, CL1, false, 2><<<64 * 9, 256, 0, stream>>>(
        x + (size_t)b0 * CC * LL, wt1, c1b, cv1, b0);
    k_conv<128, 5, 2, 8, CL1, CL2, false, 4><<<64 * 9, 256, 0, stream>>>(
        cv1, wt2, c2b, cv2, b0);
    k_conv<128, 3, 4, 8, CL2, CL3, true, 4><<<64 * 9, 256, 0, stream>>>(
        cv2, wt3, c3b, xconv, b0);
  }

  // ---- mapping MLP + BN + attention prototypes + distances ----
  k_fc0<<<BB, 256, 0, stream>>>(xconv, xgru, rbuf, fc0W, fc0b, hm);
  k_bn<<<256, 256, 0, stream>>>(hm, bn0g, bn0b, hmn);
  k_fc1<<<BB, 128, 0, stream>>>(hmn, fc1W, fc1b, zb);
  k_att<<<NC, 256, 0, stream>>>(zb, labels, idx_train, in_sizes[2], aW1, ab1, aW2, ab2, protos);
  k_dist<<<BB, 128, 0, stream>>>(zb, protos, out);
  k_pdist<<<1, 64, 0, stream>>>(protos, out);
}

// Round 5
// 1727.176 us; speedup vs baseline: 5.9105x; 1.5038x over previous
//
#include <hip/hip_runtime.h>
#include <math.h>

#define BB 256   // batch
#define CC 64    // channels / graph nodes
#define LL 512   // series length
#define HH 128   // gcn hidden
#define G3 384   // 3*gru_dim
#define NC 8
#define AT 64
#define CL1 519
#define CL2 527
#define CL3 535
#define THRESH 0.02f

typedef _Float16 h2 __attribute__((ext_vector_type(2)));
union HU { unsigned int u; h2 h; float f; };

__device__ inline float warp_red_sum(float v) {
  #pragma unroll
  for (int o = 32; o > 0; o >>= 1) v += __shfl_down(v, o, 64);
  return v;
}
__device__ inline float warp_allred_max(float v) {
  #pragma unroll
  for (int o = 32; o > 0; o >>= 1) v = fmaxf(v, __shfl_xor(v, o, 64));
  return v;
}
__device__ inline float warp_allred_sum(float v) {
  #pragma unroll
  for (int o = 32; o > 0; o >>= 1) v += __shfl_xor(v, o, 64);
  return v;
}

__device__ inline float fdot2f(h2 a, h2 b, float c) {
#if __has_builtin(__builtin_amdgcn_fdot2)
  return __builtin_amdgcn_fdot2(a, b, c, false);
#else
  float r;
  asm volatile("v_dot2_f32_f16 %0, %1, %2, %3" : "=v"(r) : "v"(a), "v"(b), "v"(c));
  return r;
#endif
}
__device__ inline h2 asH2(float f) { HU u; u.f = f; return u.h; }
__device__ inline h2 uH2(unsigned int x) { HU u; u.u = x; return u.h; }
__device__ inline unsigned int packh(float a, float b) {
  HU u; h2 t; t.x = (_Float16)a; t.y = (_Float16)b; u.h = t; return u.u;
}

// wa = gat_W @ a  (512-vector)
__global__ void k_wa(const float* __restrict__ gatW, const float* __restrict__ a1,
                     const float* __restrict__ a2, float* wa1, float* wa2) {
  int l = blockIdx.x * 64 + threadIdx.x;
  const float* row = gatW + l * LL;
  float s1 = 0.f, s2 = 0.f;
  for (int k = 0; k < LL; k++) { float w = row[k]; s1 += w * a1[k]; s2 += w * a2[k]; }
  wa1[l] = s1; wa2[l] = s2;
}

// ha1[b,c] = x[b,c,:].wa1 ; ha2 likewise. one wave per row.
__global__ void k_ha(const float* __restrict__ x, const float* __restrict__ wa1,
                     const float* __restrict__ wa2, float* ha1, float* ha2) {
  int wid = threadIdx.x >> 6, lane = threadIdx.x & 63;
  int row = blockIdx.x * 4 + wid;
  const float* xr = x + (size_t)row * LL;
  float s1 = 0.f, s2 = 0.f;
  for (int q = lane; q < LL; q += 64) { float v = xr[q]; s1 += v * wa1[q]; s2 += v * wa2[q]; }
  s1 = warp_red_sum(s1); s2 = warp_red_sum(s2);
  if (lane == 0) { ha1[row] = s1; ha2[row] = s2; }
}

__global__ void k_softmask(const float* __restrict__ ha1, const float* __restrict__ ha2,
                           float* __restrict__ mask) {
  int wid = threadIdx.x >> 6, lane = threadIdx.x & 63;
  int row = blockIdx.x * 4 + wid;       // row = b*64+i
  int b = row >> 6;
  float e = ha1[row] + ha2[b * 64 + lane];
  e = e < 0.f ? 0.2f * e : e;
  float mx = warp_allred_max(e);
  float ex = expf(e - mx);
  float sm = warp_allred_sum(ex);
  float A = ex / sm;
  mask[(size_t)row * 64 + lane] = (A > THRESH) ? 1.0f : 0.0f;
}

__global__ void k_dinv(const float* __restrict__ mask, float* dinv, int N) {
  int wid = threadIdx.x >> 6, lane = threadIdx.x & 63;
  int row = blockIdx.x * 4 + wid;       // b*N+i
  if (row >= BB * N) return;
  float v = (lane < N) ? mask[(size_t)row * N + lane] : 0.f;
  float s = warp_allred_sum(v);
  if (lane == 0) dinv[row] = 1.0f / sqrtf(s + 1.0f);
}

// ---- packing kernels (fp32 -> packed h2) ----
// transpose+pack: W[R][Lc] -> out[Lc/2][R], out[k2*R+j] = (W[j][2k2], W[j][2k2+1])
__global__ void k_packT_h(const float* __restrict__ W, unsigned int* __restrict__ out,
                          int R, int Lc) {
  int idx = blockIdx.x * 256 + threadIdx.x;
  int half = Lc >> 1;
  if (idx >= R * half) return;
  int k2 = idx / R, j = idx % R;
  out[idx] = packh(W[j * Lc + 2 * k2], W[j * Lc + 2 * k2 + 1]);
}
// pack along K (no transpose): W[K][N] -> out[K/2][N]
__global__ void k_pack_h(const float* __restrict__ W, unsigned int* __restrict__ out,
                         int K, int N) {
  int idx = blockIdx.x * 256 + threadIdx.x;
  if (idx >= (K >> 1) * N) return;
  int k2 = idx / N, n = idx % N;
  out[idx] = packh(W[(2 * k2) * N + n], W[(2 * k2 + 1) * N + n]);
}
// conv weights: W[128oc][CIN][KS] -> out[(ci2*KS+t)*128+oc] = (W[oc][2ci2][t], W[oc][2ci2+1][t])
__global__ void k_packcw(const float* __restrict__ W, unsigned int* __restrict__ out,
                         int CIN, int KS) {
  int idx = blockIdx.x * 256 + threadIdx.x;
  int cin2 = CIN >> 1;
  if (idx >= cin2 * KS * 128) return;
  int oc = idx % 128, r = idx / 128;
  int ci2 = r / KS, t = r % KS;
  out[idx] = packh(W[(size_t)oc * CIN * KS + (2 * ci2) * KS + t],
                   W[(size_t)oc * CIN * KS + (2 * ci2 + 1) * KS + t]);
}

// f16-dot2 tiled GEMM: C[M,N] = A[M,K] @ B[K,N]; A fp32 (converted during staging),
// Bh pre-packed h2 [K/2][N]. BM=BN=64, BK=32, 256 threads, 4x4 microtile.
__global__ __launch_bounds__(256) void k_gemmh(const float* __restrict__ A,
                                               const unsigned int* __restrict__ Bh,
                                               float* __restrict__ C,
                                               int M, int N, int K) {
  __shared__ unsigned int sah[16][64];   // [k2][m]
  __shared__ unsigned int sbh[16][64];   // [k2][n]
  int nbn = N >> 6;
  int bm = blockIdx.x / nbn, bn = blockIdx.x % nbn;
  int m0 = bm * 64, n0 = bn * 64;
  int tx = threadIdx.x & 15, ty = threadIdx.x >> 4;
  float acc[4][4];
  #pragma unroll
  for (int i = 0; i < 4; i++)
    #pragma unroll
    for (int j = 0; j < 4; j++) acc[i][j] = 0.f;
  int arow = threadIdx.x >> 2;            // 0..63
  int acol = (threadIdx.x & 3) * 8;       // k offset 0,8,16,24
  int brow = threadIdx.x >> 4;            // k2 0..15
  int bcol = (threadIdx.x & 15) * 4;
  for (int k0 = 0; k0 < K; k0 += 32) {
    float4 av0 = *(const float4*)&A[(size_t)(m0 + arow) * K + k0 + acol];
    float4 av1 = *(const float4*)&A[(size_t)(m0 + arow) * K + k0 + acol + 4];
    uint4 bv = *(const uint4*)&Bh[(size_t)((k0 >> 1) + brow) * N + n0 + bcol];
    __syncthreads();
    int ac2 = acol >> 1;
    sah[ac2 + 0][arow] = packh(av0.x, av0.y);
    sah[ac2 + 1][arow] = packh(av0.z, av0.w);
    sah[ac2 + 2][arow] = packh(av1.x, av1.y);
    sah[ac2 + 3][arow] = packh(av1.z, av1.w);
    *(uint4*)&sbh[brow][bcol] = bv;
    __syncthreads();
    #pragma unroll
    for (int kk = 0; kk < 16; kk++) {
      uint4 a4 = *(const uint4*)&sah[kk][ty * 4];
      uint4 b4 = *(const uint4*)&sbh[kk][tx * 4];
      h2 ax = uH2(a4.x), ay = uH2(a4.y), az = uH2(a4.z), aw = uH2(a4.w);
      h2 bx = uH2(b4.x), by = uH2(b4.y), bz = uH2(b4.z), bw = uH2(b4.w);
      acc[0][0] = fdot2f(ax, bx, acc[0][0]); acc[0][1] = fdot2f(ax, by, acc[0][1]);
      acc[0][2] = fdot2f(ax, bz, acc[0][2]); acc[0][3] = fdot2f(ax, bw, acc[0][3]);
      acc[1][0] = fdot2f(ay, bx, acc[1][0]); acc[1][1] = fdot2f(ay, by, acc[1][1]);
      acc[1][2] = fdot2f(ay, bz, acc[1][2]); acc[1][3] = fdot2f(ay, bw, acc[1][3]);
      acc[2][0] = fdot2f(az, bx, acc[2][0]); acc[2][1] = fdot2f(az, by, acc[2][1]);
      acc[2][2] = fdot2f(az, bz, acc[2][2]); acc[2][3] = fdot2f(az, bw, acc[2][3]);
      acc[3][0] = fdot2f(aw, bx, acc[3][0]); acc[3][1] = fdot2f(aw, by, acc[3][1]);
      acc[3][2] = fdot2f(aw, bz, acc[3][2]); acc[3][3] = fdot2f(aw, bw, acc[3][3]);
    }
  }
  #pragma unroll
  for (int i = 0; i < 4; i++) {
    float4 v = make_float4(acc[i][0], acc[i][1], acc[i][2], acc[i][3]);
    *(float4*)&C[(size_t)(m0 + ty * 4 + i) * N + n0 + tx * 4] = v;
  }
}

// xw[b,i,f] = sum_k gin[b,i,k] * W[k,f]  (small stages, K=128, fp32)
__global__ void k_xw(const float* __restrict__ gin, const float* __restrict__ W,
                     float* __restrict__ out, int N, int K) {
  __shared__ float xs[512];
  int b = blockIdx.x / N, i = blockIdx.x % N;
  const float* grow = gin + (size_t)(b * N + i) * K;
  for (int k = threadIdx.x; k < K; k += 128) xs[k] = grow[k];
  __syncthreads();
  int f = threadIdx.x;
  float a0 = 0.f, a1 = 0.f, a2 = 0.f, a3 = 0.f;
  for (int k = 0; k < K; k += 4) {
    a0 += xs[k]     * W[(k)     * HH + f];
    a1 += xs[k + 1] * W[(k + 1) * HH + f];
    a2 += xs[k + 2] * W[(k + 2) * HH + f];
    a3 += xs[k + 3] * W[(k + 3) * HH + f];
  }
  out[(size_t)(b * N + i) * HH + f] = (a0 + a1) + (a2 + a3);
}

// g[b,i,f] = relu(dinv_i*(dinv_i*xw_if + sum_j m_ij*dinv_j*xw_jf) + bias_f)
__global__ void k_gcnagg(const float* __restrict__ xw, const float* __restrict__ mask,
                         const float* __restrict__ dinv, const float* __restrict__ bias,
                         float* __restrict__ gout, int N) {
  __shared__ float mrow[64], dv[64];
  int b = blockIdx.x / N, i = blockIdx.x % N;
  if (threadIdx.x < N) {
    mrow[threadIdx.x] = mask[(size_t)(b * N + i) * N + threadIdx.x];
    dv[threadIdx.x] = dinv[b * N + threadIdx.x];
  }
  __syncthreads();
  int f = threadIdx.x;
  float di = dv[i];
  float acc = di * xw[(size_t)(b * N + i) * HH + f];
  for (int j = 0; j < N; j++) acc += mrow[j] * dv[j] * xw[(size_t)(b * N + j) * HH + f];
  float y = di * acc + bias[f];
  gout[(size_t)(b * N + i) * HH + f] = y > 0.f ? y : 0.f;
}

// fused SAGPool
__global__ void k_pool(const float* __restrict__ g, const float* __restrict__ mask,
                       const float* __restrict__ w1, const float* __restrict__ w2,
                       const float* __restrict__ pb, int N, int kk,
                       float* gp, float* mnext, float* __restrict__ r) {
  __shared__ float d1[64], d2[64], sv[64], vals[32], tvs[32];
  __shared__ int idxs[32];
  int b = blockIdx.x, tid = threadIdx.x;
  if (tid < N) {
    const float* gr = g + (size_t)(b * N + tid) * HH;
    float a = 0.f, c = 0.f;
    for (int d = 0; d < HH; d++) { float v = gr[d]; a += v * w1[d]; c += v * w2[d]; }
    d1[tid] = a; d2[tid] = c;
  }
  __syncthreads();
  if (tid < N) {
    const float* mr = mask + (size_t)(b * N + tid) * N;
    float s = d1[tid] + pb[0];
    for (int j = 0; j < N; j++) s += mr[j] * d2[j];
    sv[tid] = s;
  }
  __syncthreads();
  if (tid < 64) {
    float myv = (tid < N) ? sv[tid] : -3.4e38f;
    int alive = (tid < N) ? 1 : 0;
    for (int t = 0; t < kk; t++) {
      float cv = alive ? myv : -3.4e38f;
      int ci = tid;
      #pragma unroll
      for (int o = 32; o > 0; o >>= 1) {
        float ov = __shfl_xor(cv, o, 64);
        int oi = __shfl_xor(ci, o, 64);
        if (ov > cv || (ov == cv && oi < ci)) { cv = ov; ci = oi; }
      }
      if (tid == ci) alive = 0;
      if (tid == 0) { idxs[t] = ci; vals[t] = cv; }
    }
  }
  __syncthreads();
  if (tid < kk) tvs[tid] = tanhf(vals[tid]);
  __syncthreads();
  if (tid < HH) {
    float mx = -3.4e38f, sm = 0.f;
    for (int t = 0; t < kk; t++) {
      float v = g[(size_t)(b * N + idxs[t]) * HH + tid] * tvs[t];
      if (gp) gp[(size_t)(b * kk + t) * HH + tid] = v;
      mx = fmaxf(mx, v); sm += v;
    }
    r[b * 256 + tid] += mx;
    r[b * 256 + 128 + tid] += sm / (float)kk;
  }
  if (mnext) {
    for (int q = tid; q < kk * kk; q += blockDim.x) {
      int t = q / kk, u = q % kk;
      mnext[(size_t)(b * kk + t) * kk + u] = mask[(size_t)(b * N + idxs[t]) * N + idxs[u]];
    }
  }
}

__global__ void k_tr(const float* __restrict__ in, float* __restrict__ out, int R, int Lc) {
  int idx = blockIdx.x * 256 + threadIdx.x;
  if (idx >= R * Lc) return;
  int j = idx / Lc, l = idx % Lc;
  out[l * R + j] = in[idx];
}

// GRU recurrence (f16 weights in VGPRs, f16 h broadcast from LDS)
__global__ __launch_bounds__(384) void k_gru(const float* __restrict__ gi,
                                             const float* __restrict__ whhT,
                                             const float* __restrict__ bhh,
                                             const float* __restrict__ bih,
                                             float* __restrict__ ys) {
  __shared__ _Float16 hh[128];
  __shared__ float agh[384], agi[384];
  int c = blockIdx.x, j = threadIdx.x;
  h2 w[64];
  #pragma unroll
  for (int k = 0; k < 64; k++) {
    h2 t;
    t.x = (_Float16)whhT[(2 * k) * G3 + j];
    t.y = (_Float16)whhT[(2 * k + 1) * G3 + j];
    w[k] = t;
  }
  float bh = bhh[j], bi = bih[j];
  float hprev = 0.f;
  if (j < 128) hh[j] = (_Float16)0.f;
  __syncthreads();
  for (int b = 0; b < BB; b++) {
    float gv = gi[(size_t)(b * CC + c) * G3 + j] + bi;
    float a0 = 0.f, a1 = 0.f, a2 = 0.f, a3 = 0.f;
    #pragma unroll
    for (int q = 0; q < 16; q++) {
      float4 hv = *(const float4*)&hh[q * 8];
      a0 = fdot2f(w[q * 4 + 0], asH2(hv.x), a0);
      a1 = fdot2f(w[q * 4 + 1], asH2(hv.y), a1);
      a2 = fdot2f(w[q * 4 + 2], asH2(hv.z), a2);
      a3 = fdot2f(w[q * 4 + 3], asH2(hv.w), a3);
    }
    agh[j] = (a0 + a1) + (a2 + a3) + bh;
    agi[j] = gv;
    __syncthreads();
    if (j < 128) {
      float rg = 1.f / (1.f + expf(-(agi[j] + agh[j])));
      float zg = 1.f / (1.f + expf(-(agi[128 + j] + agh[128 + j])));
      float ng = tanhf(agi[256 + j] + rg * agh[256 + j]);
      float hn = (1.f - zg) * ng + zg * hprev;
      ys[(size_t)(b * CC + c) * 128 + j] = hn;
      hprev = hn;
      hh[j] = (_Float16)hn;
    }
    __syncthreads();
  }
}

__global__ void k_grumean(const float* __restrict__ ys, float* __restrict__ xgru) {
  int b = blockIdx.x, u = threadIdx.x;
  float acc = 0.f;
  for (int c = 0; c < CC; c++) acc += ys[(size_t)(b * CC + c) * 128 + u];
  xgru[b * 128 + u] = acc / 64.f;
}

// ---------------- h2-paired tiled conv ----------------
// MODE 0: input fp32 (x), output packed h2. MODE 1: h2 in, h2 out. MODE 2: h2 in, fused relu+mean.
// Channel pairs packed into h2; dot2 over (ci, ci+1).
template<int CIN, int KS, int DIL, int PAD, int LIN, int LOUT, int MODE, int CI2_CHUNK>
__global__ __launch_bounds__(256) void k_convh(const float* __restrict__ in,
                                               const unsigned int* __restrict__ Wh,
                                               const float* __restrict__ bias,
                                               float* __restrict__ out, int b0) {
  constexpr int CIN2 = CIN / 2;
  constexpr int K2_CHUNK = CI2_CHUNK * KS;
  constexpr int NCH = CIN2 / CI2_CHUNK;
  constexpr int NF4 = K2_CHUNK * 32;          // uint4s per weight chunk
  constexpr int PFN = (NF4 + 255) / 256;
  constexpr int TW = 72;
  constexpr int NT = (LOUT + 63) / 64;
  __shared__ unsigned int si2[CIN2][TW];
  __shared__ unsigned int sw2[2][K2_CHUNK][128];
  int nb = blockIdx.x / NT;
  int p0 = (blockIdx.x % NT) * 64;
  uint4 pf[PFN];
  auto prefetch = [&](int ch) {
    const uint4* src = (const uint4*)(Wh + (size_t)ch * K2_CHUNK * 128);
    #pragma unroll
    for (int i = 0; i < PFN; i++) {
      int idx = threadIdx.x + i * 256;
      if (idx < NF4) pf[i] = src[idx];
    }
  };
  auto commit = [&](int buf) {
    #pragma unroll
    for (int i = 0; i < PFN; i++) {
      int idx = threadIdx.x + i * 256;
      if (idx < NF4) ((uint4*)sw2[buf])[idx] = pf[i];
    }
  };
  prefetch(0);
  if constexpr (MODE == 0) {
    const float* inb = in + (size_t)nb * CIN * LIN;
    for (int q = threadIdx.x; q < CIN2 * TW; q += 256) {
      int ci2 = q / TW, col = q % TW;
      int gp = p0 - 8 + col;
      unsigned int v = 0u;
      if (gp >= 0 && gp < LIN)
        v = packh(inb[(2 * ci2) * LIN + gp], inb[(2 * ci2 + 1) * LIN + gp]);
      si2[ci2][col] = v;
    }
  } else {
    const unsigned int* inh = (const unsigned int*)in + (size_t)nb * CIN2 * LIN;
    for (int q = threadIdx.x; q < CIN2 * TW; q += 256) {
      int ci2 = q / TW, col = q % TW;
      int gp = p0 - 8 + col;
      si2[ci2][col] = (gp >= 0 && gp < LIN) ? inh[ci2 * LIN + gp] : 0u;
    }
  }
  commit(0);
  __syncthreads();
  int posg = threadIdx.x & 15;           // pos = p0 + posg*4 + j
  int ocg = threadIdx.x >> 4;            // oc  = ocg*8 + o
  float acc[8][4];
  #pragma unroll
  for (int o = 0; o < 8; o++)
    #pragma unroll
    for (int j = 0; j < 4; j++) acc[o][j] = 0.f;
  for (int ch = 0; ch < NCH; ch++) {
    if (ch + 1 < NCH) prefetch(ch + 1);
    int buf = ch & 1;
    #pragma unroll
    for (int cl = 0; cl < CI2_CHUNK; cl++) {
      int ci2 = ch * CI2_CHUNK + cl;
      unsigned int w12[12];
      *(uint4*)&w12[0] = *(const uint4*)&si2[ci2][posg * 4];
      *(uint4*)&w12[4] = *(const uint4*)&si2[ci2][posg * 4 + 4];
      *(uint4*)&w12[8] = *(const uint4*)&si2[ci2][posg * 4 + 8];
      #pragma unroll
      for (int t = 0; t < KS; t++) {
        int off = t * DIL - PAD + 8;     // in [0,8]
        const unsigned int* wp = &sw2[buf][cl * KS + t][ocg * 8];
        h2 i0 = uH2(w12[off]), i1 = uH2(w12[off + 1]);
        h2 i2 = uH2(w12[off + 2]), i3 = uH2(w12[off + 3]);
        #pragma unroll
        for (int o = 0; o < 8; o++) {
          h2 w = uH2(wp[o]);
          acc[o][0] = fdot2f(w, i0, acc[o][0]);
          acc[o][1] = fdot2f(w, i1, acc[o][1]);
          acc[o][2] = fdot2f(w, i2, acc[o][2]);
          acc[o][3] = fdot2f(w, i3, acc[o][3]);
        }
      }
    }
    __syncthreads();
    if (ch + 1 < NCH) {
      commit(buf ^ 1);
      __syncthreads();
    }
  }
  if constexpr (MODE == 2) {
    #pragma unroll
    for (int o = 0; o < 8; o++) {
      int oc = ocg * 8 + o;
      float bz = bias[oc];
      float s = 0.f;
      #pragma unroll
      for (int j = 0; j < 4; j++) {
        int p = p0 + posg * 4 + j;
        if (p < LOUT) { float y = acc[o][j] + bz; s += y > 0.f ? y : 0.f; }
      }
      #pragma unroll
      for (int d = 8; d > 0; d >>= 1) s += __shfl_down(s, d, 64);
      if (posg == 0) atomicAdd(&out[(size_t)(b0 + nb) * 128 + oc], s);
    }
  } else {
    unsigned int* oh = (unsigned int*)out + (size_t)nb * 64 * LOUT;
    #pragma unroll
    for (int e = 0; e < 4; e++) {
      int oc0 = ocg * 8 + 2 * e;
      float bz0 = bias[oc0], bz1 = bias[oc0 + 1];
      #pragma unroll
      for (int j = 0; j < 4; j++) {
        int p = p0 + posg * 4 + j;
        if (p < LOUT) {
          float y0 = acc[2 * e][j] + bz0;     y0 = y0 > 0.f ? y0 : 0.f;
          float y1 = acc[2 * e + 1][j] + bz1; y1 = y1 > 0.f ? y1 : 0.f;
          oh[(size_t)(ocg * 4 + e) * LOUT + p] = packh(y0, y1);
        }
      }
    }
  }
}

__global__ void k_fc0(const float* __restrict__ xconv, const float* __restrict__ xgru,
                      const float* __restrict__ r, const float* __restrict__ W,
                      const float* __restrict__ bias, float* __restrict__ hm) {
  __shared__ float feat[512];
  int b = blockIdx.x, t = threadIdx.x;
  if (t < 128) { feat[t] = xconv[b * 128 + t] * (1.f / (float)CL3); feat[128 + t] = xgru[b * 128 + t]; }
  feat[256 + t] = r[b * 256 + t];
  __syncthreads();
  float acc = bias[t];
  for (int k = 0; k < 512; k++) acc += feat[k] * W[k * 256 + t];
  hm[b * 256 + t] = acc;
}

__global__ void k_bn(const float* __restrict__ hm, const float* __restrict__ gamma,
                     const float* __restrict__ beta, float* __restrict__ out) {
  __shared__ float red[256];
  int n = blockIdx.x, t = threadIdx.x;
  float v = hm[t * 256 + n];
  red[t] = v; __syncthreads();
  for (int s = 128; s > 0; s >>= 1) { if (t < s) red[t] += red[t + s]; __syncthreads(); }
  float mean = red[0] / 256.f; __syncthreads();
  float dv = v - mean;
  red[t] = dv * dv; __syncthreads();
  for (int s = 128; s > 0; s >>= 1) { if (t < s) red[t] += red[t + s]; __syncthreads(); }
  float var = red[0] / 256.f;
  float y = gamma[n] * dv * (1.f / sqrtf(var + 1e-5f)) + beta[n];
  out[t * 256 + n] = y < 0.f ? 0.01f * y : y;
}

__global__ void k_fc1(const float* __restrict__ hmn, const float* __restrict__ W,
                      const float* __restrict__ bias, float* __restrict__ z) {
  __shared__ float hs[256];
  int b = blockIdx.x, t = threadIdx.x;
  hs[t] = hmn[b * 256 + t]; hs[128 + t] = hmn[b * 256 + 128 + t];
  __syncthreads();
  float acc = bias[t];
  for (int k = 0; k < 256; k++) acc += hs[k] * W[k * 128 + t];
  z[b * 128 + t] = acc;
}

// attention logits: grid (8 classes x 4 sample-tiles of 64), tiled GEMM + tanh/W2 epilogue.
__global__ __launch_bounds__(256) void k_att1(const float* __restrict__ z,
                                              const float* __restrict__ W1,
                                              const float* __restrict__ b1,
                                              const float* __restrict__ W2,
                                              float* __restrict__ logits) {
  __shared__ float sa[32][64];   // [k][m]
  __shared__ float sb[32][64];   // [k][a]
  int c = blockIdx.x >> 2;
  int m0 = (blockIdx.x & 3) * 64;
  const float* B = W1 + (size_t)c * 128 * AT;    // [128][64]
  int tx = threadIdx.x & 15, ty = threadIdx.x >> 4;
  float acc[4][4];
  #pragma unroll
  for (int i = 0; i < 4; i++)
    #pragma unroll
    for (int j = 0; j < 4; j++) acc[i][j] = 0.f;
  int arow = threadIdx.x >> 2;
  int acol = (threadIdx.x & 3) * 8;
  int brow = threadIdx.x >> 4;
  int bcol = (threadIdx.x & 15) * 4;
  for (int k0 = 0; k0 < 128; k0 += 32) {
    float4 av0 = *(const float4*)&z[(size_t)(m0 + arow) * 128 + k0 + acol];
    float4 av1 = *(const float4*)&z[(size_t)(m0 + arow) * 128 + k0 + acol + 4];
    float4 bv0 = *(const float4*)&B[(size_t)(k0 + brow) * AT + bcol];
    float4 bv1 = *(const float4*)&B[(size_t)(k0 + brow + 16) * AT + bcol];
    __syncthreads();
    sa[acol + 0][arow] = av0.x; sa[acol + 1][arow] = av0.y;
    sa[acol + 2][arow] = av0.z; sa[acol + 3][arow] = av0.w;
    sa[acol + 4][arow] = av1.x; sa[acol + 5][arow] = av1.y;
    sa[acol + 6][arow] = av1.z; sa[acol + 7][arow] = av1.w;
    *(float4*)&sb[brow][bcol] = bv0;
    *(float4*)&sb[brow + 16][bcol] = bv1;
    __syncthreads();
    #pragma unroll
    for (int kk = 0; kk < 32; kk++) {
      float4 a4 = *(const float4*)&sa[kk][ty * 4];
      float4 b4 = *(const float4*)&sb[kk][tx * 4];
      acc[0][0] += a4.x * b4.x; acc[0][1] += a4.x * b4.y; acc[0][2] += a4.x * b4.z; acc[0][3] += a4.x * b4.w;
      acc[1][0] += a4.y * b4.x; acc[1][1] += a4.y * b4.y; acc[1][2] += a4.y * b4.z; acc[1][3] += a4.y * b4.w;
      acc[2][0] += a4.z * b4.x; acc[2][1] += a4.z * b4.y; acc[2][2] += a4.z * b4.z; acc[2][3] += a4.z * b4.w;
      acc[3][0] += a4.w * b4.x; acc[3][1] += a4.w * b4.y; acc[3][2] += a4.w * b4.z; acc[3][3] += a4.w * b4.w;
    }
  }
  const float* b1c = b1 + c * AT;
  const float* w2c = W2 + c * AT;
  float w2v[4], b1v[4];
  #pragma unroll
  for (int j = 0; j < 4; j++) { w2v[j] = w2c[tx * 4 + j]; b1v[j] = b1c[tx * 4 + j]; }
  #pragma unroll
  for (int i = 0; i < 4; i++) {
    float s = 0.f;
    #pragma unroll
    for (int j = 0; j < 4; j++) s += tanhf(acc[i][j] + b1v[j]) * w2v[j];
    #pragma unroll
    for (int o = 8; o > 0; o >>= 1) s += __shfl_xor(s, o, 64);
    if (tx == 0) logits[c * 256 + m0 + ty * 4 + i] = s;
  }
}

// masked softmax over samples + prototype
__global__ void k_att2(const float* __restrict__ z, const int* __restrict__ labels,
                       const int* __restrict__ idx_train, int ntrain,
                       const float* __restrict__ logits, const float* __restrict__ b2,
                       float* __restrict__ protos) {
  __shared__ float wv[256], red[256];
  __shared__ int trainm[256];
  int c = blockIdx.x, n = threadIdx.x;
  trainm[n] = 0; __syncthreads();
  if (n < ntrain) trainm[idx_train[n]] = 1;
  __syncthreads();
  bool keep = trainm[n] && (labels[n] == c);
  float ml = keep ? (logits[c * 256 + n] + b2[c]) : -1e30f;
  red[n] = ml; __syncthreads();
  for (int s = 128; s > 0; s >>= 1) { if (n < s) red[n] = fmaxf(red[n], red[n + s]); __syncthreads(); }
  float mx = red[0]; __syncthreads();
  float e = expf(ml - mx);
  wv[n] = e; red[n] = e; __syncthreads();
  for (int s = 128; s > 0; s >>= 1) { if (n < s) red[n] += red[n + s]; __syncthreads(); }
  float ssum = red[0]; __syncthreads();
  wv[n] = wv[n] / ssum;
  __syncthreads();
  if (n < 128) {
    float p = 0.f;
    for (int q = 0; q < 256; q++) p += wv[q] * z[q * 128 + n];
    protos[c * 128 + n] = p;
  }
}

__global__ void k_dist(const float* __restrict__ z, const float* __restrict__ protos,
                       float* __restrict__ dout) {
  __shared__ float zs[128], red[128];
  int n = blockIdx.x, t = threadIdx.x;
  zs[t] = z[n * 128 + t];
  red[t] = zs[t] * zs[t]; __syncthreads();
  for (int s = 64; s > 0; s >>= 1) { if (t < s) red[t] += red[t + s]; __syncthreads(); }
  float z2 = red[0];
  if (t < NC) {
    float dot = 0.f, p2 = 0.f;
    const float* pr = protos + t * 128;
    for (int d = 0; d < 128; d++) { float pv = pr[d]; dot += pv * zs[d]; p2 += pv * pv; }
    float d2 = fmaxf(z2 + p2 - 2.f * dot, 1e-12f);
    dout[n * NC + t] = expf(-0.5f * sqrtf(d2));
  }
}

__global__ void k_pdist(const float* __restrict__ protos, float* __restrict__ dout) {
  __shared__ float red[64];
  int t = threadIdx.x, i = t / 8, j = t % 8;
  float dot = 0.f, p2i = 0.f, p2j = 0.f;
  for (int d = 0; d < 128; d++) {
    float a = protos[i * 128 + d], b = protos[j * 128 + d];
    dot += a * b; p2i += a * a; p2j += b * b;
  }
  float d2 = fmaxf(p2i + p2j - 2.f * dot, 1e-12f);
  red[t] = expf(-0.5f * sqrtf(d2));
  __syncthreads();
  for (int s = 32; s > 0; s >>= 1) { if (t < s) red[t] += red[t + s]; __syncthreads(); }
  if (t == 0) dout[2048] = red[0] / 28.f;
}

extern "C" void kernel_launch(void* const* d_in, const int* in_sizes, int n_in,
                              void* d_out, int out_size, void* d_ws, size_t ws_size,
                              hipStream_t stream) {
  const float* x = (const float*)d_in[0];
  const int* labels = (const int*)d_in[1];
  const int* idx_train = (const int*)d_in[2];
  const float* gat_W = (const float*)d_in[3];
  const float* gat_a1 = (const float*)d_in[4];
  const float* gat_a2 = (const float*)d_in[5];
  const float* gcnW[3] = {(const float*)d_in[6], (const float*)d_in[8], (const float*)d_in[10]};
  const float* gcnB[3] = {(const float*)d_in[7], (const float*)d_in[9], (const float*)d_in[11]};
  const float* pw1[3] = {(const float*)d_in[12], (const float*)d_in[15], (const float*)d_in[18]};
  const float* pw2[3] = {(const float*)d_in[13], (const float*)d_in[16], (const float*)d_in[19]};
  const float* pbb[3] = {(const float*)d_in[14], (const float*)d_in[17], (const float*)d_in[20]};
  const float* wih = (const float*)d_in[21];
  const float* whh = (const float*)d_in[22];
  const float* bih = (const float*)d_in[23];
  const float* bhh = (const float*)d_in[24];
  const float* c1W = (const float*)d_in[25]; const float* c1b = (const float*)d_in[26];
  const float* c2W = (const float*)d_in[27]; const float* c2b = (const float*)d_in[28];
  const float* c3W = (const float*)d_in[29]; const float* c3b = (const float*)d_in[30];
  const float* fc0W = (const float*)d_in[31]; const float* fc0b = (const float*)d_in[32];
  const float* bn0g = (const float*)d_in[33]; const float* bn0b = (const float*)d_in[34];
  const float* fc1W = (const float*)d_in[35]; const float* fc1b = (const float*)d_in[36];
  const float* aW1 = (const float*)d_in[37]; const float* ab1 = (const float*)d_in[38];
  const float* aW2 = (const float*)d_in[39]; const float* ab2 = (const float*)d_in[40];
  float* out = (float*)d_out;
  float* ws = (float*)d_ws;

  // ---- workspace layout (floats). Z region reused by 3 sequential phases. ----
  size_t off = 0;
  auto take = [&](size_t n) { size_t o = off; off += (n + 63) & ~(size_t)63; return o; };
  float* wa1   = ws + take(512);
  float* wa2   = ws + take(512);
  float* ha1   = ws + take(BB * CC);
  float* ha2   = ws + take(BB * CC);
  float* dinv  = ws + take(BB * 64);
  float* rbuf  = ws + take(BB * 256);
  float* xgru  = ws + take(BB * 128);
  float* xconv = ws + take(BB * 128);
  float* hm    = ws + take(BB * 256);
  float* hmn   = ws + take(BB * 256);
  float* zb    = ws + take(BB * 128);
  float* protos = ws + take(NC * 128);
  float* lgts  = ws + take(NC * 256);
  float* gw1h  = ws + take(256 * 128);       // packed h2 gcnW[0]
  float* wslot = ws + take(512 * 384);       // wihT_h (GRU) then conv weights (conv phase)
  float* whhT  = ws + take(128 * 384);
  float* Z     = ws + take(8568832);
  // GNN-phase aliases
  float* mA  = Z;
  float* mB  = Z + 1048576;
  float* xw  = Z + 2097152;
  float* gb  = Z + 4194304;
  float* gp1 = Z + 6291456;
  float* gp2 = Z + 7340032;
  // GRU-phase aliases
  float* gi = Z;
  float* ys = Z + 6291456;
  // conv-phase aliases (chunks of 64 samples, packed h2 activations)
  float* cv1 = Z;
  float* cv2 = Z + 4251648;
  unsigned int* wihTh = (unsigned int*)wslot;            // 256x384
  unsigned int* wt1h = (unsigned int*)wslot;             // 32*8*128 = 32768
  unsigned int* wt2h = wt1h + 32768;                     // 64*5*128 = 40960
  unsigned int* wt3h = wt2h + 40960;                     // 64*3*128 = 24576

  hipMemsetAsync(rbuf, 0, BB * 256 * sizeof(float), stream);
  hipMemsetAsync(xconv, 0, BB * 128 * sizeof(float), stream);

  // ---- GAT adjacency ----
  k_wa<<<8, 64, 0, stream>>>(gat_W, gat_a1, gat_a2, wa1, wa2);
  k_ha<<<BB * CC / 4, 256, 0, stream>>>(x, wa1, wa2, ha1, ha2);
  k_softmask<<<BB * 64 / 4, 256, 0, stream>>>(ha1, ha2, mA);

  // ---- 3x (GCN + SAGPool) with jump-knowledge readout ----
  k_pack_h<<<(256 * 128 + 255) / 256, 256, 0, stream>>>(gcnW[0], (unsigned int*)gw1h, 512, 128);
  const int Ns[3] = {64, 32, 16};
  const int ks[3] = {32, 16, 8};
  const float* gins[3] = {x, gp1, gp2};
  float* mcur[3] = {mA, mB, mA};
  float* mnxt[3] = {mB, mA, nullptr};
  float* gps[3]  = {gp1, gp2, nullptr};
  for (int s = 0; s < 3; s++) {
    int N = Ns[s];
    k_dinv<<<(BB * N + 3) / 4, 256, 0, stream>>>(mcur[s], dinv, N);
    if (s == 0) {
      k_gemmh<<<(BB * CC / 64) * (HH / 64), 256, 0, stream>>>(
          x, (unsigned int*)gw1h, xw, BB * CC, HH, LL);
    } else {
      k_xw<<<BB * N, 128, 0, stream>>>(gins[s], gcnW[s], xw, N, 128);
    }
    k_gcnagg<<<BB * N, 128, 0, stream>>>(xw, mcur[s], dinv, gcnB[s], gb, N);
    k_pool<<<BB, 256, 0, stream>>>(gb, mcur[s], pw1[s], pw2[s], pbb[s], N, ks[s],
                                   gps[s], mnxt[s], rbuf);
  }

  // ---- GRU branch: gi = x @ wihT (f16 dot2 GEMM), then f16 recurrence ----
  k_packT_h<<<(256 * 384 + 255) / 256, 256, 0, stream>>>(wih, wihTh, 384, 512);
  k_tr<<<(384 * 128 + 255) / 256, 256, 0, stream>>>(whh, whhT, 384, 128);
  k_gemmh<<<(BB * CC / 64) * (G3 / 64), 256, 0, stream>>>(x, wihTh, gi, BB * CC, G3, LL);
  k_gru<<<CC, 384, 0, stream>>>(gi, whhT, bhh, bih, ys);
  k_grumean<<<BB, 128, 0, stream>>>(ys, xgru);

  // ---- dilated conv branch (h2-paired); weight slot reused after gi GEMM ----
  k_packcw<<<(32 * 8 * 128 + 255) / 256, 256, 0, stream>>>(c1W, wt1h, 64, 8);
  k_packcw<<<(64 * 5 * 128 + 255) / 256, 256, 0, stream>>>(c2W, wt2h, 128, 5);
  k_packcw<<<(64 * 3 * 128 + 255) / 256, 256, 0, stream>>>(c3W, wt3h, 128, 3);
  for (int bc = 0; bc < 4; bc++) {
    int b0 = bc * 64;
    k_convh<64, 8, 1, 7, 512, CL1, 0, 2><<<64 * 9, 256, 0, stream>>>(
        x + (size_t)b0 * CC * LL, wt1h, c1b, cv1, b0);
    k_convh<128, 5, 2, 8, CL1, CL2, 1, 4><<<64 * 9, 256, 0, stream>>>(
        cv1, wt2h, c2b, cv2, b0);
    k_convh<128, 3, 4, 8, CL2, CL3, 2, 8><<<64 * 9, 256, 0, stream>>>(
        cv2, wt3h, c3b, xconv, b0);
  }

  // ---- mapping MLP + BN + attention prototypes + distances ----
  k_fc0<<<BB, 256, 0, stream>>>(xconv, xgru, rbuf, fc0W, fc0b, hm);
  k_bn<<<256, 256, 0, stream>>>(hm, bn0g, bn0b, hmn);
  k_fc1<<<BB, 128, 0, stream>>>(hmn, fc1W, fc1b, zb);
  k_att1<<<NC * 4, 256, 0, stream>>>(zb, aW1, ab1, aW2, lgts);
  k_att2<<<NC, 256, 0, stream>>>(zb, labels, idx_train, in_sizes[2], lgts, ab2, protos);
  k_dist<<<BB, 128, 0, stream>>>(zb, protos, out);
  k_pdist<<<1, 64, 0, stream>>>(protos, out);
}

// Round 6
// 1553.024 us; speedup vs baseline: 6.5733x; 1.1121x over previous
//
#include <hip/hip_runtime.h>
#include <math.h>

#define BB 256   // batch
#define CC 64    // channels / graph nodes
#define LL 512   // series length
#define HH 128   // gcn hidden
#define G3 384   // 3*gru_dim
#define NC 8
#define AT 64
#define CL1 519
#define CL2 527
#define CL3 535
#define THRESH 0.02f

typedef _Float16 h2 __attribute__((ext_vector_type(2)));
union HU { unsigned int u; h2 h; float f; };

__device__ inline float warp_red_sum(float v) {
  #pragma unroll
  for (int o = 32; o > 0; o >>= 1) v += __shfl_down(v, o, 64);
  return v;
}
__device__ inline float warp_allred_max(float v) {
  #pragma unroll
  for (int o = 32; o > 0; o >>= 1) v = fmaxf(v, __shfl_xor(v, o, 64));
  return v;
}
__device__ inline float warp_allred_sum(float v) {
  #pragma unroll
  for (int o = 32; o > 0; o >>= 1) v += __shfl_xor(v, o, 64);
  return v;
}

__device__ inline float fdot2f(h2 a, h2 b, float c) {
#if __has_builtin(__builtin_amdgcn_fdot2)
  return __builtin_amdgcn_fdot2(a, b, c, false);
#else
  float r;
  asm volatile("v_dot2_f32_f16 %0, %1, %2, %3" : "=v"(r) : "v"(a), "v"(b), "v"(c));
  return r;
#endif
}
__device__ inline h2 asH2(float f) { HU u; u.f = f; return u.h; }
__device__ inline h2 uH2(unsigned int x) { HU u; u.u = x; return u.h; }
__device__ inline unsigned int packh(float a, float b) {
  HU u; h2 t; t.x = (_Float16)a; t.y = (_Float16)b; u.h = t; return u.u;
}

// wa = gat_W @ a  (512-vector)
__global__ void k_wa(const float* __restrict__ gatW, const float* __restrict__ a1,
                     const float* __restrict__ a2, float* wa1, float* wa2) {
  int l = blockIdx.x * 64 + threadIdx.x;
  const float* row = gatW + l * LL;
  float s1 = 0.f, s2 = 0.f;
  for (int k = 0; k < LL; k++) { float w = row[k]; s1 += w * a1[k]; s2 += w * a2[k]; }
  wa1[l] = s1; wa2[l] = s2;
}

// ha1[b,c] = x[b,c,:].wa1 ; ha2 likewise. one wave per row.
__global__ void k_ha(const float* __restrict__ x, const float* __restrict__ wa1,
                     const float* __restrict__ wa2, float* ha1, float* ha2) {
  int wid = threadIdx.x >> 6, lane = threadIdx.x & 63;
  int row = blockIdx.x * 4 + wid;
  const float* xr = x + (size_t)row * LL;
  float s1 = 0.f, s2 = 0.f;
  for (int q = lane; q < LL; q += 64) { float v = xr[q]; s1 += v * wa1[q]; s2 += v * wa2[q]; }
  s1 = warp_red_sum(s1); s2 = warp_red_sum(s2);
  if (lane == 0) { ha1[row] = s1; ha2[row] = s2; }
}

// softmax row -> mask; fused dinv0 (row degree)
__global__ void k_softmask(const float* __restrict__ ha1, const float* __restrict__ ha2,
                           float* __restrict__ mask, float* __restrict__ dinv) {
  int wid = threadIdx.x >> 6, lane = threadIdx.x & 63;
  int row = blockIdx.x * 4 + wid;       // row = b*64+i
  int b = row >> 6;
  float e = ha1[row] + ha2[b * 64 + lane];
  e = e < 0.f ? 0.2f * e : e;
  float mx = warp_allred_max(e);
  float ex = expf(e - mx);
  float sm = warp_allred_sum(ex);
  float A = ex / sm;
  float mval = (A > THRESH) ? 1.0f : 0.0f;
  mask[(size_t)row * 64 + lane] = mval;
  float cnt = warp_allred_sum(mval);
  if (lane == 0) dinv[row] = 1.0f / sqrtf(cnt + 1.0f);
}

// ---- packing kernels (fp32 -> packed h2) ----
__global__ void k_packT_h(const float* __restrict__ W, unsigned int* __restrict__ out,
                          int R, int Lc) {
  int idx = blockIdx.x * 256 + threadIdx.x;
  int half = Lc >> 1;
  if (idx >= R * half) return;
  int k2 = idx / R, j = idx % R;
  out[idx] = packh(W[j * Lc + 2 * k2], W[j * Lc + 2 * k2 + 1]);
}
__global__ void k_pack_h(const float* __restrict__ W, unsigned int* __restrict__ out,
                         int K, int N) {
  int idx = blockIdx.x * 256 + threadIdx.x;
  if (idx >= (K >> 1) * N) return;
  int k2 = idx / N, n = idx % N;
  out[idx] = packh(W[(2 * k2) * N + n], W[(2 * k2 + 1) * N + n]);
}
// whh [384][128] -> wpk[(r*64+k2)*128 + j] = (whh[j+128r][2k2], whh[j+128r][2k2+1])
__global__ void k_packgru(const float* __restrict__ whh, unsigned int* __restrict__ out) {
  int idx = blockIdx.x * 256 + threadIdx.x;
  if (idx >= 192 * 128) return;
  int j = idx & 127, rk = idx >> 7;
  int r = rk >> 6, k2 = rk & 63;
  const float* src = whh + (size_t)(j + 128 * r) * 128 + 2 * k2;
  out[idx] = packh(src[0], src[1]);
}
// all three conv weights in one launch
__device__ inline void packcw_one(const float* W, unsigned int* out, int CIN, int KS, int idx) {
  int oc = idx % 128, r = idx / 128;
  int ci2 = r / KS, t = r % KS;
  out[idx] = packh(W[(size_t)oc * CIN * KS + (2 * ci2) * KS + t],
                   W[(size_t)oc * CIN * KS + (2 * ci2 + 1) * KS + t]);
}
__global__ void k_packcw_all(const float* __restrict__ c1W, const float* __restrict__ c2W,
                             const float* __restrict__ c3W, unsigned int* o1,
                             unsigned int* o2, unsigned int* o3) {
  int idx = blockIdx.x * 256 + threadIdx.x;
  if (idx < 32768) packcw_one(c1W, o1, 64, 8, idx);
  else if (idx < 73728) packcw_one(c2W, o2, 128, 5, idx - 32768);
  else if (idx < 98304) packcw_one(c3W, o3, 128, 3, idx - 73728);
}

// f16-dot2 tiled GEMM: C[M,N] = A[M,K] @ B[K,N]; A fp32 (converted in staging),
// Bh pre-packed h2 [K/2][N]. BM=BN=64, BK=32, 256 threads, 4x4 microtile.
__global__ __launch_bounds__(256) void k_gemmh(const float* __restrict__ A,
                                               const unsigned int* __restrict__ Bh,
                                               float* __restrict__ C,
                                               int M, int N, int K) {
  __shared__ unsigned int sah[16][64];   // [k2][m]
  __shared__ unsigned int sbh[16][64];   // [k2][n]
  int nbn = N >> 6;
  int bm = blockIdx.x / nbn, bn = blockIdx.x % nbn;
  int m0 = bm * 64, n0 = bn * 64;
  int tx = threadIdx.x & 15, ty = threadIdx.x >> 4;
  float acc[4][4];
  #pragma unroll
  for (int i = 0; i < 4; i++)
    #pragma unroll
    for (int j = 0; j < 4; j++) acc[i][j] = 0.f;
  int arow = threadIdx.x >> 2;            // 0..63
  int acol = (threadIdx.x & 3) * 8;       // k offset 0,8,16,24
  int brow = threadIdx.x >> 4;            // k2 0..15
  int bcol = (threadIdx.x & 15) * 4;
  for (int k0 = 0; k0 < K; k0 += 32) {
    float4 av0 = *(const float4*)&A[(size_t)(m0 + arow) * K + k0 + acol];
    float4 av1 = *(const float4*)&A[(size_t)(m0 + arow) * K + k0 + acol + 4];
    uint4 bv = *(const uint4*)&Bh[(size_t)((k0 >> 1) + brow) * N + n0 + bcol];
    __syncthreads();
    int ac2 = acol >> 1;
    sah[ac2 + 0][arow] = packh(av0.x, av0.y);
    sah[ac2 + 1][arow] = packh(av0.z, av0.w);
    sah[ac2 + 2][arow] = packh(av1.x, av1.y);
    sah[ac2 + 3][arow] = packh(av1.z, av1.w);
    *(uint4*)&sbh[brow][bcol] = bv;
    __syncthreads();
    #pragma unroll
    for (int kk = 0; kk < 16; kk++) {
      uint4 a4 = *(const uint4*)&sah[kk][ty * 4];
      uint4 b4 = *(const uint4*)&sbh[kk][tx * 4];
      h2 ax = uH2(a4.x), ay = uH2(a4.y), az = uH2(a4.z), aw = uH2(a4.w);
      h2 bx = uH2(b4.x), by = uH2(b4.y), bz = uH2(b4.z), bw = uH2(b4.w);
      acc[0][0] = fdot2f(ax, bx, acc[0][0]); acc[0][1] = fdot2f(ax, by, acc[0][1]);
      acc[0][2] = fdot2f(ax, bz, acc[0][2]); acc[0][3] = fdot2f(ax, bw, acc[0][3]);
      acc[1][0] = fdot2f(ay, bx, acc[1][0]); acc[1][1] = fdot2f(ay, by, acc[1][1]);
      acc[1][2] = fdot2f(ay, bz, acc[1][2]); acc[1][3] = fdot2f(ay, bw, acc[1][3]);
      acc[2][0] = fdot2f(az, bx, acc[2][0]); acc[2][1] = fdot2f(az, by, acc[2][1]);
      acc[2][2] = fdot2f(az, bz, acc[2][2]); acc[2][3] = fdot2f(az, bw, acc[2][3]);
      acc[3][0] = fdot2f(aw, bx, acc[3][0]); acc[3][1] = fdot2f(aw, by, acc[3][1]);
      acc[3][2] = fdot2f(aw, bz, acc[3][2]); acc[3][3] = fdot2f(aw, bw, acc[3][3]);
    }
  }
  #pragma unroll
  for (int i = 0; i < 4; i++) {
    float4 v = make_float4(acc[i][0], acc[i][1], acc[i][2], acc[i][3]);
    *(float4*)&C[(size_t)(m0 + ty * 4 + i) * N + n0 + tx * 4] = v;
  }
}

// xw[b,i,f] = sum_k gin[b,i,k] * W[k,f]  (small stages, K=128, fp32)
__global__ void k_xw(const float* __restrict__ gin, const float* __restrict__ W,
                     float* __restrict__ out, int N, int K) {
  __shared__ float xs[512];
  int b = blockIdx.x / N, i = blockIdx.x % N;
  const float* grow = gin + (size_t)(b * N + i) * K;
  for (int k = threadIdx.x; k < K; k += 128) xs[k] = grow[k];
  __syncthreads();
  int f = threadIdx.x;
  float a0 = 0.f, a1 = 0.f, a2 = 0.f, a3 = 0.f;
  for (int k = 0; k < K; k += 4) {
    a0 += xs[k]     * W[(k)     * HH + f];
    a1 += xs[k + 1] * W[(k + 1) * HH + f];
    a2 += xs[k + 2] * W[(k + 2) * HH + f];
    a3 += xs[k + 3] * W[(k + 3) * HH + f];
  }
  out[(size_t)(b * N + i) * HH + f] = (a0 + a1) + (a2 + a3);
}

// g[b,i,f] = relu(dinv_i*(dinv_i*xw_if + sum_j m_ij*dinv_j*xw_jf) + bias_f)
__global__ void k_gcnagg(const float* __restrict__ xw, const float* __restrict__ mask,
                         const float* __restrict__ dinv, const float* __restrict__ bias,
                         float* __restrict__ gout, int N) {
  __shared__ float mrow[64], dv[64];
  int b = blockIdx.x / N, i = blockIdx.x % N;
  if (threadIdx.x < N) {
    mrow[threadIdx.x] = mask[(size_t)(b * N + i) * N + threadIdx.x];
    dv[threadIdx.x] = dinv[b * N + threadIdx.x];
  }
  __syncthreads();
  int f = threadIdx.x;
  float di = dv[i];
  float acc = di * xw[(size_t)(b * N + i) * HH + f];
  for (int j = 0; j < N; j++) acc += mrow[j] * dv[j] * xw[(size_t)(b * N + j) * HH + f];
  float y = di * acc + bias[f];
  gout[(size_t)(b * N + i) * HH + f] = y > 0.f ? y : 0.f;
}

// fused SAGPool: LDS-staged g/mask, wave argmax top-k, gather+gate+readout, next dinv
__global__ __launch_bounds__(256) void k_pool(const float* __restrict__ g,
                                              const float* __restrict__ mask,
                                              const float* __restrict__ w1,
                                              const float* __restrict__ w2,
                                              const float* __restrict__ pb, int N, int kk,
                                              float* gp, float* mnext, float* dnext,
                                              float* __restrict__ r) {
  __shared__ float gs[64 * 129];
  __shared__ float ms[64 * 65];
  __shared__ float d1s[64], d2s[64], sv[64], vals[32], tvs[32];
  __shared__ int idxs[32];
  int b = blockIdx.x, tid = threadIdx.x;
  for (int q = tid; q < N * 128; q += 256) {
    int row = q >> 7, d = q & 127;
    gs[row * 129 + d] = g[(size_t)(b * N + row) * 128 + d];
  }
  for (int q = tid; q < N * N; q += 256) {
    int row = q / N, u = q - row * N;
    ms[row * 65 + u] = mask[(size_t)(b * N + row) * N + u];
  }
  __syncthreads();
  if (tid < N) {
    float a = 0.f, c = 0.f;
    const float* gr = &gs[tid * 129];
    for (int d = 0; d < 128; d++) { float v = gr[d]; a += v * w1[d]; c += v * w2[d]; }
    d1s[tid] = a; d2s[tid] = c;
  }
  __syncthreads();
  if (tid < N) {
    const float* mr = &ms[tid * 65];
    float s = d1s[tid] + pb[0];
    for (int j = 0; j < N; j++) s += mr[j] * d2s[j];
    sv[tid] = s;
  }
  __syncthreads();
  if (tid < 64) {
    float myv = (tid < N) ? sv[tid] : -3.4e38f;
    int alive = (tid < N) ? 1 : 0;
    for (int t = 0; t < kk; t++) {
      float cv = alive ? myv : -3.4e38f;
      int ci = tid;
      #pragma unroll
      for (int o = 32; o > 0; o >>= 1) {
        float ov = __shfl_xor(cv, o, 64);
        int oi = __shfl_xor(ci, o, 64);
        if (ov > cv || (ov == cv && oi < ci)) { cv = ov; ci = oi; }
      }
      if (tid == ci) alive = 0;
      if (tid == 0) { idxs[t] = ci; vals[t] = cv; }
    }
  }
  __syncthreads();
  if (tid < kk) tvs[tid] = tanhf(vals[tid]);
  __syncthreads();
  if (tid < HH) {
    float mx = -3.4e38f, sm = 0.f;
    for (int t = 0; t < kk; t++) {
      float v = gs[idxs[t] * 129 + tid] * tvs[t];
      if (gp) gp[(size_t)(b * kk + t) * HH + tid] = v;
      mx = fmaxf(mx, v); sm += v;
    }
    r[b * 256 + tid] += mx;
    r[b * 256 + 128 + tid] += sm / (float)kk;
  }
  for (int q = tid; q < kk * kk; q += 256) {
    int t = q / kk, u = q - t * kk;
    mnext[(size_t)(b * kk + t) * kk + u] = ms[idxs[t] * 65 + idxs[u]];
  }
  if (dnext && tid < kk) {
    float s = 0.f;
    for (int u = 0; u < kk; u++) s += ms[idxs[tid] * 65 + idxs[u]];
    dnext[b * kk + tid] = 1.0f / sqrtf(s + 1.0f);
  }
}

// GRU recurrence: 128 threads/block; thread j owns gate rows j, j+128, j+256 as
// 192 packed-h2 VGPRs; h double-buffered f16 in LDS (1 barrier/step); gi prefetch.
__global__ __launch_bounds__(128, 1) void k_gru(const float* __restrict__ gi,
                                                const unsigned int* __restrict__ wpk,
                                                const float* __restrict__ bhh,
                                                const float* __restrict__ bih,
                                                float* __restrict__ ys) {
  __shared__ _Float16 hb[2][128];
  int c = blockIdx.x, j = threadIdx.x;
  h2 w0[64], w1[64], w2[64];
  #pragma unroll
  for (int k2 = 0; k2 < 64; k2++) { HU u; u.u = wpk[k2 * 128 + j]; w0[k2] = u.h; }
  #pragma unroll
  for (int k2 = 0; k2 < 64; k2++) { HU u; u.u = wpk[(64 + k2) * 128 + j]; w1[k2] = u.h; }
  #pragma unroll
  for (int k2 = 0; k2 < 64; k2++) { HU u; u.u = wpk[(128 + k2) * 128 + j]; w2[k2] = u.h; }
  float bh0 = bhh[j], bh1 = bhh[j + 128], bh2 = bhh[j + 256];
  float bi0 = bih[j], bi1 = bih[j + 128], bi2 = bih[j + 256];
  float hprev = 0.f;
  hb[0][j] = (_Float16)0.f;
  __syncthreads();
  const float* gbase = gi + (size_t)c * G3 + j;
  float g0 = gbase[0], g1 = gbase[128], g2 = gbase[256];
  int cur = 0;
  for (int b = 0; b < BB; b++) {
    float n0 = 0.f, n1 = 0.f, n2 = 0.f;
    if (b + 1 < BB) {
      const float* gn = gbase + (size_t)(b + 1) * CC * G3;
      n0 = gn[0]; n1 = gn[128]; n2 = gn[256];
    }
    float a0a = 0.f, a0b = 0.f, a1a = 0.f, a1b = 0.f, a2a = 0.f, a2b = 0.f;
    #pragma unroll
    for (int q = 0; q < 16; q++) {
      float4 hv = *(const float4*)&hb[cur][q * 8];
      h2 h0 = asH2(hv.x), h1 = asH2(hv.y), h2v = asH2(hv.z), h3 = asH2(hv.w);
      a0a = fdot2f(w0[q * 4 + 0], h0, a0a); a0b = fdot2f(w0[q * 4 + 1], h1, a0b);
      a0a = fdot2f(w0[q * 4 + 2], h2v, a0a); a0b = fdot2f(w0[q * 4 + 3], h3, a0b);
      a1a = fdot2f(w1[q * 4 + 0], h0, a1a); a1b = fdot2f(w1[q * 4 + 1], h1, a1b);
      a1a = fdot2f(w1[q * 4 + 2], h2v, a1a); a1b = fdot2f(w1[q * 4 + 3], h3, a1b);
      a2a = fdot2f(w2[q * 4 + 0], h0, a2a); a2b = fdot2f(w2[q * 4 + 1], h1, a2b);
      a2a = fdot2f(w2[q * 4 + 2], h2v, a2a); a2b = fdot2f(w2[q * 4 + 3], h3, a2b);
    }
    float A0 = a0a + a0b + bh0;
    float A1 = a1a + a1b + bh1;
    float A2 = a2a + a2b + bh2;
    float rg = 1.f / (1.f + expf(-(g0 + bi0 + A0)));
    float zg = 1.f / (1.f + expf(-(g1 + bi1 + A1)));
    float ng = tanhf(g2 + bi2 + rg * A2);
    float hn = (1.f - zg) * ng + zg * hprev;
    ys[(size_t)(b * CC + c) * 128 + j] = hn;
    hprev = hn;
    hb[cur ^ 1][j] = (_Float16)hn;
    __syncthreads();
    cur ^= 1;
    g0 = n0; g1 = n1; g2 = n2;
  }
}

__global__ void k_grumean(const float* __restrict__ ys, float* __restrict__ xgru) {
  int b = blockIdx.x, u = threadIdx.x;
  float acc = 0.f;
  for (int c = 0; c < CC; c++) acc += ys[(size_t)(b * CC + c) * 128 + u];
  xgru[b * 128 + u] = acc / 64.f;
}

// ---------------- h2-paired tiled conv: 128 threads, 8oc x 8pos microtile ----------------
// MODE 0: fp32 in, h2 out. MODE 1: h2 in, h2 out. MODE 2: h2 in, fused relu+mean (atomic).
template<int CIN, int KS, int DIL, int PAD, int LIN, int LOUT, int MODE, int CI2_CHUNK>
__global__ __launch_bounds__(128) void k_convh(const float* __restrict__ in,
                                               const unsigned int* __restrict__ Wh,
                                               const float* __restrict__ bias,
                                               float* __restrict__ out, int b0) {
  constexpr int CIN2 = CIN / 2;
  constexpr int K2_CHUNK = CI2_CHUNK * KS;
  constexpr int NCH = CIN2 / CI2_CHUNK;
  constexpr int NF4 = K2_CHUNK * 32;          // uint4s per weight chunk
  constexpr int PFN = NF4 / 128;
  constexpr int TW = 72;
  constexpr int NT = (LOUT + 63) / 64;
  __shared__ unsigned int si2[CIN2][TW];
  __shared__ unsigned int sw2[2][K2_CHUNK][128];
  int nb = blockIdx.x / NT;
  int p0 = (blockIdx.x % NT) * 64;
  uint4 pf[PFN];
  auto prefetch = [&](int ch) {
    const uint4* src = (const uint4*)(Wh + (size_t)ch * K2_CHUNK * 128);
    #pragma unroll
    for (int i = 0; i < PFN; i++) pf[i] = src[threadIdx.x + i * 128];
  };
  auto commit = [&](int buf) {
    #pragma unroll
    for (int i = 0; i < PFN; i++) ((uint4*)sw2[buf])[threadIdx.x + i * 128] = pf[i];
  };
  prefetch(0);
  if constexpr (MODE == 0) {
    const float* inb = in + (size_t)nb * CIN * LIN;
    for (int q = threadIdx.x; q < CIN2 * TW; q += 128) {
      int ci2 = q / TW, col = q % TW;
      int gp = p0 - 8 + col;
      unsigned int v = 0u;
      if (gp >= 0 && gp < LIN)
        v = packh(inb[(2 * ci2) * LIN + gp], inb[(2 * ci2 + 1) * LIN + gp]);
      si2[ci2][col] = v;
    }
  } else {
    const unsigned int* inh = (const unsigned int*)in + (size_t)nb * CIN2 * LIN;
    for (int q = threadIdx.x; q < CIN2 * TW; q += 128) {
      int ci2 = q / TW, col = q % TW;
      int gp = p0 - 8 + col;
      si2[ci2][col] = (gp >= 0 && gp < LIN) ? inh[ci2 * LIN + gp] : 0u;
    }
  }
  commit(0);
  __syncthreads();
  int posg = threadIdx.x & 7;            // pos = p0 + posg*8 + j
  int ocg = threadIdx.x >> 3;            // oc  = ocg*8 + o
  float acc[8][8];                        // [oc][pos]
  #pragma unroll
  for (int o = 0; o < 8; o++)
    #pragma unroll
    for (int j = 0; j < 8; j++) acc[o][j] = 0.f;
  for (int ch = 0; ch < NCH; ch++) {
    if (ch + 1 < NCH) prefetch(ch + 1);
    int buf = ch & 1;
    #pragma unroll
    for (int cl = 0; cl < CI2_CHUNK; cl++) {
      int ci2 = ch * CI2_CHUNK + cl;
      unsigned int win[16];
      *(uint4*)&win[0]  = *(const uint4*)&si2[ci2][posg * 8];
      *(uint4*)&win[4]  = *(const uint4*)&si2[ci2][posg * 8 + 4];
      *(uint4*)&win[8]  = *(const uint4*)&si2[ci2][posg * 8 + 8];
      *(uint4*)&win[12] = *(const uint4*)&si2[ci2][posg * 8 + 12];
      #pragma unroll
      for (int t = 0; t < KS; t++) {
        int off = t * DIL - PAD + 8;     // in [0,8]
        const unsigned int* wp = &sw2[buf][cl * KS + t][ocg * 8];
        unsigned int wreg[8];
        *(uint4*)&wreg[0] = *(const uint4*)&wp[0];
        *(uint4*)&wreg[4] = *(const uint4*)&wp[4];
        #pragma unroll
        for (int o = 0; o < 8; o++) {
          h2 w = uH2(wreg[o]);
          #pragma unroll
          for (int j = 0; j < 8; j++)
            acc[o][j] = fdot2f(w, uH2(win[off + j]), acc[o][j]);
        }
      }
    }
    __syncthreads();
    if (ch + 1 < NCH) {
      commit(buf ^ 1);
      __syncthreads();
    }
  }
  if constexpr (MODE == 2) {
    #pragma unroll
    for (int o = 0; o < 8; o++) {
      int oc = ocg * 8 + o;
      float bz = bias[oc];
      float s = 0.f;
      #pragma unroll
      for (int j = 0; j < 8; j++) {
        int p = p0 + posg * 8 + j;
        if (p < LOUT) { float y = acc[o][j] + bz; s += y > 0.f ? y : 0.f; }
      }
      s += __shfl_down(s, 4, 64);
      s += __shfl_down(s, 2, 64);
      s += __shfl_down(s, 1, 64);
      if (posg == 0) atomicAdd(&out[(size_t)(b0 + nb) * 128 + oc], s);
    }
  } else {
    unsigned int* oh = (unsigned int*)out + (size_t)nb * (128 / 2) * LOUT;
    #pragma unroll
    for (int e = 0; e < 4; e++) {
      int oc0 = ocg * 8 + 2 * e;
      float bz0 = bias[oc0], bz1 = bias[oc0 + 1];
      #pragma unroll
      for (int j = 0; j < 8; j++) {
        int p = p0 + posg * 8 + j;
        if (p < LOUT) {
          float y0 = acc[2 * e][j] + bz0;     y0 = y0 > 0.f ? y0 : 0.f;
          float y1 = acc[2 * e + 1][j] + bz1; y1 = y1 > 0.f ? y1 : 0.f;
          oh[(size_t)(ocg * 4 + e) * LOUT + p] = packh(y0, y1);
        }
      }
    }
  }
}

__global__ void k_fc0(const float* __restrict__ xconv, const float* __restrict__ xgru,
                      const float* __restrict__ r, const float* __restrict__ W,
                      const float* __restrict__ bias, float* __restrict__ hm) {
  __shared__ float feat[512];
  int b = blockIdx.x, t = threadIdx.x;
  if (t < 128) { feat[t] = xconv[b * 128 + t] * (1.f / (float)CL3); feat[128 + t] = xgru[b * 128 + t]; }
  feat[256 + t] = r[b * 256 + t];
  __syncthreads();
  float acc = bias[t];
  for (int k = 0; k < 512; k++) acc += feat[k] * W[k * 256 + t];
  hm[b * 256 + t] = acc;
}

__global__ void k_bn(const float* __restrict__ hm, const float* __restrict__ gamma,
                     const float* __restrict__ beta, float* __restrict__ out) {
  __shared__ float red[256];
  int n = blockIdx.x, t = threadIdx.x;
  float v = hm[t * 256 + n];
  red[t] = v; __syncthreads();
  for (int s = 128; s > 0; s >>= 1) { if (t < s) red[t] += red[t + s]; __syncthreads(); }
  float mean = red[0] / 256.f; __syncthreads();
  float dv = v - mean;
  red[t] = dv * dv; __syncthreads();
  for (int s = 128; s > 0; s >>= 1) { if (t < s) red[t] += red[t + s]; __syncthreads(); }
  float var = red[0] / 256.f;
  float y = gamma[n] * dv * (1.f / sqrtf(var + 1e-5f)) + beta[n];
  out[t * 256 + n] = y < 0.f ? 0.01f * y : y;
}

__global__ void k_fc1(const float* __restrict__ hmn, const float* __restrict__ W,
                      const float* __restrict__ bias, float* __restrict__ z) {
  __shared__ float hs[256];
  int b = blockIdx.x, t = threadIdx.x;
  hs[t] = hmn[b * 256 + t]; hs[128 + t] = hmn[b * 256 + 128 + t];
  __syncthreads();
  float acc = bias[t];
  for (int k = 0; k < 256; k++) acc += hs[k] * W[k * 128 + t];
  z[b * 128 + t] = acc;
}

// attention logits: grid (8 classes x 4 sample-tiles of 64), tiled GEMM + tanh/W2 epilogue.
__global__ __launch_bounds__(256) void k_att1(const float* __restrict__ z,
                                              const float* __restrict__ W1,
                                              const float* __restrict__ b1,
                                              const float* __restrict__ W2,
                                              float* __restrict__ logits) {
  __shared__ float sa[32][64];
  __shared__ float sb[32][64];
  int c = blockIdx.x >> 2;
  int m0 = (blockIdx.x & 3) * 64;
  const float* B = W1 + (size_t)c * 128 * AT;
  int tx = threadIdx.x & 15, ty = threadIdx.x >> 4;
  float acc[4][4];
  #pragma unroll
  for (int i = 0; i < 4; i++)
    #pragma unroll
    for (int j = 0; j < 4; j++) acc[i][j] = 0.f;
  int arow = threadIdx.x >> 2;
  int acol = (threadIdx.x & 3) * 8;
  int brow = threadIdx.x >> 4;
  int bcol = (threadIdx.x & 15) * 4;
  for (int k0 = 0; k0 < 128; k0 += 32) {
    float4 av0 = *(const float4*)&z[(size_t)(m0 + arow) * 128 + k0 + acol];
    float4 av1 = *(const float4*)&z[(size_t)(m0 + arow) * 128 + k0 + acol + 4];
    float4 bv0 = *(const float4*)&B[(size_t)(k0 + brow) * AT + bcol];
    float4 bv1 = *(const float4*)&B[(size_t)(k0 + brow + 16) * AT + bcol];
    __syncthreads();
    sa[acol + 0][arow] = av0.x; sa[acol + 1][arow] = av0.y;
    sa[acol + 2][arow] = av0.z; sa[acol + 3][arow] = av0.w;
    sa[acol + 4][arow] = av1.x; sa[acol + 5][arow] = av1.y;
    sa[acol + 6][arow] = av1.z; sa[acol + 7][arow] = av1.w;
    *(float4*)&sb[brow][bcol] = bv0;
    *(float4*)&sb[brow + 16][bcol] = bv1;
    __syncthreads();
    #pragma unroll
    for (int kk = 0; kk < 32; kk++) {
      float4 a4 = *(const float4*)&sa[kk][ty * 4];
      float4 b4 = *(const float4*)&sb[kk][tx * 4];
      acc[0][0] += a4.x * b4.x; acc[0][1] += a4.x * b4.y; acc[0][2] += a4.x * b4.z; acc[0][3] += a4.x * b4.w;
      acc[1][0] += a4.y * b4.x; acc[1][1] += a4.y * b4.y; acc[1][2] += a4.y * b4.z; acc[1][3] += a4.y * b4.w;
      acc[2][0] += a4.z * b4.x; acc[2][1] += a4.z * b4.y; acc[2][2] += a4.z * b4.z; acc[2][3] += a4.z * b4.w;
      acc[3][0] += a4.w * b4.x; acc[3][1] += a4.w * b4.y; acc[3][2] += a4.w * b4.z; acc[3][3] += a4.w * b4.w;
    }
  }
  const float* b1c = b1 + c * AT;
  const float* w2c = W2 + c * AT;
  float w2v[4], b1v[4];
  #pragma unroll
  for (int j = 0; j < 4; j++) { w2v[j] = w2c[tx * 4 + j]; b1v[j] = b1c[tx * 4 + j]; }
  #pragma unroll
  for (int i = 0; i < 4; i++) {
    float s = 0.f;
    #pragma unroll
    for (int j = 0; j < 4; j++) s += tanhf(acc[i][j] + b1v[j]) * w2v[j];
    #pragma unroll
    for (int o = 8; o > 0; o >>= 1) s += __shfl_xor(s, o, 64);
    if (tx == 0) logits[c * 256 + m0 + ty * 4 + i] = s;
  }
}

// masked softmax over samples + prototype
__global__ void k_att2(const float* __restrict__ z, const int* __restrict__ labels,
                       const int* __restrict__ idx_train, int ntrain,
                       const float* __restrict__ logits, const float* __restrict__ b2,
                       float* __restrict__ protos) {
  __shared__ float wv[256], red[256];
  __shared__ int trainm[256];
  int c = blockIdx.x, n = threadIdx.x;
  trainm[n] = 0; __syncthreads();
  if (n < ntrain) trainm[idx_train[n]] = 1;
  __syncthreads();
  bool keep = trainm[n] && (labels[n] == c);
  float ml = keep ? (logits[c * 256 + n] + b2[c]) : -1e30f;
  red[n] = ml; __syncthreads();
  for (int s = 128; s > 0; s >>= 1) { if (n < s) red[n] = fmaxf(red[n], red[n + s]); __syncthreads(); }
  float mx = red[0]; __syncthreads();
  float e = expf(ml - mx);
  wv[n] = e; red[n] = e; __syncthreads();
  for (int s = 128; s > 0; s >>= 1) { if (n < s) red[n] += red[n + s]; __syncthreads(); }
  float ssum = red[0]; __syncthreads();
  wv[n] = wv[n] / ssum;
  __syncthreads();
  if (n < 128) {
    float p = 0.f;
    for (int q = 0; q < 256; q++) p += wv[q] * z[q * 128 + n];
    protos[c * 128 + n] = p;
  }
}

// distances; block BB does the prototype-pair term (shuffle-only, no barrier)
__global__ void k_dist(const float* __restrict__ z, const float* __restrict__ protos,
                       float* __restrict__ dout) {
  if (blockIdx.x == BB) {
    int t = threadIdx.x;
    if (t < 64) {
      int i = t >> 3, jx = t & 7;
      float dot = 0.f, p2i = 0.f, p2j = 0.f;
      for (int d = 0; d < 128; d++) {
        float a = protos[i * 128 + d], bb2 = protos[jx * 128 + d];
        dot += a * bb2; p2i += a * a; p2j += bb2 * bb2;
      }
      float d2 = fmaxf(p2i + p2j - 2.f * dot, 1e-12f);
      float e = expf(-0.5f * sqrtf(d2));
      e = warp_red_sum(e);
      if (t == 0) dout[2048] = e / 28.f;
    }
    return;
  }
  __shared__ float zs[128], red[128];
  int n = blockIdx.x, t = threadIdx.x;
  zs[t] = z[n * 128 + t];
  red[t] = zs[t] * zs[t]; __syncthreads();
  for (int s = 64; s > 0; s >>= 1) { if (t < s) red[t] += red[t + s]; __syncthreads(); }
  float z2 = red[0];
  if (t < NC) {
    float dot = 0.f, p2 = 0.f;
    const float* pr = protos + t * 128;
    for (int d = 0; d < 128; d++) { float pv = pr[d]; dot += pv * zs[d]; p2 += pv * pv; }
    float d2 = fmaxf(z2 + p2 - 2.f * dot, 1e-12f);
    dout[n * NC + t] = expf(-0.5f * sqrtf(d2));
  }
}

extern "C" void kernel_launch(void* const* d_in, const int* in_sizes, int n_in,
                              void* d_out, int out_size, void* d_ws, size_t ws_size,
                              hipStream_t stream) {
  const float* x = (const float*)d_in[0];
  const int* labels = (const int*)d_in[1];
  const int* idx_train = (const int*)d_in[2];
  const float* gat_W = (const float*)d_in[3];
  const float* gat_a1 = (const float*)d_in[4];
  const float* gat_a2 = (const float*)d_in[5];
  const float* gcnW[3] = {(const float*)d_in[6], (const float*)d_in[8], (const float*)d_in[10]};
  const float* gcnB[3] = {(const float*)d_in[7], (const float*)d_in[9], (const float*)d_in[11]};
  const float* pw1[3] = {(const float*)d_in[12], (const float*)d_in[15], (const float*)d_in[18]};
  const float* pw2[3] = {(const float*)d_in[13], (const float*)d_in[16], (const float*)d_in[19]};
  const float* pbb[3] = {(const float*)d_in[14], (const float*)d_in[17], (const float*)d_in[20]};
  const float* wih = (const float*)d_in[21];
  const float* whh = (const float*)d_in[22];
  const float* bih = (const float*)d_in[23];
  const float* bhh = (const float*)d_in[24];
  const float* c1W = (const float*)d_in[25]; const float* c1b = (const float*)d_in[26];
  const float* c2W = (const float*)d_in[27]; const float* c2b = (const float*)d_in[28];
  const float* c3W = (const float*)d_in[29]; const float* c3b = (const float*)d_in[30];
  const float* fc0W = (const float*)d_in[31]; const float* fc0b = (const float*)d_in[32];
  const float* bn0g = (const float*)d_in[33]; const float* bn0b = (const float*)d_in[34];
  const float* fc1W = (const float*)d_in[35]; const float* fc1b = (const float*)d_in[36];
  const float* aW1 = (const float*)d_in[37]; const float* ab1 = (const float*)d_in[38];
  const float* aW2 = (const float*)d_in[39]; const float* ab2 = (const float*)d_in[40];
  float* out = (float*)d_out;
  float* ws = (float*)d_ws;

  // ---- workspace layout (floats). Z region reused by 3 sequential phases. ----
  size_t off = 0;
  auto take = [&](size_t n) { size_t o = off; off += (n + 63) & ~(size_t)63; return o; };
  float* wa1   = ws + take(512);
  float* wa2   = ws + take(512);
  float* ha1   = ws + take(BB * CC);
  float* ha2   = ws + take(BB * CC);
  float* dinv  = ws + take(BB * 64);
  float* rbuf  = ws + take(BB * 256);
  float* xgru  = ws + take(BB * 128);
  float* xconv = ws + take(BB * 128);
  float* hm    = ws + take(BB * 256);
  float* hmn   = ws + take(BB * 256);
  float* zb    = ws + take(BB * 128);
  float* protos = ws + take(NC * 128);
  float* lgts  = ws + take(NC * 256);
  float* gw1h  = ws + take(256 * 128);       // packed h2 gcnW[0]
  float* wpkf  = ws + take(192 * 128);       // packed h2 whh for k_gru
  float* wslot = ws + take(512 * 384);       // wihT_h (GRU) then conv weights
  float* Z     = ws + take(8568832);
  // GNN-phase aliases
  float* mA  = Z;
  float* mB  = Z + 1048576;
  float* xw  = Z + 2097152;
  float* gb  = Z + 4194304;
  float* gp1 = Z + 6291456;
  float* gp2 = Z + 7340032;
  // GRU-phase aliases
  float* gi = Z;
  float* ys = Z + 6291456;
  // conv-phase aliases (2 chunks of 128 samples, packed h2 activations)
  float* cv1 = Z;                     // 128*64*519 u32 = 4251648
  float* cv2 = Z + 4251648;           // 128*64*527 u32 = 4317184  (sum = 8568832 exactly)
  unsigned int* wpk = (unsigned int*)wpkf;
  unsigned int* wihTh = (unsigned int*)wslot;            // 256x384 u32
  unsigned int* wt1h = (unsigned int*)wslot;             // 32*8*128 = 32768 (after gemmh gi)
  unsigned int* wt2h = wt1h + 32768;                     // 64*5*128 = 40960
  unsigned int* wt3h = wt2h + 40960;                     // 64*3*128 = 24576

  hipMemsetAsync(rbuf, 0, BB * 256 * sizeof(float), stream);
  hipMemsetAsync(xconv, 0, BB * 128 * sizeof(float), stream);

  // ---- GAT adjacency (fused dinv for stage 0) ----
  k_wa<<<8, 64, 0, stream>>>(gat_W, gat_a1, gat_a2, wa1, wa2);
  k_ha<<<BB * CC / 4, 256, 0, stream>>>(x, wa1, wa2, ha1, ha2);
  k_softmask<<<BB * 64 / 4, 256, 0, stream>>>(ha1, ha2, mA, dinv);

  // ---- 3x (GCN + SAGPool); pool computes next stage's dinv ----
  k_pack_h<<<(256 * 128 + 255) / 256, 256, 0, stream>>>(gcnW[0], (unsigned int*)gw1h, 512, 128);
  const int Ns[3] = {64, 32, 16};
  const int ks[3] = {32, 16, 8};
  const float* gins[3] = {x, gp1, gp2};
  float* mcur[3] = {mA, mB, mA};
  float* mnxt[3] = {mB, mA, mB};
  float* gps[3]  = {gp1, gp2, nullptr};
  for (int s = 0; s < 3; s++) {
    int N = Ns[s];
    if (s == 0) {
      k_gemmh<<<(BB * CC / 64) * (HH / 64), 256, 0, stream>>>(
          x, (unsigned int*)gw1h, xw, BB * CC, HH, LL);
    } else {
      k_xw<<<BB * N, 128, 0, stream>>>(gins[s], gcnW[s], xw, N, 128);
    }
    k_gcnagg<<<BB * N, 128, 0, stream>>>(xw, mcur[s], dinv, gcnB[s], gb, N);
    k_pool<<<BB, 256, 0, stream>>>(gb, mcur[s], pw1[s], pw2[s], pbb[s], N, ks[s],
                                   gps[s], mnxt[s], s < 2 ? dinv : nullptr, rbuf);
  }

  // ---- GRU branch ----
  k_packT_h<<<(256 * 384 + 255) / 256, 256, 0, stream>>>(wih, wihTh, 384, 512);
  k_packgru<<<(192 * 128 + 255) / 256, 256, 0, stream>>>(whh, wpk);
  k_gemmh<<<(BB * CC / 64) * (G3 / 64), 256, 0, stream>>>(x, wihTh, gi, BB * CC, G3, LL);
  k_gru<<<CC, 128, 0, stream>>>(gi, wpk, bhh, bih, ys);
  k_grumean<<<BB, 128, 0, stream>>>(ys, xgru);

  // ---- dilated conv branch: 2 chunks of 128 samples ----
  k_packcw_all<<<384, 256, 0, stream>>>(c1W, c2W, c3W, wt1h, wt2h, wt3h);
  for (int bc = 0; bc < 2; bc++) {
    int b0 = bc * 128;
    k_convh<64, 8, 1, 7, 512, CL1, 0, 2><<<128 * 9, 128, 0, stream>>>(
        x + (size_t)b0 * CC * LL, wt1h, c1b, cv1, b0);
    k_convh<128, 5, 2, 8, CL1, CL2, 1, 4><<<128 * 9, 128, 0, stream>>>(
        cv1, wt2h, c2b, cv2, b0);
    k_convh<128, 3, 4, 8, CL2, CL3, 2, 8><<<128 * 9, 128, 0, stream>>>(
        cv2, wt3h, c3b, xconv, b0);
  }

  // ---- mapping MLP + BN + attention prototypes + distances ----
  k_fc0<<<BB, 256, 0, stream>>>(xconv, xgru, rbuf, fc0W, fc0b, hm);
  k_bn<<<256, 256, 0, stream>>>(hm, bn0g, bn0b, hmn);
  k_fc1<<<BB, 128, 0, stream>>>(hmn, fc1W, fc1b, zb);
  k_att1<<<NC * 4, 256, 0, stream>>>(zb, aW1, ab1, aW2, lgts);
  k_att2<<<NC, 256, 0, stream>>>(zb, labels, idx_train, in_sizes[2], lgts, ab2, protos);
  k_dist<<<BB + 1, 128, 0, stream>>>(zb, protos, out);
}

// Round 7
// 638.948 us; speedup vs baseline: 15.9770x; 2.4306x over previous
//
#include <hip/hip_runtime.h>
#include <math.h>

#define BB 256   // batch
#define CC 64    // channels / graph nodes
#define LL 512   // series length
#define HH 128   // gcn hidden
#define G3 384   // 3*gru_dim
#define NC 8
#define AT 64
#define CL1 519
#define CL2 527
#define CL3 535
#define THRESH 0.02f

typedef _Float16 h2 __attribute__((ext_vector_type(2)));
typedef _Float16 f16x8 __attribute__((ext_vector_type(8)));
typedef float f32x4 __attribute__((ext_vector_type(4)));
union HU { unsigned int u; h2 h; float f; };
union BU { uint4 u; f16x8 h; };

__device__ inline float warp_red_sum(float v) {
  #pragma unroll
  for (int o = 32; o > 0; o >>= 1) v += __shfl_down(v, o, 64);
  return v;
}
__device__ inline float warp_allred_max(float v) {
  #pragma unroll
  for (int o = 32; o > 0; o >>= 1) v = fmaxf(v, __shfl_xor(v, o, 64));
  return v;
}
__device__ inline float warp_allred_sum(float v) {
  #pragma unroll
  for (int o = 32; o > 0; o >>= 1) v += __shfl_xor(v, o, 64);
  return v;
}

__device__ inline float fdot2f(h2 a, h2 b, float c) {
#if __has_builtin(__builtin_amdgcn_fdot2)
  return __builtin_amdgcn_fdot2(a, b, c, false);
#else
  float r;
  asm volatile("v_dot2_f32_f16 %0, %1, %2, %3" : "=v"(r) : "v"(a), "v"(b), "v"(c));
  return r;
#endif
}
__device__ inline h2 asH2(float f) { HU u; u.f = f; return u.h; }
__device__ inline h2 uH2(unsigned int x) { HU u; u.u = x; return u.h; }
__device__ inline unsigned int packh(float a, float b) {
  HU u; h2 t; t.x = (_Float16)a; t.y = (_Float16)b; u.h = t; return u.u;
}

// wa = gat_W @ a  (512-vector)
__global__ void k_wa(const float* __restrict__ gatW, const float* __restrict__ a1,
                     const float* __restrict__ a2, float* wa1, float* wa2) {
  int l = blockIdx.x * 64 + threadIdx.x;
  const float* row = gatW + l * LL;
  float s1 = 0.f, s2 = 0.f;
  for (int k = 0; k < LL; k++) { float w = row[k]; s1 += w * a1[k]; s2 += w * a2[k]; }
  wa1[l] = s1; wa2[l] = s2;
}

// ha1[b,c] = x[b,c,:].wa1 ; ha2 likewise. one wave per row.
__global__ void k_ha(const float* __restrict__ x, const float* __restrict__ wa1,
                     const float* __restrict__ wa2, float* ha1, float* ha2) {
  int wid = threadIdx.x >> 6, lane = threadIdx.x & 63;
  int row = blockIdx.x * 4 + wid;
  const float* xr = x + (size_t)row * LL;
  float s1 = 0.f, s2 = 0.f;
  for (int q = lane; q < LL; q += 64) { float v = xr[q]; s1 += v * wa1[q]; s2 += v * wa2[q]; }
  s1 = warp_red_sum(s1); s2 = warp_red_sum(s2);
  if (lane == 0) { ha1[row] = s1; ha2[row] = s2; }
}

// softmax row -> mask; fused dinv0 (row degree)
__global__ void k_softmask(const float* __restrict__ ha1, const float* __restrict__ ha2,
                           float* __restrict__ mask, float* __restrict__ dinv) {
  int wid = threadIdx.x >> 6, lane = threadIdx.x & 63;
  int row = blockIdx.x * 4 + wid;       // row = b*64+i
  int b = row >> 6;
  float e = ha1[row] + ha2[b * 64 + lane];
  e = e < 0.f ? 0.2f * e : e;
  float mx = warp_allred_max(e);
  float ex = expf(e - mx);
  float sm = warp_allred_sum(ex);
  float A = ex / sm;
  float mval = (A > THRESH) ? 1.0f : 0.0f;
  mask[(size_t)row * 64 + lane] = mval;
  float cnt = warp_allred_sum(mval);
  if (lane == 0) dinv[row] = 1.0f / sqrtf(cnt + 1.0f);
}

// ---- packing kernels ----
__global__ void k_packT_h(const float* __restrict__ W, unsigned int* __restrict__ out,
                          int R, int Lc) {
  int idx = blockIdx.x * 256 + threadIdx.x;
  int half = Lc >> 1;
  if (idx >= R * half) return;
  int k2 = idx / R, j = idx % R;
  out[idx] = packh(W[j * Lc + 2 * k2], W[j * Lc + 2 * k2 + 1]);
}
__global__ void k_pack_h(const float* __restrict__ W, unsigned int* __restrict__ out,
                         int K, int N) {
  int idx = blockIdx.x * 256 + threadIdx.x;
  if (idx >= (K >> 1) * N) return;
  int k2 = idx / N, n = idx % N;
  out[idx] = packh(W[(2 * k2) * N + n], W[(2 * k2 + 1) * N + n]);
}
__global__ void k_packgru(const float* __restrict__ whh, unsigned int* __restrict__ out) {
  int idx = blockIdx.x * 256 + threadIdx.x;
  if (idx >= 192 * 128) return;
  int j = idx & 127, rk = idx >> 7;
  int r = rk >> 6, k2 = rk & 63;
  const float* src = whh + (size_t)(j + 128 * r) * 128 + 2 * k2;
  out[idx] = packh(src[0], src[1]);
}

// conv weights -> MFMA B-fragment-linear layout.
// u32 idx decode: w=idx&3, l=(idx>>2)&63, n=(idx>>8)&7, c=idx>>11.
// oc = n*16+(l&15); k = c*32 + ((l>>4)<<3) + 2w (+0/+1); t = k>>cinlog; ci = k&(CIN-1).
__device__ inline void packw_one(const float* __restrict__ W, unsigned int* __restrict__ out,
                                 int idx, int cinlog, int KS) {
  int w_ = idx & 3, l = (idx >> 2) & 63, n = (idx >> 8) & 7, c = idx >> 11;
  int CIN = 1 << cinlog;
  int oc = n * 16 + (l & 15);
  int k0 = c * 32 + ((l >> 4) << 3) + 2 * w_;
  int t0 = k0 >> cinlog, ci0 = k0 & (CIN - 1);
  int t1 = (k0 + 1) >> cinlog, ci1 = (k0 + 1) & (CIN - 1);
  out[idx] = packh(W[(size_t)oc * CIN * KS + ci0 * KS + t0],
                   W[(size_t)oc * CIN * KS + ci1 * KS + t1]);
}
__global__ void k_packw_mfma(const float* __restrict__ c1W, const float* __restrict__ c2W,
                             const float* __restrict__ c3W, unsigned int* o1,
                             unsigned int* o2, unsigned int* o3) {
  int idx = blockIdx.x * 256 + threadIdx.x;
  if (idx < 32768) packw_one(c1W, o1, idx, 6, 8);
  else if (idx < 73728) packw_one(c2W, o2, idx - 32768, 7, 5);
  else if (idx < 98304) packw_one(c3W, o3, idx - 73728, 7, 3);
}

// f16-dot2 tiled GEMM: C[M,N] = A[M,K] @ B[K,N]
__global__ __launch_bounds__(256) void k_gemmh(const float* __restrict__ A,
                                               const unsigned int* __restrict__ Bh,
                                               float* __restrict__ C,
                                               int M, int N, int K) {
  __shared__ unsigned int sah[16][64];
  __shared__ unsigned int sbh[16][64];
  int nbn = N >> 6;
  int bm = blockIdx.x / nbn, bn = blockIdx.x % nbn;
  int m0 = bm * 64, n0 = bn * 64;
  int tx = threadIdx.x & 15, ty = threadIdx.x >> 4;
  float acc[4][4];
  #pragma unroll
  for (int i = 0; i < 4; i++)
    #pragma unroll
    for (int j = 0; j < 4; j++) acc[i][j] = 0.f;
  int arow = threadIdx.x >> 2;
  int acol = (threadIdx.x & 3) * 8;
  int brow = threadIdx.x >> 4;
  int bcol = (threadIdx.x & 15) * 4;
  for (int k0 = 0; k0 < K; k0 += 32) {
    float4 av0 = *(const float4*)&A[(size_t)(m0 + arow) * K + k0 + acol];
    float4 av1 = *(const float4*)&A[(size_t)(m0 + arow) * K + k0 + acol + 4];
    uint4 bv = *(const uint4*)&Bh[(size_t)((k0 >> 1) + brow) * N + n0 + bcol];
    __syncthreads();
    int ac2 = acol >> 1;
    sah[ac2 + 0][arow] = packh(av0.x, av0.y);
    sah[ac2 + 1][arow] = packh(av0.z, av0.w);
    sah[ac2 + 2][arow] = packh(av1.x, av1.y);
    sah[ac2 + 3][arow] = packh(av1.z, av1.w);
    *(uint4*)&sbh[brow][bcol] = bv;
    __syncthreads();
    #pragma unroll
    for (int kk = 0; kk < 16; kk++) {
      uint4 a4 = *(const uint4*)&sah[kk][ty * 4];
      uint4 b4 = *(const uint4*)&sbh[kk][tx * 4];
      h2 ax = uH2(a4.x), ay = uH2(a4.y), az = uH2(a4.z), aw = uH2(a4.w);
      h2 bx = uH2(b4.x), by = uH2(b4.y), bz = uH2(b4.z), bw = uH2(b4.w);
      acc[0][0] = fdot2f(ax, bx, acc[0][0]); acc[0][1] = fdot2f(ax, by, acc[0][1]);
      acc[0][2] = fdot2f(ax, bz, acc[0][2]); acc[0][3] = fdot2f(ax, bw, acc[0][3]);
      acc[1][0] = fdot2f(ay, bx, acc[1][0]); acc[1][1] = fdot2f(ay, by, acc[1][1]);
      acc[1][2] = fdot2f(ay, bz, acc[1][2]); acc[1][3] = fdot2f(ay, bw, acc[1][3]);
      acc[2][0] = fdot2f(az, bx, acc[2][0]); acc[2][1] = fdot2f(az, by, acc[2][1]);
      acc[2][2] = fdot2f(az, bz, acc[2][2]); acc[2][3] = fdot2f(az, bw, acc[2][3]);
      acc[3][0] = fdot2f(aw, bx, acc[3][0]); acc[3][1] = fdot2f(aw, by, acc[3][1]);
      acc[3][2] = fdot2f(aw, bz, acc[3][2]); acc[3][3] = fdot2f(aw, bw, acc[3][3]);
    }
  }
  #pragma unroll
  for (int i = 0; i < 4; i++) {
    float4 v = make_float4(acc[i][0], acc[i][1], acc[i][2], acc[i][3]);
    *(float4*)&C[(size_t)(m0 + ty * 4 + i) * N + n0 + tx * 4] = v;
  }
}

// xw[b,i,f] = sum_k gin[b,i,k] * W[k,f]  (small stages, K=128, fp32)
__global__ void k_xw(const float* __restrict__ gin, const float* __restrict__ W,
                     float* __restrict__ out, int N, int K) {
  __shared__ float xs[512];
  int b = blockIdx.x / N, i = blockIdx.x % N;
  const float* grow = gin + (size_t)(b * N + i) * K;
  for (int k = threadIdx.x; k < K; k += 128) xs[k] = grow[k];
  __syncthreads();
  int f = threadIdx.x;
  float a0 = 0.f, a1 = 0.f, a2 = 0.f, a3 = 0.f;
  for (int k = 0; k < K; k += 4) {
    a0 += xs[k]     * W[(k)     * HH + f];
    a1 += xs[k + 1] * W[(k + 1) * HH + f];
    a2 += xs[k + 2] * W[(k + 2) * HH + f];
    a3 += xs[k + 3] * W[(k + 3) * HH + f];
  }
  out[(size_t)(b * N + i) * HH + f] = (a0 + a1) + (a2 + a3);
}

// g[b,i,f] = relu(dinv_i*(dinv_i*xw_if + sum_j m_ij*dinv_j*xw_jf) + bias_f)
__global__ void k_gcnagg(const float* __restrict__ xw, const float* __restrict__ mask,
                         const float* __restrict__ dinv, const float* __restrict__ bias,
                         float* __restrict__ gout, int N) {
  __shared__ float mrow[64], dv[64];
  int b = blockIdx.x / N, i = blockIdx.x % N;
  if (threadIdx.x < N) {
    mrow[threadIdx.x] = mask[(size_t)(b * N + i) * N + threadIdx.x];
    dv[threadIdx.x] = dinv[b * N + threadIdx.x];
  }
  __syncthreads();
  int f = threadIdx.x;
  float di = dv[i];
  float acc = di * xw[(size_t)(b * N + i) * HH + f];
  for (int j = 0; j < N; j++) acc += mrow[j] * dv[j] * xw[(size_t)(b * N + j) * HH + f];
  float y = di * acc + bias[f];
  gout[(size_t)(b * N + i) * HH + f] = y > 0.f ? y : 0.f;
}

// fused SAGPool: LDS-staged g/mask, wave argmax top-k, gather+gate+readout, next dinv
__global__ __launch_bounds__(256) void k_pool(const float* __restrict__ g,
                                              const float* __restrict__ mask,
                                              const float* __restrict__ w1,
                                              const float* __restrict__ w2,
                                              const float* __restrict__ pb, int N, int kk,
                                              float* gp, float* mnext, float* dnext,
                                              float* __restrict__ r) {
  __shared__ float gs[64 * 129];
  __shared__ float ms[64 * 65];
  __shared__ float d1s[64], d2s[64], sv[64], vals[32], tvs[32];
  __shared__ int idxs[32];
  int b = blockIdx.x, tid = threadIdx.x;
  for (int q = tid; q < N * 128; q += 256) {
    int row = q >> 7, d = q & 127;
    gs[row * 129 + d] = g[(size_t)(b * N + row) * 128 + d];
  }
  for (int q = tid; q < N * N; q += 256) {
    int row = q / N, u = q - row * N;
    ms[row * 65 + u] = mask[(size_t)(b * N + row) * N + u];
  }
  __syncthreads();
  if (tid < N) {
    float a = 0.f, c = 0.f;
    const float* gr = &gs[tid * 129];
    for (int d = 0; d < 128; d++) { float v = gr[d]; a += v * w1[d]; c += v * w2[d]; }
    d1s[tid] = a; d2s[tid] = c;
  }
  __syncthreads();
  if (tid < N) {
    const float* mr = &ms[tid * 65];
    float s = d1s[tid] + pb[0];
    for (int j = 0; j < N; j++) s += mr[j] * d2s[j];
    sv[tid] = s;
  }
  __syncthreads();
  if (tid < 64) {
    float myv = (tid < N) ? sv[tid] : -3.4e38f;
    int alive = (tid < N) ? 1 : 0;
    for (int t = 0; t < kk; t++) {
      float cv = alive ? myv : -3.4e38f;
      int ci = tid;
      #pragma unroll
      for (int o = 32; o > 0; o >>= 1) {
        float ov = __shfl_xor(cv, o, 64);
        int oi = __shfl_xor(ci, o, 64);
        if (ov > cv || (ov == cv && oi < ci)) { cv = ov; ci = oi; }
      }
      if (tid == ci) alive = 0;
      if (tid == 0) { idxs[t] = ci; vals[t] = cv; }
    }
  }
  __syncthreads();
  if (tid < kk) tvs[tid] = tanhf(vals[tid]);
  __syncthreads();
  if (tid < HH) {
    float mx = -3.4e38f, sm = 0.f;
    for (int t = 0; t < kk; t++) {
      float v = gs[idxs[t] * 129 + tid] * tvs[t];
      if (gp) gp[(size_t)(b * kk + t) * HH + tid] = v;
      mx = fmaxf(mx, v); sm += v;
    }
    r[b * 256 + tid] += mx;
    r[b * 256 + 128 + tid] += sm / (float)kk;
  }
  for (int q = tid; q < kk * kk; q += 256) {
    int t = q / kk, u = q - t * kk;
    mnext[(size_t)(b * kk + t) * kk + u] = ms[idxs[t] * 65 + idxs[u]];
  }
  if (dnext && tid < kk) {
    float s = 0.f;
    for (int u = 0; u < kk; u++) s += ms[idxs[tid] * 65 + idxs[u]];
    dnext[b * kk + tid] = 1.0f / sqrtf(s + 1.0f);
  }
}

// GRU recurrence: 128 threads/block; thread j owns gate rows j, j+128, j+256.
__global__ __launch_bounds__(128, 1) void k_gru(const float* __restrict__ gi,
                                                const unsigned int* __restrict__ wpk,
                                                const float* __restrict__ bhh,
                                                const float* __restrict__ bih,
                                                float* __restrict__ ys) {
  __shared__ _Float16 hb[2][128];
  int c = blockIdx.x, j = threadIdx.x;
  h2 w0[64], w1[64], w2[64];
  #pragma unroll
  for (int k2 = 0; k2 < 64; k2++) { HU u; u.u = wpk[k2 * 128 + j]; w0[k2] = u.h; }
  #pragma unroll
  for (int k2 = 0; k2 < 64; k2++) { HU u; u.u = wpk[(64 + k2) * 128 + j]; w1[k2] = u.h; }
  #pragma unroll
  for (int k2 = 0; k2 < 64; k2++) { HU u; u.u = wpk[(128 + k2) * 128 + j]; w2[k2] = u.h; }
  float bh0 = bhh[j], bh1 = bhh[j + 128], bh2 = bhh[j + 256];
  float bi0 = bih[j], bi1 = bih[j + 128], bi2 = bih[j + 256];
  float hprev = 0.f;
  hb[0][j] = (_Float16)0.f;
  __syncthreads();
  const float* gbase = gi + (size_t)c * G3 + j;
  float g0 = gbase[0], g1 = gbase[128], g2 = gbase[256];
  int cur = 0;
  for (int b = 0; b < BB; b++) {
    float n0 = 0.f, n1 = 0.f, n2 = 0.f;
    if (b + 1 < BB) {
      const float* gn = gbase + (size_t)(b + 1) * CC * G3;
      n0 = gn[0]; n1 = gn[128]; n2 = gn[256];
    }
    float a0a = 0.f, a0b = 0.f, a1a = 0.f, a1b = 0.f, a2a = 0.f, a2b = 0.f;
    #pragma unroll
    for (int q = 0; q < 16; q++) {
      float4 hv = *(const float4*)&hb[cur][q * 8];
      h2 h0 = asH2(hv.x), h1 = asH2(hv.y), h2v = asH2(hv.z), h3 = asH2(hv.w);
      a0a = fdot2f(w0[q * 4 + 0], h0, a0a); a0b = fdot2f(w0[q * 4 + 1], h1, a0b);
      a0a = fdot2f(w0[q * 4 + 2], h2v, a0a); a0b = fdot2f(w0[q * 4 + 3], h3, a0b);
      a1a = fdot2f(w1[q * 4 + 0], h0, a1a); a1b = fdot2f(w1[q * 4 + 1], h1, a1b);
      a1a = fdot2f(w1[q * 4 + 2], h2v, a1a); a1b = fdot2f(w1[q * 4 + 3], h3, a1b);
      a2a = fdot2f(w2[q * 4 + 0], h0, a2a); a2b = fdot2f(w2[q * 4 + 1], h1, a2b);
      a2a = fdot2f(w2[q * 4 + 2], h2v, a2a); a2b = fdot2f(w2[q * 4 + 3], h3, a2b);
    }
    float A0 = a0a + a0b + bh0;
    float A1 = a1a + a1b + bh1;
    float A2 = a2a + a2b + bh2;
    float rg = 1.f / (1.f + expf(-(g0 + bi0 + A0)));
    float zg = 1.f / (1.f + expf(-(g1 + bi1 + A1)));
    float ng = tanhf(g2 + bi2 + rg * A2);
    float hn = (1.f - zg) * ng + zg * hprev;
    ys[(size_t)(b * CC + c) * 128 + j] = hn;
    hprev = hn;
    hb[cur ^ 1][j] = (_Float16)hn;
    __syncthreads();
    cur ^= 1;
    g0 = n0; g1 = n1; g2 = n2;
  }
}

__global__ void k_grumean(const float* __restrict__ ys, float* __restrict__ xgru) {
  int b = blockIdx.x, u = threadIdx.x;
  float acc = 0.f;
  for (int c = 0; c < CC; c++) acc += ys[(size_t)(b * CC + c) * 128 + u];
  xgru[b * 128 + u] = acc / 64.f;
}

// ---------------- MFMA implicit-GEMM conv ----------------
// Activations [pos][ci] f16 (conv1 converts fp32 [ci][pos] on stage-in).
// k ordering t-major: k = t*CIN + ci. A frag (lane l): row=pos=l&15, k=(l>>4)*8+j ->
// one ds_read_b128 from the staged window. B frags pre-packed fragment-linear in
// global (L2-resident), streamed with 1-chunk prefetch. Wave = 64 pos x 32 oc.
// MODE 0: fp32 in, f16 out. MODE 1: f16 in, f16 out. MODE 2: f16 in, relu+mean atomic.
template<int CIN, int KS, int DIL, int PAD, int LIN, int LOUT, int MODE>
__global__ __launch_bounds__(256) void k_cmfma(const void* __restrict__ inv,
                                               const uint4* __restrict__ Bf,
                                               const float* __restrict__ bias,
                                               void* __restrict__ outv, int b0) {
  constexpr int QN = CIN / 32;          // k-chunks per tap
  constexpr int NCH = KS * QN;
  constexpr int SLOTS = CIN / 8;        // 16B slots per row
  constexpr int NT = (LOUT + 63) / 64;
  __shared__ _Float16 xs[72 * CIN];
  int nb = blockIdx.x / NT;
  int p0 = (blockIdx.x % NT) * 64;
  int tid = threadIdx.x;
  int l = tid & 63, w = tid >> 6;

  // ---- stage input window rows [p0-PAD, p0-PAD+71], XOR-swizzled 16B slots ----
  if constexpr (MODE == 0) {
    const float* src = (const float*)inv + (size_t)nb * CIN * LIN;
    for (int q = tid; q < (CIN / 2) * 72; q += 256) {
      int ci2 = q / 72, r = q % 72;
      int ci = 2 * ci2;
      int p = p0 - PAD + r;
      float v0 = 0.f, v1 = 0.f;
      if (p >= 0 && p < LIN) { v0 = src[ci * LIN + p]; v1 = src[(ci + 1) * LIN + p]; }
      int slot = ci >> 3;
      int phys = slot ^ (r & 7);
      *(unsigned int*)&xs[r * CIN + phys * 8 + (ci & 7)] = packh(v0, v1);
    }
  } else {
    const _Float16* src = (const _Float16*)inv + (size_t)nb * LIN * CIN;
    for (int q = tid; q < 72 * SLOTS; q += 256) {
      int r = q / SLOTS, s = q % SLOTS;
      int p = p0 - PAD + r;
      uint4 v = make_uint4(0u, 0u, 0u, 0u);
      if (p >= 0 && p < LIN) v = *(const uint4*)&src[(size_t)p * CIN + s * 8];
      int phys = s ^ (r & 7);
      *(uint4*)&xs[r * CIN + phys * 8] = v;
    }
  }
  __syncthreads();

  // ---- K loop: no barriers; B streamed from global with 1-chunk prefetch ----
  int n0 = 2 * w, n1 = n0 + 1;
  f32x4 acc[4][2];
  #pragma unroll
  for (int m = 0; m < 4; m++) {
    acc[m][0] = (f32x4){0.f, 0.f, 0.f, 0.f};
    acc[m][1] = (f32x4){0.f, 0.f, 0.f, 0.f};
  }
  uint4 bc0 = Bf[(size_t)(0 * 8 + n0) * 64 + l];
  uint4 bc1 = Bf[(size_t)(0 * 8 + n1) * 64 + l];
  for (int c = 0; c < NCH; c++) {
    uint4 bn0 = bc0, bn1 = bc1;
    if (c + 1 < NCH) {
      bn0 = Bf[(size_t)((c + 1) * 8 + n0) * 64 + l];
      bn1 = Bf[(size_t)((c + 1) * 8 + n1) * 64 + l];
    }
    int t = c / QN, q = c % QN;
    int slotbase = q * 4 + (l >> 4);
    f16x8 a[4];
    #pragma unroll
    for (int m = 0; m < 4; m++) {
      int r = m * 16 + (l & 15) + t * DIL;
      int phys = slotbase ^ (r & 7);
      a[m] = *(const f16x8*)&xs[r * CIN + phys * 8];
    }
    BU u0, u1; u0.u = bc0; u1.u = bc1;
    #pragma unroll
    for (int m = 0; m < 4; m++) {
      acc[m][0] = __builtin_amdgcn_mfma_f32_16x16x32_f16(a[m], u0.h, acc[m][0], 0, 0, 0);
      acc[m][1] = __builtin_amdgcn_mfma_f32_16x16x32_f16(a[m], u1.h, acc[m][1], 0, 0, 0);
    }
    bc0 = bn0; bc1 = bn1;
  }

  // ---- epilogue ----
  if constexpr (MODE == 2) {
    float* xcv = (float*)outv;
    #pragma unroll
    for (int n = 0; n < 2; n++) {
      int oc = (2 * w + n) * 16 + (l & 15);
      float bz = bias[oc];
      float s = 0.f;
      #pragma unroll
      for (int m = 0; m < 4; m++) {
        #pragma unroll
        for (int i = 0; i < 4; i++) {
          int pos = p0 + m * 16 + (l >> 4) * 4 + i;
          if (pos < LOUT) { float y = acc[m][n][i] + bz; s += y > 0.f ? y : 0.f; }
        }
      }
      s += __shfl_xor(s, 16, 64);
      s += __shfl_xor(s, 32, 64);
      if (l < 16) atomicAdd(&xcv[(size_t)(b0 + nb) * 128 + oc], s);
    }
  } else {
    _Float16* outp = (_Float16*)outv + (size_t)nb * LOUT * 128;
    #pragma unroll
    for (int n = 0; n < 2; n++) {
      int oc = (2 * w + n) * 16 + (l & 15);
      float bz = bias[oc];
      #pragma unroll
      for (int m = 0; m < 4; m++) {
        #pragma unroll
        for (int i = 0; i < 4; i++) {
          int pos = p0 + m * 16 + (l >> 4) * 4 + i;
          if (pos < LOUT) {
            float y = acc[m][n][i] + bz;
            outp[(size_t)pos * 128 + oc] = (_Float16)(y > 0.f ? y : 0.f);
          }
        }
      }
    }
  }
}

__global__ void k_fc0(const float* __restrict__ xconv, const float* __restrict__ xgru,
                      const float* __restrict__ r, const float* __restrict__ W,
                      const float* __restrict__ bias, float* __restrict__ hm) {
  __shared__ float feat[512];
  int b = blockIdx.x, t = threadIdx.x;
  if (t < 128) { feat[t] = xconv[b * 128 + t] * (1.f / (float)CL3); feat[128 + t] = xgru[b * 128 + t]; }
  feat[256 + t] = r[b * 256 + t];
  __syncthreads();
  float acc = bias[t];
  for (int k = 0; k < 512; k++) acc += feat[k] * W[k * 256 + t];
  hm[b * 256 + t] = acc;
}

__global__ void k_bn(const float* __restrict__ hm, const float* __restrict__ gamma,
                     const float* __restrict__ beta, float* __restrict__ out) {
  __shared__ float red[256];
  int n = blockIdx.x, t = threadIdx.x;
  float v = hm[t * 256 + n];
  red[t] = v; __syncthreads();
  for (int s = 128; s > 0; s >>= 1) { if (t < s) red[t] += red[t + s]; __syncthreads(); }
  float mean = red[0] / 256.f; __syncthreads();
  float dv = v - mean;
  red[t] = dv * dv; __syncthreads();
  for (int s = 128; s > 0; s >>= 1) { if (t < s) red[t] += red[t + s]; __syncthreads(); }
  float var = red[0] / 256.f;
  float y = gamma[n] * dv * (1.f / sqrtf(var + 1e-5f)) + beta[n];
  out[t * 256 + n] = y < 0.f ? 0.01f * y : y;
}

__global__ void k_fc1(const float* __restrict__ hmn, const float* __restrict__ W,
                      const float* __restrict__ bias, float* __restrict__ z) {
  __shared__ float hs[256];
  int b = blockIdx.x, t = threadIdx.x;
  hs[t] = hmn[b * 256 + t]; hs[128 + t] = hmn[b * 256 + 128 + t];
  __syncthreads();
  float acc = bias[t];
  for (int k = 0; k < 256; k++) acc += hs[k] * W[k * 128 + t];
  z[b * 128 + t] = acc;
}

// attention logits: grid (8 classes x 4 sample-tiles of 64)
__global__ __launch_bounds__(256) void k_att1(const float* __restrict__ z,
                                              const float* __restrict__ W1,
                                              const float* __restrict__ b1,
                                              const float* __restrict__ W2,
                                              float* __restrict__ logits) {
  __shared__ float sa[32][64];
  __shared__ float sb[32][64];
  int c = blockIdx.x >> 2;
  int m0 = (blockIdx.x & 3) * 64;
  const float* B = W1 + (size_t)c * 128 * AT;
  int tx = threadIdx.x & 15, ty = threadIdx.x >> 4;
  float acc[4][4];
  #pragma unroll
  for (int i = 0; i < 4; i++)
    #pragma unroll
    for (int j = 0; j < 4; j++) acc[i][j] = 0.f;
  int arow = threadIdx.x >> 2;
  int acol = (threadIdx.x & 3) * 8;
  int brow = threadIdx.x >> 4;
  int bcol = (threadIdx.x & 15) * 4;
  for (int k0 = 0; k0 < 128; k0 += 32) {
    float4 av0 = *(const float4*)&z[(size_t)(m0 + arow) * 128 + k0 + acol];
    float4 av1 = *(const float4*)&z[(size_t)(m0 + arow) * 128 + k0 + acol + 4];
    float4 bv0 = *(const float4*)&B[(size_t)(k0 + brow) * AT + bcol];
    float4 bv1 = *(const float4*)&B[(size_t)(k0 + brow + 16) * AT + bcol];
    __syncthreads();
    sa[acol + 0][arow] = av0.x; sa[acol + 1][arow] = av0.y;
    sa[acol + 2][arow] = av0.z; sa[acol + 3][arow] = av0.w;
    sa[acol + 4][arow] = av1.x; sa[acol + 5][arow] = av1.y;
    sa[acol + 6][arow] = av1.z; sa[acol + 7][arow] = av1.w;
    *(float4*)&sb[brow][bcol] = bv0;
    *(float4*)&sb[brow + 16][bcol] = bv1;
    __syncthreads();
    #pragma unroll
    for (int kk = 0; kk < 32; kk++) {
      float4 a4 = *(const float4*)&sa[kk][ty * 4];
      float4 b4 = *(const float4*)&sb[kk][tx * 4];
      acc[0][0] += a4.x * b4.x; acc[0][1] += a4.x * b4.y; acc[0][2] += a4.x * b4.z; acc[0][3] += a4.x * b4.w;
      acc[1][0] += a4.y * b4.x; acc[1][1] += a4.y * b4.y; acc[1][2] += a4.y * b4.z; acc[1][3] += a4.y * b4.w;
      acc[2][0] += a4.z * b4.x; acc[2][1] += a4.z * b4.y; acc[2][2] += a4.z * b4.z; acc[2][3] += a4.z * b4.w;
      acc[3][0] += a4.w * b4.x; acc[3][1] += a4.w * b4.y; acc[3][2] += a4.w * b4.z; acc[3][3] += a4.w * b4.w;
    }
  }
  const float* b1c = b1 + c * AT;
  const float* w2c = W2 + c * AT;
  float w2v[4], b1v[4];
  #pragma unroll
  for (int j = 0; j < 4; j++) { w2v[j] = w2c[tx * 4 + j]; b1v[j] = b1c[tx * 4 + j]; }
  #pragma unroll
  for (int i = 0; i < 4; i++) {
    float s = 0.f;
    #pragma unroll
    for (int j = 0; j < 4; j++) s += tanhf(acc[i][j] + b1v[j]) * w2v[j];
    #pragma unroll
    for (int o = 8; o > 0; o >>= 1) s += __shfl_xor(s, o, 64);
    if (tx == 0) logits[c * 256 + m0 + ty * 4 + i] = s;
  }
}

// masked softmax over samples + prototype
__global__ void k_att2(const float* __restrict__ z, const int* __restrict__ labels,
                       const int* __restrict__ idx_train, int ntrain,
                       const float* __restrict__ logits, const float* __restrict__ b2,
                       float* __restrict__ protos) {
  __shared__ float wv[256], red[256];
  __shared__ int trainm[256];
  int c = blockIdx.x, n = threadIdx.x;
  trainm[n] = 0; __syncthreads();
  if (n < ntrain) trainm[idx_train[n]] = 1;
  __syncthreads();
  bool keep = trainm[n] && (labels[n] == c);
  float ml = keep ? (logits[c * 256 + n] + b2[c]) : -1e30f;
  red[n] = ml; __syncthreads();
  for (int s = 128; s > 0; s >>= 1) { if (n < s) red[n] = fmaxf(red[n], red[n + s]); __syncthreads(); }
  float mx = red[0]; __syncthreads();
  float e = expf(ml - mx);
  wv[n] = e; red[n] = e; __syncthreads();
  for (int s = 128; s > 0; s >>= 1) { if (n < s) red[n] += red[n + s]; __syncthreads(); }
  float ssum = red[0]; __syncthreads();
  wv[n] = wv[n] / ssum;
  __syncthreads();
  if (n < 128) {
    float p = 0.f;
    for (int q = 0; q < 256; q++) p += wv[q] * z[q * 128 + n];
    protos[c * 128 + n] = p;
  }
}

// distances; block BB does the prototype-pair term
__global__ void k_dist(const float* __restrict__ z, const float* __restrict__ protos,
                       float* __restrict__ dout) {
  if (blockIdx.x == BB) {
    int t = threadIdx.x;
    if (t < 64) {
      int i = t >> 3, jx = t & 7;
      float dot = 0.f, p2i = 0.f, p2j = 0.f;
      for (int d = 0; d < 128; d++) {
        float a = protos[i * 128 + d], bb2 = protos[jx * 128 + d];
        dot += a * bb2; p2i += a * a; p2j += bb2 * bb2;
      }
      float d2 = fmaxf(p2i + p2j - 2.f * dot, 1e-12f);
      float e = expf(-0.5f * sqrtf(d2));
      e = warp_red_sum(e);
      if (t == 0) dout[2048] = e / 28.f;
    }
    return;
  }
  __shared__ float zs[128], red[128];
  int n = blockIdx.x, t = threadIdx.x;
  zs[t] = z[n * 128 + t];
  red[t] = zs[t] * zs[t]; __syncthreads();
  for (int s = 64; s > 0; s >>= 1) { if (t < s) red[t] += red[t + s]; __syncthreads(); }
  float z2 = red[0];
  if (t < NC) {
    float dot = 0.f, p2 = 0.f;
    const float* pr = protos + t * 128;
    for (int d = 0; d < 128; d++) { float pv = pr[d]; dot += pv * zs[d]; p2 += pv * pv; }
    float d2 = fmaxf(z2 + p2 - 2.f * dot, 1e-12f);
    dout[n * NC + t] = expf(-0.5f * sqrtf(d2));
  }
}

extern "C" void kernel_launch(void* const* d_in, const int* in_sizes, int n_in,
                              void* d_out, int out_size, void* d_ws, size_t ws_size,
                              hipStream_t stream) {
  const float* x = (const float*)d_in[0];
  const int* labels = (const int*)d_in[1];
  const int* idx_train = (const int*)d_in[2];
  const float* gat_W = (const float*)d_in[3];
  const float* gat_a1 = (const float*)d_in[4];
  const float* gat_a2 = (const float*)d_in[5];
  const float* gcnW[3] = {(const float*)d_in[6], (const float*)d_in[8], (const float*)d_in[10]};
  const float* gcnB[3] = {(const float*)d_in[7], (const float*)d_in[9], (const float*)d_in[11]};
  const float* pw1[3] = {(const float*)d_in[12], (const float*)d_in[15], (const float*)d_in[18]};
  const float* pw2[3] = {(const float*)d_in[13], (const float*)d_in[16], (const float*)d_in[19]};
  const float* pbb[3] = {(const float*)d_in[14], (const float*)d_in[17], (const float*)d_in[20]};
  const float* wih = (const float*)d_in[21];
  const float* whh = (const float*)d_in[22];
  const float* bih = (const float*)d_in[23];
  const float* bhh = (const float*)d_in[24];
  const float* c1W = (const float*)d_in[25]; const float* c1b = (const float*)d_in[26];
  const float* c2W = (const float*)d_in[27]; const float* c2b = (const float*)d_in[28];
  const float* c3W = (const float*)d_in[29]; const float* c3b = (const float*)d_in[30];
  const float* fc0W = (const float*)d_in[31]; const float* fc0b = (const float*)d_in[32];
  const float* bn0g = (const float*)d_in[33]; const float* bn0b = (const float*)d_in[34];
  const float* fc1W = (const float*)d_in[35]; const float* fc1b = (const float*)d_in[36];
  const float* aW1 = (const float*)d_in[37]; const float* ab1 = (const float*)d_in[38];
  const float* aW2 = (const float*)d_in[39]; const float* ab2 = (const float*)d_in[40];
  float* out = (float*)d_out;
  float* ws = (float*)d_ws;

  // ---- workspace layout (floats). Z region reused by 3 sequential phases. ----
  size_t off = 0;
  auto take = [&](size_t n) { size_t o = off; off += (n + 63) & ~(size_t)63; return o; };
  float* wa1   = ws + take(512);
  float* wa2   = ws + take(512);
  float* ha1   = ws + take(BB * CC);
  float* ha2   = ws + take(BB * CC);
  float* dinv  = ws + take(BB * 64);
  float* rbuf  = ws + take(BB * 256);
  float* xgru  = ws + take(BB * 128);
  float* xconv = ws + take(BB * 128);
  float* hm    = ws + take(BB * 256);
  float* hmn   = ws + take(BB * 256);
  float* zb    = ws + take(BB * 128);
  float* protos = ws + take(NC * 128);
  float* lgts  = ws + take(NC * 256);
  float* gw1h  = ws + take(256 * 128);       // packed h2 gcnW[0]
  float* wpkf  = ws + take(192 * 128);       // packed h2 whh for k_gru
  float* wslot = ws + take(512 * 384);       // wihT_h (GRU) then conv MFMA frags
  float* Z     = ws + take(8568832);
  // GNN-phase aliases
  float* mA  = Z;
  float* mB  = Z + 1048576;
  float* xw  = Z + 2097152;
  float* gb  = Z + 4194304;
  float* gp1 = Z + 6291456;
  float* gp2 = Z + 7340032;
  // GRU-phase aliases
  float* gi = Z;
  float* ys = Z + 6291456;
  // conv-phase aliases (2 chunks of 128 samples; f16 [pos][128oc] activations)
  float* cv1 = Z;                     // 128*519*128 f16 = 4251648 floats
  float* cv2 = Z + 4251648;           // 128*527*128 f16 = 4317184 floats
  unsigned int* wpk = (unsigned int*)wpkf;
  unsigned int* wihTh = (unsigned int*)wslot;
  unsigned int* wt1h = (unsigned int*)wslot;             // 16 chunks * 2048 = 32768 u32
  unsigned int* wt2h = wt1h + 32768;                     // 20 * 2048 = 40960
  unsigned int* wt3h = wt2h + 40960;                     // 12 * 2048 = 24576

  hipMemsetAsync(rbuf, 0, BB * 256 * sizeof(float), stream);
  hipMemsetAsync(xconv, 0, BB * 128 * sizeof(float), stream);

  // ---- GAT adjacency (fused dinv for stage 0) ----
  k_wa<<<8, 64, 0, stream>>>(gat_W, gat_a1, gat_a2, wa1, wa2);
  k_ha<<<BB * CC / 4, 256, 0, stream>>>(x, wa1, wa2, ha1, ha2);
  k_softmask<<<BB * 64 / 4, 256, 0, stream>>>(ha1, ha2, mA, dinv);

  // ---- 3x (GCN + SAGPool); pool computes next stage's dinv ----
  k_pack_h<<<(256 * 128 + 255) / 256, 256, 0, stream>>>(gcnW[0], (unsigned int*)gw1h, 512, 128);
  const int Ns[3] = {64, 32, 16};
  const int ks[3] = {32, 16, 8};
  const float* gins[3] = {x, gp1, gp2};
  float* mcur[3] = {mA, mB, mA};
  float* mnxt[3] = {mB, mA, mB};
  float* gps[3]  = {gp1, gp2, nullptr};
  for (int s = 0; s < 3; s++) {
    int N = Ns[s];
    if (s == 0) {
      k_gemmh<<<(BB * CC / 64) * (HH / 64), 256, 0, stream>>>(
          x, (unsigned int*)gw1h, xw, BB * CC, HH, LL);
    } else {
      k_xw<<<BB * N, 128, 0, stream>>>(gins[s], gcnW[s], xw, N, 128);
    }
    k_gcnagg<<<BB * N, 128, 0, stream>>>(xw, mcur[s], dinv, gcnB[s], gb, N);
    k_pool<<<BB, 256, 0, stream>>>(gb, mcur[s], pw1[s], pw2[s], pbb[s], N, ks[s],
                                   gps[s], mnxt[s], s < 2 ? dinv : nullptr, rbuf);
  }

  // ---- GRU branch ----
  k_packT_h<<<(256 * 384 + 255) / 256, 256, 0, stream>>>(wih, wihTh, 384, 512);
  k_packgru<<<(192 * 128 + 255) / 256, 256, 0, stream>>>(whh, wpk);
  k_gemmh<<<(BB * CC / 64) * (G3 / 64), 256, 0, stream>>>(x, wihTh, gi, BB * CC, G3, LL);
  k_gru<<<CC, 128, 0, stream>>>(gi, wpk, bhh, bih, ys);
  k_grumean<<<BB, 128, 0, stream>>>(ys, xgru);

  // ---- dilated conv branch: MFMA implicit GEMM, 2 chunks of 128 samples ----
  k_packw_mfma<<<384, 256, 0, stream>>>(c1W, c2W, c3W, wt1h, wt2h, wt3h);
  for (int bc = 0; bc < 2; bc++) {
    int b0 = bc * 128;
    k_cmfma<64, 8, 1, 7, 512, CL1, 0><<<128 * 9, 256, 0, stream>>>(
        x + (size_t)b0 * CC * LL, (const uint4*)wt1h, c1b, cv1, b0);
    k_cmfma<128, 5, 2, 8, CL1, CL2, 1><<<128 * 9, 256, 0, stream>>>(
        cv1, (const uint4*)wt2h, c2b, cv2, b0);
    k_cmfma<128, 3, 4, 8, CL2, CL3, 2><<<128 * 9, 256, 0, stream>>>(
        cv2, (const uint4*)wt3h, c3b, xconv, b0);
  }

  // ---- mapping MLP + BN + attention prototypes + distances ----
  k_fc0<<<BB, 256, 0, stream>>>(xconv, xgru, rbuf, fc0W, fc0b, hm);
  k_bn<<<256, 256, 0, stream>>>(hm, bn0g, bn0b, hmn);
  k_fc1<<<BB, 128, 0, stream>>>(hmn, fc1W, fc1b, zb);
  k_att1<<<NC * 4, 256, 0, stream>>>(zb, aW1, ab1, aW2, lgts);
  k_att2<<<NC, 256, 0, stream>>>(zb, labels, idx_train, in_sizes[2], lgts, ab2, protos);
  k_dist<<<BB + 1, 128, 0, stream>>>(zb, protos, out);
}

// Round 8
// 624.711 us; speedup vs baseline: 16.3411x; 1.0228x over previous
//
#include <hip/hip_runtime.h>
#include <math.h>

#define BB 256   // batch
#define CC 64    // channels / graph nodes
#define LL 512   // series length
#define HH 128   // gcn hidden
#define G3 384   // 3*gru_dim
#define NC 8
#define AT 64
#define CL1 519
#define CL2 527
#define CL3 535
#define THRESH 0.02f

typedef _Float16 h2 __attribute__((ext_vector_type(2)));
typedef _Float16 f16x8 __attribute__((ext_vector_type(8)));
typedef float f32x4 __attribute__((ext_vector_type(4)));
union HU { unsigned int u; h2 h; float f; };
union BU { uint4 u; f16x8 h; };

__device__ inline float warp_red_sum(float v) {
  #pragma unroll
  for (int o = 32; o > 0; o >>= 1) v += __shfl_down(v, o, 64);
  return v;
}
__device__ inline float warp_allred_max(float v) {
  #pragma unroll
  for (int o = 32; o > 0; o >>= 1) v = fmaxf(v, __shfl_xor(v, o, 64));
  return v;
}
__device__ inline float warp_allred_sum(float v) {
  #pragma unroll
  for (int o = 32; o > 0; o >>= 1) v += __shfl_xor(v, o, 64);
  return v;
}

__device__ inline float fdot2f(h2 a, h2 b, float c) {
#if __has_builtin(__builtin_amdgcn_fdot2)
  return __builtin_amdgcn_fdot2(a, b, c, false);
#else
  float r;
  asm volatile("v_dot2_f32_f16 %0, %1, %2, %3" : "=v"(r) : "v"(a), "v"(b), "v"(c));
  return r;
#endif
}
__device__ inline h2 asH2(float f) { HU u; u.f = f; return u.h; }
__device__ inline h2 uH2(unsigned int x) { HU u; u.u = x; return u.h; }
__device__ inline unsigned int packh(float a, float b) {
  HU u; h2 t; t.x = (_Float16)a; t.y = (_Float16)b; u.h = t; return u.u;
}

// wa = gat_W @ a  (512-vector)
__global__ void k_wa(const float* __restrict__ gatW, const float* __restrict__ a1,
                     const float* __restrict__ a2, float* wa1, float* wa2) {
  int l = blockIdx.x * 64 + threadIdx.x;
  const float* row = gatW + l * LL;
  float s1 = 0.f, s2 = 0.f;
  for (int k = 0; k < LL; k++) { float w = row[k]; s1 += w * a1[k]; s2 += w * a2[k]; }
  wa1[l] = s1; wa2[l] = s2;
}

// ha1[b,c] = x[b,c,:].wa1 ; ha2 likewise. one wave per row.
__global__ void k_ha(const float* __restrict__ x, const float* __restrict__ wa1,
                     const float* __restrict__ wa2, float* ha1, float* ha2) {
  int wid = threadIdx.x >> 6, lane = threadIdx.x & 63;
  int row = blockIdx.x * 4 + wid;
  const float* xr = x + (size_t)row * LL;
  float s1 = 0.f, s2 = 0.f;
  for (int q = lane; q < LL; q += 64) { float v = xr[q]; s1 += v * wa1[q]; s2 += v * wa2[q]; }
  s1 = warp_red_sum(s1); s2 = warp_red_sum(s2);
  if (lane == 0) { ha1[row] = s1; ha2[row] = s2; }
}

// softmax row -> mask; fused dinv0 (row degree)
__global__ void k_softmask(const float* __restrict__ ha1, const float* __restrict__ ha2,
                           float* __restrict__ mask, float* __restrict__ dinv) {
  int wid = threadIdx.x >> 6, lane = threadIdx.x & 63;
  int row = blockIdx.x * 4 + wid;       // row = b*64+i
  int b = row >> 6;
  float e = ha1[row] + ha2[b * 64 + lane];
  e = e < 0.f ? 0.2f * e : e;
  float mx = warp_allred_max(e);
  float ex = expf(e - mx);
  float sm = warp_allred_sum(ex);
  float A = ex / sm;
  float mval = (A > THRESH) ? 1.0f : 0.0f;
  mask[(size_t)row * 64 + lane] = mval;
  float cnt = warp_allred_sum(mval);
  if (lane == 0) dinv[row] = 1.0f / sqrtf(cnt + 1.0f);
}

// ---- packing kernels ----
__global__ void k_packT_h(const float* __restrict__ W, unsigned int* __restrict__ out,
                          int R, int Lc) {
  int idx = blockIdx.x * 256 + threadIdx.x;
  int half = Lc >> 1;
  if (idx >= R * half) return;
  int k2 = idx / R, j = idx % R;
  out[idx] = packh(W[j * Lc + 2 * k2], W[j * Lc + 2 * k2 + 1]);
}
__global__ void k_pack_h(const float* __restrict__ W, unsigned int* __restrict__ out,
                         int K, int N) {
  int idx = blockIdx.x * 256 + threadIdx.x;
  if (idx >= (K >> 1) * N) return;
  int k2 = idx / N, n = idx % N;
  out[idx] = packh(W[(2 * k2) * N + n], W[(2 * k2 + 1) * N + n]);
}
__global__ void k_packgru(const float* __restrict__ whh, unsigned int* __restrict__ out) {
  int idx = blockIdx.x * 256 + threadIdx.x;
  if (idx >= 192 * 128) return;
  int j = idx & 127, rk = idx >> 7;
  int r = rk >> 6, k2 = rk & 63;
  const float* src = whh + (size_t)(j + 128 * r) * 128 + 2 * k2;
  out[idx] = packh(src[0], src[1]);
}

// conv weights -> MFMA B-fragment-linear layout.
__device__ inline void packw_one(const float* __restrict__ W, unsigned int* __restrict__ out,
                                 int idx, int cinlog, int KS) {
  int w_ = idx & 3, l = (idx >> 2) & 63, n = (idx >> 8) & 7, c = idx >> 11;
  int CIN = 1 << cinlog;
  int oc = n * 16 + (l & 15);
  int k0 = c * 32 + ((l >> 4) << 3) + 2 * w_;
  int t0 = k0 >> cinlog, ci0 = k0 & (CIN - 1);
  int t1 = (k0 + 1) >> cinlog, ci1 = (k0 + 1) & (CIN - 1);
  out[idx] = packh(W[(size_t)oc * CIN * KS + ci0 * KS + t0],
                   W[(size_t)oc * CIN * KS + ci1 * KS + t1]);
}
__global__ void k_packw_mfma(const float* __restrict__ c1W, const float* __restrict__ c2W,
                             const float* __restrict__ c3W, unsigned int* o1,
                             unsigned int* o2, unsigned int* o3) {
  int idx = blockIdx.x * 256 + threadIdx.x;
  if (idx < 32768) packw_one(c1W, o1, idx, 6, 8);
  else if (idx < 73728) packw_one(c2W, o2, idx - 32768, 7, 5);
  else if (idx < 98304) packw_one(c3W, o3, idx - 73728, 7, 3);
}

// f16-dot2 tiled GEMM: C[M,N] = A[M,K] @ B[K,N]; bijective XCD-chunk swizzle (T1).
__global__ __launch_bounds__(256) void k_gemmh(const float* __restrict__ A,
                                               const unsigned int* __restrict__ Bh,
                                               float* __restrict__ C,
                                               int M, int N, int K) {
  __shared__ unsigned int sah[16][64];
  __shared__ unsigned int sbh[16][64];
  int nwg = gridDim.x, bid = blockIdx.x;
  int qq = nwg >> 3, rr = nwg & 7;
  int xcd = bid & 7, rk = bid >> 3;
  int lb = (xcd < rr ? xcd * (qq + 1) : rr * (qq + 1) + (xcd - rr) * qq) + rk;
  int nbn = N >> 6;
  int bm = lb / nbn, bn = lb % nbn;
  int m0 = bm * 64, n0 = bn * 64;
  int tx = threadIdx.x & 15, ty = threadIdx.x >> 4;
  float acc[4][4];
  #pragma unroll
  for (int i = 0; i < 4; i++)
    #pragma unroll
    for (int j = 0; j < 4; j++) acc[i][j] = 0.f;
  int arow = threadIdx.x >> 2;
  int acol = (threadIdx.x & 3) * 8;
  int brow = threadIdx.x >> 4;
  int bcol = (threadIdx.x & 15) * 4;
  for (int k0 = 0; k0 < K; k0 += 32) {
    float4 av0 = *(const float4*)&A[(size_t)(m0 + arow) * K + k0 + acol];
    float4 av1 = *(const float4*)&A[(size_t)(m0 + arow) * K + k0 + acol + 4];
    uint4 bv = *(const uint4*)&Bh[(size_t)((k0 >> 1) + brow) * N + n0 + bcol];
    __syncthreads();
    int ac2 = acol >> 1;
    sah[ac2 + 0][arow] = packh(av0.x, av0.y);
    sah[ac2 + 1][arow] = packh(av0.z, av0.w);
    sah[ac2 + 2][arow] = packh(av1.x, av1.y);
    sah[ac2 + 3][arow] = packh(av1.z, av1.w);
    *(uint4*)&sbh[brow][bcol] = bv;
    __syncthreads();
    #pragma unroll
    for (int kk = 0; kk < 16; kk++) {
      uint4 a4 = *(const uint4*)&sah[kk][ty * 4];
      uint4 b4 = *(const uint4*)&sbh[kk][tx * 4];
      h2 ax = uH2(a4.x), ay = uH2(a4.y), az = uH2(a4.z), aw = uH2(a4.w);
      h2 bx = uH2(b4.x), by = uH2(b4.y), bz = uH2(b4.z), bw = uH2(b4.w);
      acc[0][0] = fdot2f(ax, bx, acc[0][0]); acc[0][1] = fdot2f(ax, by, acc[0][1]);
      acc[0][2] = fdot2f(ax, bz, acc[0][2]); acc[0][3] = fdot2f(ax, bw, acc[0][3]);
      acc[1][0] = fdot2f(ay, bx, acc[1][0]); acc[1][1] = fdot2f(ay, by, acc[1][1]);
      acc[1][2] = fdot2f(ay, bz, acc[1][2]); acc[1][3] = fdot2f(ay, bw, acc[1][3]);
      acc[2][0] = fdot2f(az, bx, acc[2][0]); acc[2][1] = fdot2f(az, by, acc[2][1]);
      acc[2][2] = fdot2f(az, bz, acc[2][2]); acc[2][3] = fdot2f(az, bw, acc[2][3]);
      acc[3][0] = fdot2f(aw, bx, acc[3][0]); acc[3][1] = fdot2f(aw, by, acc[3][1]);
      acc[3][2] = fdot2f(aw, bz, acc[3][2]); acc[3][3] = fdot2f(aw, bw, acc[3][3]);
    }
  }
  #pragma unroll
  for (int i = 0; i < 4; i++) {
    float4 v = make_float4(acc[i][0], acc[i][1], acc[i][2], acc[i][3]);
    *(float4*)&C[(size_t)(m0 + ty * 4 + i) * N + n0 + tx * 4] = v;
  }
}

// g[b,i,f] = relu(dinv_i*(dinv_i*xw_if + sum_j m_ij*dinv_j*xw_jf) + bias_f)
__global__ void k_gcnagg(const float* __restrict__ xw, const float* __restrict__ mask,
                         const float* __restrict__ dinv, const float* __restrict__ bias,
                         float* __restrict__ gout, int N) {
  __shared__ float mrow[64], dv[64];
  int b = blockIdx.x / N, i = blockIdx.x % N;
  if (threadIdx.x < N) {
    mrow[threadIdx.x] = mask[(size_t)(b * N + i) * N + threadIdx.x];
    dv[threadIdx.x] = dinv[b * N + threadIdx.x];
  }
  __syncthreads();
  int f = threadIdx.x;
  float di = dv[i];
  float acc = di * xw[(size_t)(b * N + i) * HH + f];
  for (int j = 0; j < N; j++) acc += mrow[j] * dv[j] * xw[(size_t)(b * N + j) * HH + f];
  float y = di * acc + bias[f];
  gout[(size_t)(b * N + i) * HH + f] = y > 0.f ? y : 0.f;
}

// fused SAGPool: LDS-staged g/mask, wave argmax top-k, gather+gate+readout, next dinv
__global__ __launch_bounds__(256) void k_pool(const float* __restrict__ g,
                                              const float* __restrict__ mask,
                                              const float* __restrict__ w1,
                                              const float* __restrict__ w2,
                                              const float* __restrict__ pb, int N, int kk,
                                              float* gp, float* mnext, float* dnext,
                                              float* __restrict__ r) {
  __shared__ float gs[64 * 129];
  __shared__ float ms[64 * 65];
  __shared__ float d1s[64], d2s[64], sv[64], vals[32], tvs[32];
  __shared__ int idxs[32];
  int b = blockIdx.x, tid = threadIdx.x;
  for (int q = tid; q < N * 128; q += 256) {
    int row = q >> 7, d = q & 127;
    gs[row * 129 + d] = g[(size_t)(b * N + row) * 128 + d];
  }
  for (int q = tid; q < N * N; q += 256) {
    int row = q / N, u = q - row * N;
    ms[row * 65 + u] = mask[(size_t)(b * N + row) * N + u];
  }
  __syncthreads();
  if (tid < N) {
    float a = 0.f, c = 0.f;
    const float* gr = &gs[tid * 129];
    for (int d = 0; d < 128; d++) { float v = gr[d]; a += v * w1[d]; c += v * w2[d]; }
    d1s[tid] = a; d2s[tid] = c;
  }
  __syncthreads();
  if (tid < N) {
    const float* mr = &ms[tid * 65];
    float s = d1s[tid] + pb[0];
    for (int j = 0; j < N; j++) s += mr[j] * d2s[j];
    sv[tid] = s;
  }
  __syncthreads();
  if (tid < 64) {
    float myv = (tid < N) ? sv[tid] : -3.4e38f;
    int alive = (tid < N) ? 1 : 0;
    for (int t = 0; t < kk; t++) {
      float cv = alive ? myv : -3.4e38f;
      int ci = tid;
      #pragma unroll
      for (int o = 32; o > 0; o >>= 1) {
        float ov = __shfl_xor(cv, o, 64);
        int oi = __shfl_xor(ci, o, 64);
        if (ov > cv || (ov == cv && oi < ci)) { cv = ov; ci = oi; }
      }
      if (tid == ci) alive = 0;
      if (tid == 0) { idxs[t] = ci; vals[t] = cv; }
    }
  }
  __syncthreads();
  if (tid < kk) tvs[tid] = tanhf(vals[tid]);
  __syncthreads();
  if (tid < HH) {
    float mx = -3.4e38f, sm = 0.f;
    for (int t = 0; t < kk; t++) {
      float v = gs[idxs[t] * 129 + tid] * tvs[t];
      if (gp) gp[(size_t)(b * kk + t) * HH + tid] = v;
      mx = fmaxf(mx, v); sm += v;
    }
    r[b * 256 + tid] += mx;
    r[b * 256 + 128 + tid] += sm / (float)kk;
  }
  for (int q = tid; q < kk * kk; q += 256) {
    int t = q / kk, u = q - t * kk;
    mnext[(size_t)(b * kk + t) * kk + u] = ms[idxs[t] * 65 + idxs[u]];
  }
  if (dnext && tid < kk) {
    float s = 0.f;
    for (int u = 0; u < kk; u++) s += ms[idxs[tid] * 65 + idxs[u]];
    dnext[b * kk + tid] = 1.0f / sqrtf(s + 1.0f);
  }
}

// GRU recurrence: 128 threads/block; thread j owns gate rows j, j+128, j+256.
// Barrier is lgkmcnt-only (T4): gi prefetch + ys stores stay in flight across it.
__global__ __launch_bounds__(128, 1) void k_gru(const float* __restrict__ gi,
                                                const unsigned int* __restrict__ wpk,
                                                const float* __restrict__ bhh,
                                                const float* __restrict__ bih,
                                                float* __restrict__ ys) {
  __shared__ _Float16 hb[2][128];
  int c = blockIdx.x, j = threadIdx.x;
  h2 w0[64], w1[64], w2[64];
  #pragma unroll
  for (int k2 = 0; k2 < 64; k2++) { HU u; u.u = wpk[k2 * 128 + j]; w0[k2] = u.h; }
  #pragma unroll
  for (int k2 = 0; k2 < 64; k2++) { HU u; u.u = wpk[(64 + k2) * 128 + j]; w1[k2] = u.h; }
  #pragma unroll
  for (int k2 = 0; k2 < 64; k2++) { HU u; u.u = wpk[(128 + k2) * 128 + j]; w2[k2] = u.h; }
  float bh0 = bhh[j], bh1 = bhh[j + 128], bh2 = bhh[j + 256];
  float bi0 = bih[j], bi1 = bih[j + 128], bi2 = bih[j + 256];
  float hprev = 0.f;
  hb[0][j] = (_Float16)0.f;
  __syncthreads();
  const float* gbase = gi + (size_t)c * G3 + j;
  float g0 = gbase[0], g1 = gbase[128], g2 = gbase[256];
  int cur = 0;
  for (int b = 0; b < BB; b++) {
    float n0 = 0.f, n1 = 0.f, n2 = 0.f;
    if (b + 1 < BB) {
      const float* gn = gbase + (size_t)(b + 1) * CC * G3;
      n0 = gn[0]; n1 = gn[128]; n2 = gn[256];
    }
    float a0a = 0.f, a0b = 0.f, a1a = 0.f, a1b = 0.f, a2a = 0.f, a2b = 0.f;
    #pragma unroll
    for (int q = 0; q < 16; q++) {
      float4 hv = *(const float4*)&hb[cur][q * 8];
      h2 h0 = asH2(hv.x), h1 = asH2(hv.y), h2v = asH2(hv.z), h3 = asH2(hv.w);
      a0a = fdot2f(w0[q * 4 + 0], h0, a0a); a0b = fdot2f(w0[q * 4 + 1], h1, a0b);
      a0a = fdot2f(w0[q * 4 + 2], h2v, a0a); a0b = fdot2f(w0[q * 4 + 3], h3, a0b);
      a1a = fdot2f(w1[q * 4 + 0], h0, a1a); a1b = fdot2f(w1[q * 4 + 1], h1, a1b);
      a1a = fdot2f(w1[q * 4 + 2], h2v, a1a); a1b = fdot2f(w1[q * 4 + 3], h3, a1b);
      a2a = fdot2f(w2[q * 4 + 0], h0, a2a); a2b = fdot2f(w2[q * 4 + 1], h1, a2b);
      a2a = fdot2f(w2[q * 4 + 2], h2v, a2a); a2b = fdot2f(w2[q * 4 + 3], h3, a2b);
    }
    float A0 = a0a + a0b + bh0;
    float A1 = a1a + a1b + bh1;
    float A2 = a2a + a2b + bh2;
    float rg = 1.f / (1.f + expf(-(g0 + bi0 + A0)));
    float zg = 1.f / (1.f + expf(-(g1 + bi1 + A1)));
    float ng = tanhf(g2 + bi2 + rg * A2);
    float hn = (1.f - zg) * ng + zg * hprev;
    ys[(size_t)(b * CC + c) * 128 + j] = hn;
    hprev = hn;
    hb[cur ^ 1][j] = (_Float16)hn;
    // lgkmcnt-only barrier: don't drain vmcnt (gi prefetch / ys store in flight)
    asm volatile("s_waitcnt lgkmcnt(0)" ::: "memory");
    __builtin_amdgcn_s_barrier();
    cur ^= 1;
    g0 = n0; g1 = n1; g2 = n2;
  }
}

__global__ void k_grumean(const float* __restrict__ ys, float* __restrict__ xgru) {
  int b = blockIdx.x, u = threadIdx.x;
  float acc = 0.f;
  for (int c = 0; c < CC; c++) acc += ys[(size_t)(b * CC + c) * 128 + u];
  xgru[b * 128 + u] = acc / 64.f;
}

// ---------------- MFMA implicit-GEMM conv ----------------
template<int CIN, int KS, int DIL, int PAD, int LIN, int LOUT, int MODE>
__global__ __launch_bounds__(256) void k_cmfma(const void* __restrict__ inv,
                                               const uint4* __restrict__ Bf,
                                               const float* __restrict__ bias,
                                               void* __restrict__ outv, int b0) {
  constexpr int QN = CIN / 32;          // k-chunks per tap
  constexpr int NCH = KS * QN;
  constexpr int SLOTS = CIN / 8;        // 16B slots per row
  constexpr int NT = (LOUT + 63) / 64;
  __shared__ _Float16 xs[72 * CIN];
  int nb = blockIdx.x / NT;
  int p0 = (blockIdx.x % NT) * 64;
  int tid = threadIdx.x;
  int l = tid & 63, w = tid >> 6;

  if constexpr (MODE == 0) {
    const float* src = (const float*)inv + (size_t)nb * CIN * LIN;
    for (int q = tid; q < (CIN / 2) * 72; q += 256) {
      int ci2 = q / 72, r = q % 72;
      int ci = 2 * ci2;
      int p = p0 - PAD + r;
      float v0 = 0.f, v1 = 0.f;
      if (p >= 0 && p < LIN) { v0 = src[ci * LIN + p]; v1 = src[(ci + 1) * LIN + p]; }
      int slot = ci >> 3;
      int phys = slot ^ (r & 7);
      *(unsigned int*)&xs[r * CIN + phys * 8 + (ci & 7)] = packh(v0, v1);
    }
  } else {
    const _Float16* src = (const _Float16*)inv + (size_t)nb * LIN * CIN;
    for (int q = tid; q < 72 * SLOTS; q += 256) {
      int r = q / SLOTS, s = q % SLOTS;
      int p = p0 - PAD + r;
      uint4 v = make_uint4(0u, 0u, 0u, 0u);
      if (p >= 0 && p < LIN) v = *(const uint4*)&src[(size_t)p * CIN + s * 8];
      int phys = s ^ (r & 7);
      *(uint4*)&xs[r * CIN + phys * 8] = v;
    }
  }
  __syncthreads();

  int n0 = 2 * w, n1 = n0 + 1;
  f32x4 acc[4][2];
  #pragma unroll
  for (int m = 0; m < 4; m++) {
    acc[m][0] = (f32x4){0.f, 0.f, 0.f, 0.f};
    acc[m][1] = (f32x4){0.f, 0.f, 0.f, 0.f};
  }
  uint4 bc0 = Bf[(size_t)(0 * 8 + n0) * 64 + l];
  uint4 bc1 = Bf[(size_t)(0 * 8 + n1) * 64 + l];
  for (int c = 0; c < NCH; c++) {
    uint4 bn0 = bc0, bn1 = bc1;
    if (c + 1 < NCH) {
      bn0 = Bf[(size_t)((c + 1) * 8 + n0) * 64 + l];
      bn1 = Bf[(size_t)((c + 1) * 8 + n1) * 64 + l];
    }
    int t = c / QN, q = c % QN;
    int slotbase = q * 4 + (l >> 4);
    f16x8 a[4];
    #pragma unroll
    for (int m = 0; m < 4; m++) {
      int r = m * 16 + (l & 15) + t * DIL;
      int phys = slotbase ^ (r & 7);
      a[m] = *(const f16x8*)&xs[r * CIN + phys * 8];
    }
    BU u0, u1; u0.u = bc0; u1.u = bc1;
    #pragma unroll
    for (int m = 0; m < 4; m++) {
      acc[m][0] = __builtin_amdgcn_mfma_f32_16x16x32_f16(a[m], u0.h, acc[m][0], 0, 0, 0);
      acc[m][1] = __builtin_amdgcn_mfma_f32_16x16x32_f16(a[m], u1.h, acc[m][1], 0, 0, 0);
    }
    bc0 = bn0; bc1 = bn1;
  }

  if constexpr (MODE == 2) {
    float* xcv = (float*)outv;
    #pragma unroll
    for (int n = 0; n < 2; n++) {
      int oc = (2 * w + n) * 16 + (l & 15);
      float bz = bias[oc];
      float s = 0.f;
      #pragma unroll
      for (int m = 0; m < 4; m++) {
        #pragma unroll
        for (int i = 0; i < 4; i++) {
          int pos = p0 + m * 16 + (l >> 4) * 4 + i;
          if (pos < LOUT) { float y = acc[m][n][i] + bz; s += y > 0.f ? y : 0.f; }
        }
      }
      s += __shfl_xor(s, 16, 64);
      s += __shfl_xor(s, 32, 64);
      if (l < 16) atomicAdd(&xcv[(size_t)(b0 + nb) * 128 + oc], s);
    }
  } else {
    _Float16* outp = (_Float16*)outv + (size_t)nb * LOUT * 128;
    #pragma unroll
    for (int n = 0; n < 2; n++) {
      int oc = (2 * w + n) * 16 + (l & 15);
      float bz = bias[oc];
      #pragma unroll
      for (int m = 0; m < 4; m++) {
        #pragma unroll
        for (int i = 0; i < 4; i++) {
          int pos = p0 + m * 16 + (l >> 4) * 4 + i;
          if (pos < LOUT) {
            float y = acc[m][n][i] + bz;
            outp[(size_t)pos * 128 + oc] = (_Float16)(y > 0.f ? y : 0.f);
          }
        }
      }
    }
  }
}

__global__ void k_fc0(const float* __restrict__ xconv, const float* __restrict__ xgru,
                      const float* __restrict__ r, const float* __restrict__ W,
                      const float* __restrict__ bias, float* __restrict__ hm) {
  __shared__ float feat[512];
  int b = blockIdx.x, t = threadIdx.x;
  if (t < 128) { feat[t] = xconv[b * 128 + t] * (1.f / (float)CL3); feat[128 + t] = xgru[b * 128 + t]; }
  feat[256 + t] = r[b * 256 + t];
  __syncthreads();
  float acc = bias[t];
  for (int k = 0; k < 512; k++) acc += feat[k] * W[k * 256 + t];
  hm[b * 256 + t] = acc;
}

__global__ void k_bn(const float* __restrict__ hm, const float* __restrict__ gamma,
                     const float* __restrict__ beta, float* __restrict__ out) {
  __shared__ float red[256];
  int n = blockIdx.x, t = threadIdx.x;
  float v = hm[t * 256 + n];
  red[t] = v; __syncthreads();
  for (int s = 128; s > 0; s >>= 1) { if (t < s) red[t] += red[t + s]; __syncthreads(); }
  float mean = red[0] / 256.f; __syncthreads();
  float dv = v - mean;
  red[t] = dv * dv; __syncthreads();
  for (int s = 128; s > 0; s >>= 1) { if (t < s) red[t] += red[t + s]; __syncthreads(); }
  float var = red[0] / 256.f;
  float y = gamma[n] * dv * (1.f / sqrtf(var + 1e-5f)) + beta[n];
  out[t * 256 + n] = y < 0.f ? 0.01f * y : y;
}

__global__ void k_fc1(const float* __restrict__ hmn, const float* __restrict__ W,
                      const float* __restrict__ bias, float* __restrict__ z) {
  __shared__ float hs[256];
  int b = blockIdx.x, t = threadIdx.x;
  hs[t] = hmn[b * 256 + t]; hs[128 + t] = hmn[b * 256 + 128 + t];
  __syncthreads();
  float acc = bias[t];
  for (int k = 0; k < 256; k++) acc += hs[k] * W[k * 128 + t];
  z[b * 128 + t] = acc;
}

// attention logits: grid (8 classes x 4 sample-tiles of 64)
__global__ __launch_bounds__(256) void k_att1(const float* __restrict__ z,
                                              const float* __restrict__ W1,
                                              const float* __restrict__ b1,
                                              const float* __restrict__ W2,
                                              float* __restrict__ logits) {
  __shared__ float sa[32][64];
  __shared__ float sb[32][64];
  int c = blockIdx.x >> 2;
  int m0 = (blockIdx.x & 3) * 64;
  const float* B = W1 + (size_t)c * 128 * AT;
  int tx = threadIdx.x & 15, ty = threadIdx.x >> 4;
  float acc[4][4];
  #pragma unroll
  for (int i = 0; i < 4; i++)
    #pragma unroll
    for (int j = 0; j < 4; j++) acc[i][j] = 0.f;
  int arow = threadIdx.x >> 2;
  int acol = (threadIdx.x & 3) * 8;
  int brow = threadIdx.x >> 4;
  int bcol = (threadIdx.x & 15) * 4;
  for (int k0 = 0; k0 < 128; k0 += 32) {
    float4 av0 = *(const float4*)&z[(size_t)(m0 + arow) * 128 + k0 + acol];
    float4 av1 = *(const float4*)&z[(size_t)(m0 + arow) * 128 + k0 + acol + 4];
    float4 bv0 = *(const float4*)&B[(size_t)(k0 + brow) * AT + bcol];
    float4 bv1 = *(const float4*)&B[(size_t)(k0 + brow + 16) * AT + bcol];
    __syncthreads();
    sa[acol + 0][arow] = av0.x; sa[acol + 1][arow] = av0.y;
    sa[acol + 2][arow] = av0.z; sa[acol + 3][arow] = av0.w;
    sa[acol + 4][arow] = av1.x; sa[acol + 5][arow] = av1.y;
    sa[acol + 6][arow] = av1.z; sa[acol + 7][arow] = av1.w;
    *(float4*)&sb[brow][bcol] = bv0;
    *(float4*)&sb[brow + 16][bcol] = bv1;
    __syncthreads();
    #pragma unroll
    for (int kk = 0; kk < 32; kk++) {
      float4 a4 = *(const float4*)&sa[kk][ty * 4];
      float4 b4 = *(const float4*)&sb[kk][tx * 4];
      acc[0][0] += a4.x * b4.x; acc[0][1] += a4.x * b4.y; acc[0][2] += a4.x * b4.z; acc[0][3] += a4.x * b4.w;
      acc[1][0] += a4.y * b4.x; acc[1][1] += a4.y * b4.y; acc[1][2] += a4.y * b4.z; acc[1][3] += a4.y * b4.w;
      acc[2][0] += a4.z * b4.x; acc[2][1] += a4.z * b4.y; acc[2][2] += a4.z * b4.z; acc[2][3] += a4.z * b4.w;
      acc[3][0] += a4.w * b4.x; acc[3][1] += a4.w * b4.y; acc[3][2] += a4.w * b4.z; acc[3][3] += a4.w * b4.w;
    }
  }
  const float* b1c = b1 + c * AT;
  const float* w2c = W2 + c * AT;
  float w2v[4], b1v[4];
  #pragma unroll
  for (int j = 0; j < 4; j++) { w2v[j] = w2c[tx * 4 + j]; b1v[j] = b1c[tx * 4 + j]; }
  #pragma unroll
  for (int i = 0; i < 4; i++) {
    float s = 0.f;
    #pragma unroll
    for (int j = 0; j < 4; j++) s += tanhf(acc[i][j] + b1v[j]) * w2v[j];
    #pragma unroll
    for (int o = 8; o > 0; o >>= 1) s += __shfl_xor(s, o, 64);
    if (tx == 0) logits[c * 256 + m0 + ty * 4 + i] = s;
  }
}

// masked softmax over samples + prototype
__global__ void k_att2(const float* __restrict__ z, const int* __restrict__ labels,
                       const int* __restrict__ idx_train, int ntrain,
                       const float* __restrict__ logits, const float* __restrict__ b2,
                       float* __restrict__ protos) {
  __shared__ float wv[256], red[256];
  __shared__ int trainm[256];
  int c = blockIdx.x, n = threadIdx.x;
  trainm[n] = 0; __syncthreads();
  if (n < ntrain) trainm[idx_train[n]] = 1;
  __syncthreads();
  bool keep = trainm[n] && (labels[n] == c);
  float ml = keep ? (logits[c * 256 + n] + b2[c]) : -1e30f;
  red[n] = ml; __syncthreads();
  for (int s = 128; s > 0; s >>= 1) { if (n < s) red[n] = fmaxf(red[n], red[n + s]); __syncthreads(); }
  float mx = red[0]; __syncthreads();
  float e = expf(ml - mx);
  wv[n] = e; red[n] = e; __syncthreads();
  for (int s = 128; s > 0; s >>= 1) { if (n < s) red[n] += red[n + s]; __syncthreads(); }
  float ssum = red[0]; __syncthreads();
  wv[n] = wv[n] / ssum;
  __syncthreads();
  if (n < 128) {
    float p = 0.f;
    for (int q = 0; q < 256; q++) p += wv[q] * z[q * 128 + n];
    protos[c * 128 + n] = p;
  }
}

// distances; block BB does the prototype-pair term
__global__ void k_dist(const float* __restrict__ z, const float* __restrict__ protos,
                       float* __restrict__ dout) {
  if (blockIdx.x == BB) {
    int t = threadIdx.x;
    if (t < 64) {
      int i = t >> 3, jx = t & 7;
      float dot = 0.f, p2i = 0.f, p2j = 0.f;
      for (int d = 0; d < 128; d++) {
        float a = protos[i * 128 + d], bb2 = protos[jx * 128 + d];
        dot += a * bb2; p2i += a * a; p2j += bb2 * bb2;
      }
      float d2 = fmaxf(p2i + p2j - 2.f * dot, 1e-12f);
      float e = expf(-0.5f * sqrtf(d2));
      e = warp_red_sum(e);
      if (t == 0) dout[2048] = e / 28.f;
    }
    return;
  }
  __shared__ float zs[128], red[128];
  int n = blockIdx.x, t = threadIdx.x;
  zs[t] = z[n * 128 + t];
  red[t] = zs[t] * zs[t]; __syncthreads();
  for (int s = 64; s > 0; s >>= 1) { if (t < s) red[t] += red[t + s]; __syncthreads(); }
  float z2 = red[0];
  if (t < NC) {
    float dot = 0.f, p2 = 0.f;
    const float* pr = protos + t * 128;
    for (int d = 0; d < 128; d++) { float pv = pr[d]; dot += pv * zs[d]; p2 += pv * pv; }
    float d2 = fmaxf(z2 + p2 - 2.f * dot, 1e-12f);
    dout[n * NC + t] = expf(-0.5f * sqrtf(d2));
  }
}

extern "C" void kernel_launch(void* const* d_in, const int* in_sizes, int n_in,
                              void* d_out, int out_size, void* d_ws, size_t ws_size,
                              hipStream_t stream) {
  const float* x = (const float*)d_in[0];
  const int* labels = (const int*)d_in[1];
  const int* idx_train = (const int*)d_in[2];
  const float* gat_W = (const float*)d_in[3];
  const float* gat_a1 = (const float*)d_in[4];
  const float* gat_a2 = (const float*)d_in[5];
  const float* gcnW[3] = {(const float*)d_in[6], (const float*)d_in[8], (const float*)d_in[10]};
  const float* gcnB[3] = {(const float*)d_in[7], (const float*)d_in[9], (const float*)d_in[11]};
  const float* pw1[3] = {(const float*)d_in[12], (const float*)d_in[15], (const float*)d_in[18]};
  const float* pw2[3] = {(const float*)d_in[13], (const float*)d_in[16], (const float*)d_in[19]};
  const float* pbb[3] = {(const float*)d_in[14], (const float*)d_in[17], (const float*)d_in[20]};
  const float* wih = (const float*)d_in[21];
  const float* whh = (const float*)d_in[22];
  const float* bih = (const float*)d_in[23];
  const float* bhh = (const float*)d_in[24];
  const float* c1W = (const float*)d_in[25]; const float* c1b = (const float*)d_in[26];
  const float* c2W = (const float*)d_in[27]; const float* c2b = (const float*)d_in[28];
  const float* c3W = (const float*)d_in[29]; const float* c3b = (const float*)d_in[30];
  const float* fc0W = (const float*)d_in[31]; const float* fc0b = (const float*)d_in[32];
  const float* bn0g = (const float*)d_in[33]; const float* bn0b = (const float*)d_in[34];
  const float* fc1W = (const float*)d_in[35]; const float* fc1b = (const float*)d_in[36];
  const float* aW1 = (const float*)d_in[37]; const float* ab1 = (const float*)d_in[38];
  const float* aW2 = (const float*)d_in[39]; const float* ab2 = (const float*)d_in[40];
  float* out = (float*)d_out;
  float* ws = (float*)d_ws;

  // ---- workspace layout (floats). Z region reused by 3 sequential phases. ----
  size_t off = 0;
  auto take = [&](size_t n) { size_t o = off; off += (n + 63) & ~(size_t)63; return o; };
  float* wa1   = ws + take(512);
  float* wa2   = ws + take(512);
  float* ha1   = ws + take(BB * CC);
  float* ha2   = ws + take(BB * CC);
  float* dinv  = ws + take(BB * 64);
  float* rbuf  = ws + take(BB * 256);
  float* xgru  = ws + take(BB * 128);
  float* xconv = ws + take(BB * 128);
  float* hm    = ws + take(BB * 256);
  float* hmn   = ws + take(BB * 256);
  float* zb    = ws + take(BB * 128);
  float* protos = ws + take(NC * 128);
  float* lgts  = ws + take(NC * 256);
  float* gw1h  = ws + take(256 * 128);       // packed h2 gcnW[0]
  float* gw2h  = ws + take(64 * 128);        // packed h2 gcnW[1]
  float* gw3h  = ws + take(64 * 128);        // packed h2 gcnW[2]
  float* wpkf  = ws + take(192 * 128);       // packed h2 whh for k_gru
  float* wslot = ws + take(512 * 384);       // wihT_h (GRU) then conv MFMA frags
  float* Z     = ws + take(8568832);
  // GNN-phase aliases
  float* mA  = Z;
  float* mB  = Z + 1048576;
  float* xw  = Z + 2097152;
  float* gb  = Z + 4194304;
  float* gp1 = Z + 6291456;
  float* gp2 = Z + 7340032;
  // GRU-phase aliases
  float* gi = Z;
  float* ys = Z + 6291456;
  // conv-phase aliases (2 chunks of 128 samples; f16 [pos][128oc] activations)
  float* cv1 = Z;                     // 128*519*128 f16 = 4251648 floats
  float* cv2 = Z + 4251648;           // 128*527*128 f16 = 4317184 floats
  unsigned int* wpk = (unsigned int*)wpkf;
  unsigned int* wihTh = (unsigned int*)wslot;
  unsigned int* wt1h = (unsigned int*)wslot;             // 16 chunks * 2048 = 32768 u32
  unsigned int* wt2h = wt1h + 32768;                     // 20 * 2048 = 40960
  unsigned int* wt3h = wt2h + 40960;                     // 12 * 2048 = 24576

  hipMemsetAsync(rbuf, 0, BB * 256 * sizeof(float), stream);
  hipMemsetAsync(xconv, 0, BB * 128 * sizeof(float), stream);

  // ---- GAT adjacency (fused dinv for stage 0) ----
  k_wa<<<8, 64, 0, stream>>>(gat_W, gat_a1, gat_a2, wa1, wa2);
  k_ha<<<BB * CC / 4, 256, 0, stream>>>(x, wa1, wa2, ha1, ha2);
  k_softmask<<<BB * 64 / 4, 256, 0, stream>>>(ha1, ha2, mA, dinv);

  // ---- 3x (GCN + SAGPool); xw via f16 GEMM at every stage ----
  k_pack_h<<<(256 * 128 + 255) / 256, 256, 0, stream>>>(gcnW[0], (unsigned int*)gw1h, 512, 128);
  k_pack_h<<<(64 * 128 + 255) / 256, 256, 0, stream>>>(gcnW[1], (unsigned int*)gw2h, 128, 128);
  k_pack_h<<<(64 * 128 + 255) / 256, 256, 0, stream>>>(gcnW[2], (unsigned int*)gw3h, 128, 128);
  const int Ns[3] = {64, 32, 16};
  const int ks[3] = {32, 16, 8};
  const int Kin[3] = {512, 128, 128};
  const float* gins[3] = {x, gp1, gp2};
  const unsigned int* gwh[3] = {(unsigned int*)gw1h, (unsigned int*)gw2h, (unsigned int*)gw3h};
  float* mcur[3] = {mA, mB, mA};
  float* mnxt[3] = {mB, mA, mB};
  float* gps[3]  = {gp1, gp2, nullptr};
  for (int s = 0; s < 3; s++) {
    int N = Ns[s];
    k_gemmh<<<(BB * N / 64) * (HH / 64), 256, 0, stream>>>(
        gins[s], gwh[s], xw, BB * N, HH, Kin[s]);
    k_gcnagg<<<BB * N, 128, 0, stream>>>(xw, mcur[s], dinv, gcnB[s], gb, N);
    k_pool<<<BB, 256, 0, stream>>>(gb, mcur[s], pw1[s], pw2[s], pbb[s], N, ks[s],
                                   gps[s], mnxt[s], s < 2 ? dinv : nullptr, rbuf);
  }

  // ---- GRU branch ----
  k_packT_h<<<(256 * 384 + 255) / 256, 256, 0, stream>>>(wih, wihTh, 384, 512);
  k_packgru<<<(192 * 128 + 255) / 256, 256, 0, stream>>>(whh, wpk);
  k_gemmh<<<(BB * CC / 64) * (G3 / 64), 256, 0, stream>>>(x, wihTh, gi, BB * CC, G3, LL);
  k_gru<<<CC, 128, 0, stream>>>(gi, wpk, bhh, bih, ys);
  k_grumean<<<BB, 128, 0, stream>>>(ys, xgru);

  // ---- dilated conv branch: MFMA implicit GEMM, 2 chunks of 128 samples ----
  k_packw_mfma<<<384, 256, 0, stream>>>(c1W, c2W, c3W, wt1h, wt2h, wt3h);
  for (int bc = 0; bc < 2; bc++) {
    int b0 = bc * 128;
    k_cmfma<64, 8, 1, 7, 512, CL1, 0><<<128 * 9, 256, 0, stream>>>(
        x + (size_t)b0 * CC * LL, (const uint4*)wt1h, c1b, cv1, b0);
    k_cmfma<128, 5, 2, 8, CL1, CL2, 1><<<128 * 9, 256, 0, stream>>>(
        cv1, (const uint4*)wt2h, c2b, cv2, b0);
    k_cmfma<128, 3, 4, 8, CL2, CL3, 2><<<128 * 9, 256, 0, stream>>>(
        cv2, (const uint4*)wt3h, c3b, xconv, b0);
  }

  // ---- mapping MLP + BN + attention prototypes + distances ----
  k_fc0<<<BB, 256, 0, stream>>>(xconv, xgru, rbuf, fc0W, fc0b, hm);
  k_bn<<<256, 256, 0, stream>>>(hm, bn0g, bn0b, hmn);
  k_fc1<<<BB, 128, 0, stream>>>(hmn, fc1W, fc1b, zb);
  k_att1<<<NC * 4, 256, 0, stream>>>(zb, aW1, ab1, aW2, lgts);
  k_att2<<<NC, 256, 0, stream>>>(zb, labels, idx_train, in_sizes[2], lgts, ab2, protos);
  k_dist<<<BB + 1, 128, 0, stream>>>(zb, protos, out);
}

// Round 9
// 552.699 us; speedup vs baseline: 18.4702x; 1.1303x over previous
//
#include <hip/hip_runtime.h>
#include <math.h>

#define BB 256   // batch
#define CC 64    // channels / graph nodes
#define LL 512   // series length
#define HH 128   // gcn hidden
#define G3 384   // 3*gru_dim
#define NC 8
#define AT 64
#define CL1 519
#define CL2 527
#define CL3 535
#define THRESH 0.02f

typedef _Float16 h2 __attribute__((ext_vector_type(2)));
typedef _Float16 f16x8 __attribute__((ext_vector_type(8)));
typedef float f32x4 __attribute__((ext_vector_type(4)));
union HU { unsigned int u; h2 h; float f; };
union BU { uint4 u; f16x8 h; };

__device__ inline float warp_red_sum(float v) {
  #pragma unroll
  for (int o = 32; o > 0; o >>= 1) v += __shfl_down(v, o, 64);
  return v;
}
__device__ inline float warp_allred_max(float v) {
  #pragma unroll
  for (int o = 32; o > 0; o >>= 1) v = fmaxf(v, __shfl_xor(v, o, 64));
  return v;
}
__device__ inline float warp_allred_sum(float v) {
  #pragma unroll
  for (int o = 32; o > 0; o >>= 1) v += __shfl_xor(v, o, 64);
  return v;
}

__device__ inline float fdot2f(h2 a, h2 b, float c) {
#if __has_builtin(__builtin_amdgcn_fdot2)
  return __builtin_amdgcn_fdot2(a, b, c, false);
#else
  float r;
  asm volatile("v_dot2_f32_f16 %0, %1, %2, %3" : "=v"(r) : "v"(a), "v"(b), "v"(c));
  return r;
#endif
}
__device__ inline h2 asH2(float f) { HU u; u.f = f; return u.h; }
__device__ inline h2 uH2(unsigned int x) { HU u; u.u = x; return u.h; }
__device__ inline unsigned int packh(float a, float b) {
  HU u; h2 t; t.x = (_Float16)a; t.y = (_Float16)b; u.h = t; return u.u;
}
// hardware exp2 / rcp (1-ulp; used ONLY on continuous paths, never near discrete thresholds)
__device__ inline float vexp2(float x) { float r; asm("v_exp_f32 %0, %1" : "=v"(r) : "v"(x)); return r; }
__device__ inline float vrcp(float x)  { float r; asm("v_rcp_f32 %0, %1" : "=v"(r) : "v"(x)); return r; }
__device__ inline float fsigm(float x) { return vrcp(1.f + vexp2(-1.44269504f * x)); }
__device__ inline float ftanh(float x) { return 1.f - 2.f * vrcp(vexp2(2.88539008f * x) + 1.f); }

// wa = gat_W @ a  (512-vector)
__global__ void k_wa(const float* __restrict__ gatW, const float* __restrict__ a1,
                     const float* __restrict__ a2, float* wa1, float* wa2) {
  int l = blockIdx.x * 64 + threadIdx.x;
  const float* row = gatW + l * LL;
  float s1 = 0.f, s2 = 0.f;
  for (int k = 0; k < LL; k++) { float w = row[k]; s1 += w * a1[k]; s2 += w * a2[k]; }
  wa1[l] = s1; wa2[l] = s2;
}

// ha1[b,c] = x[b,c,:].wa1 ; ha2 likewise. one wave per row.
__global__ void k_ha(const float* __restrict__ x, const float* __restrict__ wa1,
                     const float* __restrict__ wa2, float* ha1, float* ha2) {
  int wid = threadIdx.x >> 6, lane = threadIdx.x & 63;
  int row = blockIdx.x * 4 + wid;
  const float* xr = x + (size_t)row * LL;
  float s1 = 0.f, s2 = 0.f;
  for (int q = lane; q < LL; q += 64) { float v = xr[q]; s1 += v * wa1[q]; s2 += v * wa2[q]; }
  s1 = warp_red_sum(s1); s2 = warp_red_sum(s2);
  if (lane == 0) { ha1[row] = s1; ha2[row] = s2; }
}

// softmax row -> mask; fused dinv0 (row degree). Precise expf: A > 0.02 is discrete.
__global__ void k_softmask(const float* __restrict__ ha1, const float* __restrict__ ha2,
                           float* __restrict__ mask, float* __restrict__ dinv) {
  int wid = threadIdx.x >> 6, lane = threadIdx.x & 63;
  int row = blockIdx.x * 4 + wid;       // row = b*64+i
  int b = row >> 6;
  float e = ha1[row] + ha2[b * 64 + lane];
  e = e < 0.f ? 0.2f * e : e;
  float mx = warp_allred_max(e);
  float ex = expf(e - mx);
  float sm = warp_allred_sum(ex);
  float A = ex / sm;
  float mval = (A > THRESH) ? 1.0f : 0.0f;
  mask[(size_t)row * 64 + lane] = mval;
  float cnt = warp_allred_sum(mval);
  if (lane == 0) dinv[row] = 1.0f / sqrtf(cnt + 1.0f);
}

// ---- one mega pack kernel: gcnW0/1/2 (pack_h), wihT (packT_h), whh (packgru) ----
__global__ void k_packall(const float* __restrict__ gcnW0, const float* __restrict__ gcnW1,
                          const float* __restrict__ gcnW2, const float* __restrict__ wih,
                          const float* __restrict__ whh,
                          unsigned int* gw1h, unsigned int* gw2h, unsigned int* gw3h,
                          unsigned int* wihTh, unsigned int* wpk) {
  int idx = blockIdx.x * 256 + threadIdx.x;
  if (idx < 32768) {
    int k2 = idx / 128, n = idx % 128;
    gw1h[idx] = packh(gcnW0[(2 * k2) * 128 + n], gcnW0[(2 * k2 + 1) * 128 + n]);
  } else if (idx < 40960) {
    int t = idx - 32768; int k2 = t / 128, n = t % 128;
    gw2h[t] = packh(gcnW1[(2 * k2) * 128 + n], gcnW1[(2 * k2 + 1) * 128 + n]);
  } else if (idx < 49152) {
    int t = idx - 40960; int k2 = t / 128, n = t % 128;
    gw3h[t] = packh(gcnW2[(2 * k2) * 128 + n], gcnW2[(2 * k2 + 1) * 128 + n]);
  } else if (idx < 147456) {
    int t = idx - 49152; int k2 = t / 384, j = t % 384;
    wihTh[t] = packh(wih[j * 512 + 2 * k2], wih[j * 512 + 2 * k2 + 1]);
  } else if (idx < 172032) {
    int t = idx - 147456; int j = t & 127, rk = t >> 7;
    int r = rk >> 6, k2 = rk & 63;
    const float* src = whh + (size_t)(j + 128 * r) * 128 + 2 * k2;
    wpk[t] = packh(src[0], src[1]);
  }
}

// conv weights -> MFMA B-fragment-linear layout.
__device__ inline void packw_one(const float* __restrict__ W, unsigned int* __restrict__ out,
                                 int idx, int cinlog, int KS) {
  int w_ = idx & 3, l = (idx >> 2) & 63, n = (idx >> 8) & 7, c = idx >> 11;
  int CIN = 1 << cinlog;
  int oc = n * 16 + (l & 15);
  int k0 = c * 32 + ((l >> 4) << 3) + 2 * w_;
  int t0 = k0 >> cinlog, ci0 = k0 & (CIN - 1);
  int t1 = (k0 + 1) >> cinlog, ci1 = (k0 + 1) & (CIN - 1);
  out[idx] = packh(W[(size_t)oc * CIN * KS + ci0 * KS + t0],
                   W[(size_t)oc * CIN * KS + ci1 * KS + t1]);
}
__global__ void k_packw_mfma(const float* __restrict__ c1W, const float* __restrict__ c2W,
                             const float* __restrict__ c3W, unsigned int* o1,
                             unsigned int* o2, unsigned int* o3) {
  int idx = blockIdx.x * 256 + threadIdx.x;
  if (idx < 32768) packw_one(c1W, o1, idx, 6, 8);
  else if (idx < 73728) packw_one(c2W, o2, idx - 32768, 7, 5);
  else if (idx < 98304) packw_one(c3W, o3, idx - 73728, 7, 3);
}

// f16-dot2 tiled GEMM: C[M,N] = A[M,K] @ B[K,N]; bijective XCD-chunk swizzle (T1).
__global__ __launch_bounds__(256) void k_gemmh(const float* __restrict__ A,
                                               const unsigned int* __restrict__ Bh,
                                               float* __restrict__ C,
                                               int M, int N, int K) {
  __shared__ unsigned int sah[16][64];
  __shared__ unsigned int sbh[16][64];
  int nwg = gridDim.x, bid = blockIdx.x;
  int qq = nwg >> 3, rr = nwg & 7;
  int xcd = bid & 7, rk = bid >> 3;
  int lb = (xcd < rr ? xcd * (qq + 1) : rr * (qq + 1) + (xcd - rr) * qq) + rk;
  int nbn = N >> 6;
  int bm = lb / nbn, bn = lb % nbn;
  int m0 = bm * 64, n0 = bn * 64;
  int tx = threadIdx.x & 15, ty = threadIdx.x >> 4;
  float acc[4][4];
  #pragma unroll
  for (int i = 0; i < 4; i++)
    #pragma unroll
    for (int j = 0; j < 4; j++) acc[i][j] = 0.f;
  int arow = threadIdx.x >> 2;
  int acol = (threadIdx.x & 3) * 8;
  int brow = threadIdx.x >> 4;
  int bcol = (threadIdx.x & 15) * 4;
  for (int k0 = 0; k0 < K; k0 += 32) {
    float4 av0 = *(const float4*)&A[(size_t)(m0 + arow) * K + k0 + acol];
    float4 av1 = *(const float4*)&A[(size_t)(m0 + arow) * K + k0 + acol + 4];
    uint4 bv = *(const uint4*)&Bh[(size_t)((k0 >> 1) + brow) * N + n0 + bcol];
    __syncthreads();
    int ac2 = acol >> 1;
    sah[ac2 + 0][arow] = packh(av0.x, av0.y);
    sah[ac2 + 1][arow] = packh(av0.z, av0.w);
    sah[ac2 + 2][arow] = packh(av1.x, av1.y);
    sah[ac2 + 3][arow] = packh(av1.z, av1.w);
    *(uint4*)&sbh[brow][bcol] = bv;
    __syncthreads();
    #pragma unroll
    for (int kk = 0; kk < 16; kk++) {
      uint4 a4 = *(const uint4*)&sah[kk][ty * 4];
      uint4 b4 = *(const uint4*)&sbh[kk][tx * 4];
      h2 ax = uH2(a4.x), ay = uH2(a4.y), az = uH2(a4.z), aw = uH2(a4.w);
      h2 bx = uH2(b4.x), by = uH2(b4.y), bz = uH2(b4.z), bw = uH2(b4.w);
      acc[0][0] = fdot2f(ax, bx, acc[0][0]); acc[0][1] = fdot2f(ax, by, acc[0][1]);
      acc[0][2] = fdot2f(ax, bz, acc[0][2]); acc[0][3] = fdot2f(ax, bw, acc[0][3]);
      acc[1][0] = fdot2f(ay, bx, acc[1][0]); acc[1][1] = fdot2f(ay, by, acc[1][1]);
      acc[1][2] = fdot2f(ay, bz, acc[1][2]); acc[1][3] = fdot2f(ay, bw, acc[1][3]);
      acc[2][0] = fdot2f(az, bx, acc[2][0]); acc[2][1] = fdot2f(az, by, acc[2][1]);
      acc[2][2] = fdot2f(az, bz, acc[2][2]); acc[2][3] = fdot2f(az, bw, acc[2][3]);
      acc[3][0] = fdot2f(aw, bx, acc[3][0]); acc[3][1] = fdot2f(aw, by, acc[3][1]);
      acc[3][2] = fdot2f(aw, bz, acc[3][2]); acc[3][3] = fdot2f(aw, bw, acc[3][3]);
    }
  }
  #pragma unroll
  for (int i = 0; i < 4; i++) {
    float4 v = make_float4(acc[i][0], acc[i][1], acc[i][2], acc[i][3]);
    *(float4*)&C[(size_t)(m0 + ty * 4 + i) * N + n0 + tx * 4] = v;
  }
}

// g[b,i,f] = relu(dinv_i*(dinv_i*xw_if + sum_j m_ij*dinv_j*xw_jf) + bias_f)
__global__ void k_gcnagg(const float* __restrict__ xw, const float* __restrict__ mask,
                         const float* __restrict__ dinv, const float* __restrict__ bias,
                         float* __restrict__ gout, int N) {
  __shared__ float mrow[64], dv[64];
  int b = blockIdx.x / N, i = blockIdx.x % N;
  if (threadIdx.x < N) {
    mrow[threadIdx.x] = mask[(size_t)(b * N + i) * N + threadIdx.x];
    dv[threadIdx.x] = dinv[b * N + threadIdx.x];
  }
  __syncthreads();
  int f = threadIdx.x;
  float di = dv[i];
  float acc = di * xw[(size_t)(b * N + i) * HH + f];
  for (int j = 0; j < N; j++) acc += mrow[j] * dv[j] * xw[(size_t)(b * N + j) * HH + f];
  float y = di * acc + bias[f];
  gout[(size_t)(b * N + i) * HH + f] = y > 0.f ? y : 0.f;
}

// fused SAGPool: LDS-staged g/mask, wave argmax top-k, gather+gate+readout, next dinv
__global__ __launch_bounds__(256) void k_pool(const float* __restrict__ g,
                                              const float* __restrict__ mask,
                                              const float* __restrict__ w1,
                                              const float* __restrict__ w2,
                                              const float* __restrict__ pb, int N, int kk,
                                              float* gp, float* mnext, float* dnext,
                                              float* __restrict__ r) {
  __shared__ float gs[64 * 129];
  __shared__ float ms[64 * 65];
  __shared__ float d1s[64], d2s[64], sv[64], vals[32], tvs[32];
  __shared__ int idxs[32];
  int b = blockIdx.x, tid = threadIdx.x;
  for (int q = tid; q < N * 128; q += 256) {
    int row = q >> 7, d = q & 127;
    gs[row * 129 + d] = g[(size_t)(b * N + row) * 128 + d];
  }
  for (int q = tid; q < N * N; q += 256) {
    int row = q / N, u = q - row * N;
    ms[row * 65 + u] = mask[(size_t)(b * N + row) * N + u];
  }
  __syncthreads();
  if (tid < N) {
    float a = 0.f, c = 0.f;
    const float* gr = &gs[tid * 129];
    for (int d = 0; d < 128; d++) { float v = gr[d]; a += v * w1[d]; c += v * w2[d]; }
    d1s[tid] = a; d2s[tid] = c;
  }
  __syncthreads();
  if (tid < N) {
    const float* mr = &ms[tid * 65];
    float s = d1s[tid] + pb[0];
    for (int j = 0; j < N; j++) s += mr[j] * d2s[j];
    sv[tid] = s;
  }
  __syncthreads();
  if (tid < 64) {
    float myv = (tid < N) ? sv[tid] : -3.4e38f;
    int alive = (tid < N) ? 1 : 0;
    for (int t = 0; t < kk; t++) {
      float cv = alive ? myv : -3.4e38f;
      int ci = tid;
      #pragma unroll
      for (int o = 32; o > 0; o >>= 1) {
        float ov = __shfl_xor(cv, o, 64);
        int oi = __shfl_xor(ci, o, 64);
        if (ov > cv || (ov == cv && oi < ci)) { cv = ov; ci = oi; }
      }
      if (tid == ci) alive = 0;
      if (tid == 0) { idxs[t] = ci; vals[t] = cv; }
    }
  }
  __syncthreads();
  if (tid < kk) tvs[tid] = tanhf(vals[tid]);
  __syncthreads();
  if (tid < HH) {
    float mx = -3.4e38f, sm = 0.f;
    for (int t = 0; t < kk; t++) {
      float v = gs[idxs[t] * 129 + tid] * tvs[t];
      if (gp) gp[(size_t)(b * kk + t) * HH + tid] = v;
      mx = fmaxf(mx, v); sm += v;
    }
    r[b * 256 + tid] += mx;
    r[b * 256 + 128 + tid] += sm / (float)kk;
  }
  for (int q = tid; q < kk * kk; q += 256) {
    int t = q / kk, u = q - t * kk;
    mnext[(size_t)(b * kk + t) * kk + u] = ms[idxs[t] * 65 + idxs[u]];
  }
  if (dnext && tid < kk) {
    float s = 0.f;
    for (int u = 0; u < kk; u++) s += ms[idxs[tid] * 65 + idxs[u]];
    dnext[b * kk + tid] = 1.0f / sqrtf(s + 1.0f);
  }
}

// GRU recurrence: 256 threads/block, K-split pairs (tid=2j+half).
// Thread (j,half) does half the h-range for gate rows j,j+128,j+256 (96 dot2);
// shfl_xor(1) combines halves; native exp2/rcp gates shorten the serial chain.
__global__ __launch_bounds__(256, 1) void k_gru(const float* __restrict__ gi,
                                                const unsigned int* __restrict__ wpk,
                                                const float* __restrict__ bhh,
                                                const float* __restrict__ bih,
                                                float* __restrict__ ys) {
  __shared__ _Float16 hb[2][128];
  int c = blockIdx.x;
  int j = threadIdx.x >> 1, half = threadIdx.x & 1;
  int kb = half * 32;                  // h2-index base of this thread's K-half
  h2 w0[32], w1[32], w2[32];
  #pragma unroll
  for (int kk = 0; kk < 32; kk++) { HU u; u.u = wpk[(kb + kk) * 128 + j]; w0[kk] = u.h; }
  #pragma unroll
  for (int kk = 0; kk < 32; kk++) { HU u; u.u = wpk[(64 + kb + kk) * 128 + j]; w1[kk] = u.h; }
  #pragma unroll
  for (int kk = 0; kk < 32; kk++) { HU u; u.u = wpk[(128 + kb + kk) * 128 + j]; w2[kk] = u.h; }
  float bh0 = bhh[j], bh1 = bhh[j + 128], bh2 = bhh[j + 256];
  float bi0 = bih[j], bi1 = bih[j + 128], bi2 = bih[j + 256];
  float hprev = 0.f;
  if (half == 0) hb[0][j] = (_Float16)0.f;
  __syncthreads();
  const float* gbase = gi + (size_t)c * G3 + j;
  float g0 = gbase[0], g1 = gbase[128], g2 = gbase[256];
  int cur = 0;
  for (int b = 0; b < BB; b++) {
    float n0 = 0.f, n1 = 0.f, n2 = 0.f;
    if (b + 1 < BB) {
      const float* gn = gbase + (size_t)(b + 1) * CC * G3;
      n0 = gn[0]; n1 = gn[128]; n2 = gn[256];
    }
    float a0a = 0.f, a0b = 0.f, a1a = 0.f, a1b = 0.f, a2a = 0.f, a2b = 0.f;
    #pragma unroll
    for (int q = 0; q < 8; q++) {
      float4 hv = *(const float4*)&hb[cur][half * 64 + q * 8];
      h2 h0 = asH2(hv.x), h1 = asH2(hv.y), h2v = asH2(hv.z), h3 = asH2(hv.w);
      a0a = fdot2f(w0[q * 4 + 0], h0, a0a); a0b = fdot2f(w0[q * 4 + 1], h1, a0b);
      a0a = fdot2f(w0[q * 4 + 2], h2v, a0a); a0b = fdot2f(w0[q * 4 + 3], h3, a0b);
      a1a = fdot2f(w1[q * 4 + 0], h0, a1a); a1b = fdot2f(w1[q * 4 + 1], h1, a1b);
      a1a = fdot2f(w1[q * 4 + 2], h2v, a1a); a1b = fdot2f(w1[q * 4 + 3], h3, a1b);
      a2a = fdot2f(w2[q * 4 + 0], h0, a2a); a2b = fdot2f(w2[q * 4 + 1], h1, a2b);
      a2a = fdot2f(w2[q * 4 + 2], h2v, a2a); a2b = fdot2f(w2[q * 4 + 3], h3, a2b);
    }
    float A0 = a0a + a0b, A1 = a1a + a1b, A2 = a2a + a2b;
    A0 += __shfl_xor(A0, 1, 64);
    A1 += __shfl_xor(A1, 1, 64);
    A2 += __shfl_xor(A2, 1, 64);
    A0 += bh0; A1 += bh1; A2 += bh2;
    float rg = fsigm(g0 + bi0 + A0);
    float zg = fsigm(g1 + bi1 + A1);
    float ng = ftanh(g2 + bi2 + rg * A2);
    float hn = (1.f - zg) * ng + zg * hprev;
    hprev = hn;
    if (half == 0) {
      ys[(size_t)(b * CC + c) * 128 + j] = hn;
      hb[cur ^ 1][j] = (_Float16)hn;
    }
    asm volatile("s_waitcnt lgkmcnt(0)" ::: "memory");
    __builtin_amdgcn_s_barrier();
    cur ^= 1;
    g0 = n0; g1 = n1; g2 = n2;
  }
}

__global__ void k_grumean(const float* __restrict__ ys, float* __restrict__ xgru) {
  int b = blockIdx.x, u = threadIdx.x;
  float acc = 0.f;
  for (int c = 0; c < CC; c++) acc += ys[(size_t)(b * CC + c) * 128 + u];
  xgru[b * 128 + u] = acc / 64.f;
}

// ---------------- MFMA implicit-GEMM conv ----------------
template<int CIN, int KS, int DIL, int PAD, int LIN, int LOUT, int MODE>
__global__ __launch_bounds__(256) void k_cmfma(const void* __restrict__ inv,
                                               const uint4* __restrict__ Bf,
                                               const float* __restrict__ bias,
                                               void* __restrict__ outv, int b0) {
  constexpr int QN = CIN / 32;          // k-chunks per tap
  constexpr int NCH = KS * QN;
  constexpr int SLOTS = CIN / 8;        // 16B slots per row
  constexpr int NT = (LOUT + 63) / 64;
  __shared__ _Float16 xs[72 * CIN];
  int nb = blockIdx.x / NT;
  int p0 = (blockIdx.x % NT) * 64;
  int tid = threadIdx.x;
  int l = tid & 63, w = tid >> 6;

  if constexpr (MODE == 0) {
    const float* src = (const float*)inv + (size_t)nb * CIN * LIN;
    for (int q = tid; q < (CIN / 2) * 72; q += 256) {
      int ci2 = q / 72, r = q % 72;
      int ci = 2 * ci2;
      int p = p0 - PAD + r;
      float v0 = 0.f, v1 = 0.f;
      if (p >= 0 && p < LIN) { v0 = src[ci * LIN + p]; v1 = src[(ci + 1) * LIN + p]; }
      int slot = ci >> 3;
      int phys = slot ^ (r & 7);
      *(unsigned int*)&xs[r * CIN + phys * 8 + (ci & 7)] = packh(v0, v1);
    }
  } else {
    const _Float16* src = (const _Float16*)inv + (size_t)nb * LIN * CIN;
    for (int q = tid; q < 72 * SLOTS; q += 256) {
      int r = q / SLOTS, s = q % SLOTS;
      int p = p0 - PAD + r;
      uint4 v = make_uint4(0u, 0u, 0u, 0u);
      if (p >= 0 && p < LIN) v = *(const uint4*)&src[(size_t)p * CIN + s * 8];
      int phys = s ^ (r & 7);
      *(uint4*)&xs[r * CIN + phys * 8] = v;
    }
  }
  __syncthreads();

  int n0 = 2 * w, n1 = n0 + 1;
  f32x4 acc[4][2];
  #pragma unroll
  for (int m = 0; m < 4; m++) {
    acc[m][0] = (f32x4){0.f, 0.f, 0.f, 0.f};
    acc[m][1] = (f32x4){0.f, 0.f, 0.f, 0.f};
  }
  uint4 bc0 = Bf[(size_t)(0 * 8 + n0) * 64 + l];
  uint4 bc1 = Bf[(size_t)(0 * 8 + n1) * 64 + l];
  for (int c = 0; c < NCH; c++) {
    uint4 bn0 = bc0, bn1 = bc1;
    if (c + 1 < NCH) {
      bn0 = Bf[(size_t)((c + 1) * 8 + n0) * 64 + l];
      bn1 = Bf[(size_t)((c + 1) * 8 + n1) * 64 + l];
    }
    int t = c / QN, q = c % QN;
    int slotbase = q * 4 + (l >> 4);
    f16x8 a[4];
    #pragma unroll
    for (int m = 0; m < 4; m++) {
      int r = m * 16 + (l & 15) + t * DIL;
      int phys = slotbase ^ (r & 7);
      a[m] = *(const f16x8*)&xs[r * CIN + phys * 8];
    }
    BU u0, u1; u0.u = bc0; u1.u = bc1;
    #pragma unroll
    for (int m = 0; m < 4; m++) {
      acc[m][0] = __builtin_amdgcn_mfma_f32_16x16x32_f16(a[m], u0.h, acc[m][0], 0, 0, 0);
      acc[m][1] = __builtin_amdgcn_mfma_f32_16x16x32_f16(a[m], u1.h, acc[m][1], 0, 0, 0);
    }
    bc0 = bn0; bc1 = bn1;
  }

  if constexpr (MODE == 2) {
    float* xcv = (float*)outv;
    #pragma unroll
    for (int n = 0; n < 2; n++) {
      int oc = (2 * w + n) * 16 + (l & 15);
      float bz = bias[oc];
      float s = 0.f;
      #pragma unroll
      for (int m = 0; m < 4; m++) {
        #pragma unroll
        for (int i = 0; i < 4; i++) {
          int pos = p0 + m * 16 + (l >> 4) * 4 + i;
          if (pos < LOUT) { float y = acc[m][n][i] + bz; s += y > 0.f ? y : 0.f; }
        }
      }
      s += __shfl_xor(s, 16, 64);
      s += __shfl_xor(s, 32, 64);
      if (l < 16) atomicAdd(&xcv[(size_t)(b0 + nb) * 128 + oc], s);
    }
  } else {
    _Float16* outp = (_Float16*)outv + (size_t)nb * LOUT * 128;
    #pragma unroll
    for (int n = 0; n < 2; n++) {
      int oc = (2 * w + n) * 16 + (l & 15);
      float bz = bias[oc];
      #pragma unroll
      for (int m = 0; m < 4; m++) {
        #pragma unroll
        for (int i = 0; i < 4; i++) {
          int pos = p0 + m * 16 + (l >> 4) * 4 + i;
          if (pos < LOUT) {
            float y = acc[m][n][i] + bz;
            outp[(size_t)pos * 128 + oc] = (_Float16)(y > 0.f ? y : 0.f);
          }
        }
      }
    }
  }
}

__global__ void k_fc0(const float* __restrict__ xconv, const float* __restrict__ xgru,
                      const float* __restrict__ r, const float* __restrict__ W,
                      const float* __restrict__ bias, float* __restrict__ hm) {
  __shared__ float feat[512];
  int b = blockIdx.x, t = threadIdx.x;
  if (t < 128) { feat[t] = xconv[b * 128 + t] * (1.f / (float)CL3); feat[128 + t] = xgru[b * 128 + t]; }
  feat[256 + t] = r[b * 256 + t];
  __syncthreads();
  float acc = bias[t];
  for (int k = 0; k < 512; k++) acc += feat[k] * W[k * 256 + t];
  hm[b * 256 + t] = acc;
}

__global__ void k_bn(const float* __restrict__ hm, const float* __restrict__ gamma,
                     const float* __restrict__ beta, float* __restrict__ out) {
  __shared__ float red[256];
  int n = blockIdx.x, t = threadIdx.x;
  float v = hm[t * 256 + n];
  red[t] = v; __syncthreads();
  for (int s = 128; s > 0; s >>= 1) { if (t < s) red[t] += red[t + s]; __syncthreads(); }
  float mean = red[0] / 256.f; __syncthreads();
  float dv = v - mean;
  red[t] = dv * dv; __syncthreads();
  for (int s = 128; s > 0; s >>= 1) { if (t < s) red[t] += red[t + s]; __syncthreads(); }
  float var = red[0] / 256.f;
  float y = gamma[n] * dv * (1.f / sqrtf(var + 1e-5f)) + beta[n];
  out[t * 256 + n] = y < 0.f ? 0.01f * y : y;
}

__global__ void k_fc1(const float* __restrict__ hmn, const float* __restrict__ W,
                      const float* __restrict__ bias, float* __restrict__ z) {
  __shared__ float hs[256];
  int b = blockIdx.x, t = threadIdx.x;
  hs[t] = hmn[b * 256 + t]; hs[128 + t] = hmn[b * 256 + 128 + t];
  __syncthreads();
  float acc = bias[t];
  for (int k = 0; k < 256; k++) acc += hs[k] * W[k * 128 + t];
  z[b * 128 + t] = acc;
}

// attention logits: grid (8 classes x 4 sample-tiles of 64)
__global__ __launch_bounds__(256) void k_att1(const float* __restrict__ z,
                                              const float* __restrict__ W1,
                                              const float* __restrict__ b1,
                                              const float* __restrict__ W2,
                                              float* __restrict__ logits) {
  __shared__ float sa[32][64];
  __shared__ float sb[32][64];
  int c = blockIdx.x >> 2;
  int m0 = (blockIdx.x & 3) * 64;
  const float* B = W1 + (size_t)c * 128 * AT;
  int tx = threadIdx.x & 15, ty = threadIdx.x >> 4;
  float acc[4][4];
  #pragma unroll
  for (int i = 0; i < 4; i++)
    #pragma unroll
    for (int j = 0; j < 4; j++) acc[i][j] = 0.f;
  int arow = threadIdx.x >> 2;
  int acol = (threadIdx.x & 3) * 8;
  int brow = threadIdx.x >> 4;
  int bcol = (threadIdx.x & 15) * 4;
  for (int k0 = 0; k0 < 128; k0 += 32) {
    float4 av0 = *(const float4*)&z[(size_t)(m0 + arow) * 128 + k0 + acol];
    float4 av1 = *(const float4*)&z[(size_t)(m0 + arow) * 128 + k0 + acol + 4];
    float4 bv0 = *(const float4*)&B[(size_t)(k0 + brow) * AT + bcol];
    float4 bv1 = *(const float4*)&B[(size_t)(k0 + brow + 16) * AT + bcol];
    __syncthreads();
    sa[acol + 0][arow] = av0.x; sa[acol + 1][arow] = av0.y;
    sa[acol + 2][arow] = av0.z; sa[acol + 3][arow] = av0.w;
    sa[acol + 4][arow] = av1.x; sa[acol + 5][arow] = av1.y;
    sa[acol + 6][arow] = av1.z; sa[acol + 7][arow] = av1.w;
    *(float4*)&sb[brow][bcol] = bv0;
    *(float4*)&sb[brow + 16][bcol] = bv1;
    __syncthreads();
    #pragma unroll
    for (int kk = 0; kk < 32; kk++) {
      float4 a4 = *(const float4*)&sa[kk][ty * 4];
      float4 b4 = *(const float4*)&sb[kk][tx * 4];
      acc[0][0] += a4.x * b4.x; acc[0][1] += a4.x * b4.y; acc[0][2] += a4.x * b4.z; acc[0][3] += a4.x * b4.w;
      acc[1][0] += a4.y * b4.x; acc[1][1] += a4.y * b4.y; acc[1][2] += a4.y * b4.z; acc[1][3] += a4.y * b4.w;
      acc[2][0] += a4.z * b4.x; acc[2][1] += a4.z * b4.y; acc[2][2] += a4.z * b4.z; acc[2][3] += a4.z * b4.w;
      acc[3][0] += a4.w * b4.x; acc[3][1] += a4.w * b4.y; acc[3][2] += a4.w * b4.z; acc[3][3] += a4.w * b4.w;
    }
  }
  const float* b1c = b1 + c * AT;
  const float* w2c = W2 + c * AT;
  float w2v[4], b1v[4];
  #pragma unroll
  for (int j = 0; j < 4; j++) { w2v[j] = w2c[tx * 4 + j]; b1v[j] = b1c[tx * 4 + j]; }
  #pragma unroll
  for (int i = 0; i < 4; i++) {
    float s = 0.f;
    #pragma unroll
    for (int j = 0; j < 4; j++) s += tanhf(acc[i][j] + b1v[j]) * w2v[j];
    #pragma unroll
    for (int o = 8; o > 0; o >>= 1) s += __shfl_xor(s, o, 64);
    if (tx == 0) logits[c * 256 + m0 + ty * 4 + i] = s;
  }
}

// masked softmax over samples + prototype
__global__ void k_att2(const float* __restrict__ z, const int* __restrict__ labels,
                       const int* __restrict__ idx_train, int ntrain,
                       const float* __restrict__ logits, const float* __restrict__ b2,
                       float* __restrict__ protos) {
  __shared__ float wv[256], red[256];
  __shared__ int trainm[256];
  int c = blockIdx.x, n = threadIdx.x;
  trainm[n] = 0; __syncthreads();
  if (n < ntrain) trainm[idx_train[n]] = 1;
  __syncthreads();
  bool keep = trainm[n] && (labels[n] == c);
  float ml = keep ? (logits[c * 256 + n] + b2[c]) : -1e30f;
  red[n] = ml; __syncthreads();
  for (int s = 128; s > 0; s >>= 1) { if (n < s) red[n] = fmaxf(red[n], red[n + s]); __syncthreads(); }
  float mx = red[0]; __syncthreads();
  float e = expf(ml - mx);
  wv[n] = e; red[n] = e; __syncthreads();
  for (int s = 128; s > 0; s >>= 1) { if (n < s) red[n] += red[n + s]; __syncthreads(); }
  float ssum = red[0]; __syncthreads();
  wv[n] = wv[n] / ssum;
  __syncthreads();
  if (n < 128) {
    float p = 0.f;
    for (int q = 0; q < 256; q++) p += wv[q] * z[q * 128 + n];
    protos[c * 128 + n] = p;
  }
}

// distances; block BB does the prototype-pair term
__global__ void k_dist(const float* __restrict__ z, const float* __restrict__ protos,
                       float* __restrict__ dout) {
  if (blockIdx.x == BB) {
    int t = threadIdx.x;
    if (t < 64) {
      int i = t >> 3, jx = t & 7;
      float dot = 0.f, p2i = 0.f, p2j = 0.f;
      for (int d = 0; d < 128; d++) {
        float a = protos[i * 128 + d], bb2 = protos[jx * 128 + d];
        dot += a * bb2; p2i += a * a; p2j += bb2 * bb2;
      }
      float d2 = fmaxf(p2i + p2j - 2.f * dot, 1e-12f);
      float e = expf(-0.5f * sqrtf(d2));
      e = warp_red_sum(e);
      if (t == 0) dout[2048] = e / 28.f;
    }
    return;
  }
  __shared__ float zs[128], red[128];
  int n = blockIdx.x, t = threadIdx.x;
  zs[t] = z[n * 128 + t];
  red[t] = zs[t] * zs[t]; __syncthreads();
  for (int s = 64; s > 0; s >>= 1) { if (t < s) red[t] += red[t + s]; __syncthreads(); }
  float z2 = red[0];
  if (t < NC) {
    float dot = 0.f, p2 = 0.f;
    const float* pr = protos + t * 128;
    for (int d = 0; d < 128; d++) { float pv = pr[d]; dot += pv * zs[d]; p2 += pv * pv; }
    float d2 = fmaxf(z2 + p2 - 2.f * dot, 1e-12f);
    dout[n * NC + t] = expf(-0.5f * sqrtf(d2));
  }
}

extern "C" void kernel_launch(void* const* d_in, const int* in_sizes, int n_in,
                              void* d_out, int out_size, void* d_ws, size_t ws_size,
                              hipStream_t stream) {
  const float* x = (const float*)d_in[0];
  const int* labels = (const int*)d_in[1];
  const int* idx_train = (const int*)d_in[2];
  const float* gat_W = (const float*)d_in[3];
  const float* gat_a1 = (const float*)d_in[4];
  const float* gat_a2 = (const float*)d_in[5];
  const float* gcnW[3] = {(const float*)d_in[6], (const float*)d_in[8], (const float*)d_in[10]};
  const float* gcnB[3] = {(const float*)d_in[7], (const float*)d_in[9], (const float*)d_in[11]};
  const float* pw1[3] = {(const float*)d_in[12], (const float*)d_in[15], (const float*)d_in[18]};
  const float* pw2[3] = {(const float*)d_in[13], (const float*)d_in[16], (const float*)d_in[19]};
  const float* pbb[3] = {(const float*)d_in[14], (const float*)d_in[17], (const float*)d_in[20]};
  const float* wih = (const float*)d_in[21];
  const float* whh = (const float*)d_in[22];
  const float* bih = (const float*)d_in[23];
  const float* bhh = (const float*)d_in[24];
  const float* c1W = (const float*)d_in[25]; const float* c1b = (const float*)d_in[26];
  const float* c2W = (const float*)d_in[27]; const float* c2b = (const float*)d_in[28];
  const float* c3W = (const float*)d_in[29]; const float* c3b = (const float*)d_in[30];
  const float* fc0W = (const float*)d_in[31]; const float* fc0b = (const float*)d_in[32];
  const float* bn0g = (const float*)d_in[33]; const float* bn0b = (const float*)d_in[34];
  const float* fc1W = (const float*)d_in[35]; const float* fc1b = (const float*)d_in[36];
  const float* aW1 = (const float*)d_in[37]; const float* ab1 = (const float*)d_in[38];
  const float* aW2 = (const float*)d_in[39]; const float* ab2 = (const float*)d_in[40];
  float* out = (float*)d_out;
  float* ws = (float*)d_ws;

  // ---- workspace layout (floats). Z region reused by 3 sequential phases. ----
  size_t off = 0;
  auto take = [&](size_t n) { size_t o = off; off += (n + 63) & ~(size_t)63; return o; };
  float* wa1   = ws + take(512);
  float* wa2   = ws + take(512);
  float* ha1   = ws + take(BB * CC);
  float* ha2   = ws + take(BB * CC);
  float* dinv  = ws + take(BB * 64);
  float* rbuf  = ws + take(BB * 256);
  float* xgru  = ws + take(BB * 128);
  float* xconv = ws + take(BB * 128);
  float* hm    = ws + take(BB * 256);
  float* hmn   = ws + take(BB * 256);
  float* zb    = ws + take(BB * 128);
  float* protos = ws + take(NC * 128);
  float* lgts  = ws + take(NC * 256);
  float* gw1h  = ws + take(256 * 128);       // packed h2 gcnW[0]
  float* gw2h  = ws + take(64 * 128);        // packed h2 gcnW[1]
  float* gw3h  = ws + take(64 * 128);        // packed h2 gcnW[2]
  float* wpkf  = ws + take(192 * 128);       // packed h2 whh for k_gru
  float* wslot = ws + take(512 * 384);       // wihT_h (GRU) then conv MFMA frags
  float* Z     = ws + take(8568832);
  // GNN-phase aliases
  float* mA  = Z;
  float* mB  = Z + 1048576;
  float* xw  = Z + 2097152;
  float* gb  = Z + 4194304;
  float* gp1 = Z + 6291456;
  float* gp2 = Z + 7340032;
  // GRU-phase aliases
  float* gi = Z;
  float* ys = Z + 6291456;
  // conv-phase aliases (2 chunks of 128 samples; f16 [pos][128oc] activations)
  float* cv1 = Z;                     // 128*519*128 f16 = 4251648 floats
  float* cv2 = Z + 4251648;           // 128*527*128 f16 = 4317184 floats
  unsigned int* wpk = (unsigned int*)wpkf;
  unsigned int* wihTh = (unsigned int*)wslot;
  unsigned int* wt1h = (unsigned int*)wslot;             // 16 chunks * 2048 = 32768 u32
  unsigned int* wt2h = wt1h + 32768;                     // 20 * 2048 = 40960
  unsigned int* wt3h = wt2h + 40960;                     // 12 * 2048 = 24576

  hipMemsetAsync(rbuf, 0, BB * 256 * sizeof(float), stream);
  hipMemsetAsync(xconv, 0, BB * 128 * sizeof(float), stream);

  // ---- GAT adjacency (fused dinv for stage 0) + all weight packing ----
  k_wa<<<8, 64, 0, stream>>>(gat_W, gat_a1, gat_a2, wa1, wa2);
  k_packall<<<672, 256, 0, stream>>>(gcnW[0], gcnW[1], gcnW[2], wih, whh,
                                     (unsigned int*)gw1h, (unsigned int*)gw2h,
                                     (unsigned int*)gw3h, wihTh, wpk);
  k_ha<<<BB * CC / 4, 256, 0, stream>>>(x, wa1, wa2, ha1, ha2);
  k_softmask<<<BB * 64 / 4, 256, 0, stream>>>(ha1, ha2, mA, dinv);

  // ---- 3x (GCN + SAGPool); xw via f16 GEMM at every stage ----
  const int Ns[3] = {64, 32, 16};
  const int ks[3] = {32, 16, 8};
  const int Kin[3] = {512, 128, 128};
  const float* gins[3] = {x, gp1, gp2};
  const unsigned int* gwh[3] = {(unsigned int*)gw1h, (unsigned int*)gw2h, (unsigned int*)gw3h};
  float* mcur[3] = {mA, mB, mA};
  float* mnxt[3] = {mB, mA, mB};
  float* gps[3]  = {gp1, gp2, nullptr};
  for (int s = 0; s < 3; s++) {
    int N = Ns[s];
    k_gemmh<<<(BB * N / 64) * (HH / 64), 256, 0, stream>>>(
        gins[s], gwh[s], xw, BB * N, HH, Kin[s]);
    k_gcnagg<<<BB * N, 128, 0, stream>>>(xw, mcur[s], dinv, gcnB[s], gb, N);
    k_pool<<<BB, 256, 0, stream>>>(gb, mcur[s], pw1[s], pw2[s], pbb[s], N, ks[s],
                                   gps[s], mnxt[s], s < 2 ? dinv : nullptr, rbuf);
  }

  // ---- GRU branch ----
  k_gemmh<<<(BB * CC / 64) * (G3 / 64), 256, 0, stream>>>(x, wihTh, gi, BB * CC, G3, LL);
  k_gru<<<CC, 256, 0, stream>>>(gi, wpk, bhh, bih, ys);
  k_grumean<<<BB, 128, 0, stream>>>(ys, xgru);

  // ---- dilated conv branch: MFMA implicit GEMM, 2 chunks of 128 samples ----
  k_packw_mfma<<<384, 256, 0, stream>>>(c1W, c2W, c3W, wt1h, wt2h, wt3h);
  for (int bc = 0; bc < 2; bc++) {
    int b0 = bc * 128;
    k_cmfma<64, 8, 1, 7, 512, CL1, 0><<<128 * 9, 256, 0, stream>>>(
        x + (size_t)b0 * CC * LL, (const uint4*)wt1h, c1b, cv1, b0);
    k_cmfma<128, 5, 2, 8, CL1, CL2, 1><<<128 * 9, 256, 0, stream>>>(
        cv1, (const uint4*)wt2h, c2b, cv2, b0);
    k_cmfma<128, 3, 4, 8, CL2, CL3, 2><<<128 * 9, 256, 0, stream>>>(
        cv2, (const uint4*)wt3h, c3b, xconv, b0);
  }

  // ---- mapping MLP + BN + attention prototypes + distances ----
  k_fc0<<<BB, 256, 0, stream>>>(xconv, xgru, rbuf, fc0W, fc0b, hm);
  k_bn<<<256, 256, 0, stream>>>(hm, bn0g, bn0b, hmn);
  k_fc1<<<BB, 128, 0, stream>>>(hmn, fc1W, fc1b, zb);
  k_att1<<<NC * 4, 256, 0, stream>>>(zb, aW1, ab1, aW2, lgts);
  k_att2<<<NC, 256, 0, stream>>>(zb, labels, idx_train, in_sizes[2], lgts, ab2, protos);
  k_dist<<<BB + 1, 128, 0, stream>>>(zb, protos, out);
}

// Round 10
// 486.174 us; speedup vs baseline: 20.9975x; 1.1368x over previous
//
#include <hip/hip_runtime.h>
#include <math.h>

#define BB 256   // batch
#define CC 64    // channels / graph nodes
#define LL 512   // series length
#define HH 128   // gcn hidden
#define G3 384   // 3*gru_dim
#define NC 8
#define AT 64
#define CL1 519
#define CL2 527
#define CL3 535
#define THRESH 0.02f

typedef _Float16 h2 __attribute__((ext_vector_type(2)));
typedef _Float16 f16x8 __attribute__((ext_vector_type(8)));
typedef float f32x4 __attribute__((ext_vector_type(4)));
union HU { unsigned int u; h2 h; float f; };
union BU { uint4 u; f16x8 h; };

__device__ inline float warp_red_sum(float v) {
  #pragma unroll
  for (int o = 32; o > 0; o >>= 1) v += __shfl_down(v, o, 64);
  return v;
}
__device__ inline float warp_allred_max(float v) {
  #pragma unroll
  for (int o = 32; o > 0; o >>= 1) v = fmaxf(v, __shfl_xor(v, o, 64));
  return v;
}
__device__ inline float warp_allred_sum(float v) {
  #pragma unroll
  for (int o = 32; o > 0; o >>= 1) v += __shfl_xor(v, o, 64);
  return v;
}

__device__ inline float fdot2f(h2 a, h2 b, float c) {
#if __has_builtin(__builtin_amdgcn_fdot2)
  return __builtin_amdgcn_fdot2(a, b, c, false);
#else
  float r;
  asm volatile("v_dot2_f32_f16 %0, %1, %2, %3" : "=v"(r) : "v"(a), "v"(b), "v"(c));
  return r;
#endif
}
__device__ inline h2 asH2(float f) { HU u; u.f = f; return u.h; }
__device__ inline h2 uH2(unsigned int x) { HU u; u.u = x; return u.h; }
__device__ inline unsigned int packh(float a, float b) {
  HU u; h2 t; t.x = (_Float16)a; t.y = (_Float16)b; u.h = t; return u.u;
}
// hardware exp2 / rcp (1-ulp; continuous paths only, never near discrete thresholds)
__device__ inline float vexp2(float x) { float r; asm("v_exp_f32 %0, %1" : "=v"(r) : "v"(x)); return r; }
__device__ inline float vrcp(float x)  { float r; asm("v_rcp_f32 %0, %1" : "=v"(r) : "v"(x)); return r; }
__device__ inline float fsigm(float x) { return vrcp(1.f + vexp2(-1.44269504f * x)); }
__device__ inline float ftanh(float x) { return 1.f - 2.f * vrcp(vexp2(2.88539008f * x) + 1.f); }

// wa = gat_W @ a  (512-vector)
__global__ void k_wa(const float* __restrict__ gatW, const float* __restrict__ a1,
                     const float* __restrict__ a2, float* wa1, float* wa2) {
  int l = blockIdx.x * 64 + threadIdx.x;
  const float* row = gatW + l * LL;
  float s1 = 0.f, s2 = 0.f;
  for (int k = 0; k < LL; k++) { float w = row[k]; s1 += w * a1[k]; s2 += w * a2[k]; }
  wa1[l] = s1; wa2[l] = s2;
}

// ha1[b,c] = x[b,c,:].wa1 ; ha2 likewise. one wave per row.
__global__ void k_ha(const float* __restrict__ x, const float* __restrict__ wa1,
                     const float* __restrict__ wa2, float* ha1, float* ha2) {
  int wid = threadIdx.x >> 6, lane = threadIdx.x & 63;
  int row = blockIdx.x * 4 + wid;
  const float* xr = x + (size_t)row * LL;
  float s1 = 0.f, s2 = 0.f;
  for (int q = lane; q < LL; q += 64) { float v = xr[q]; s1 += v * wa1[q]; s2 += v * wa2[q]; }
  s1 = warp_red_sum(s1); s2 = warp_red_sum(s2);
  if (lane == 0) { ha1[row] = s1; ha2[row] = s2; }
}

// softmax row -> mask; fused dinv0 (row degree). Precise expf: A > 0.02 is discrete.
__global__ void k_softmask(const float* __restrict__ ha1, const float* __restrict__ ha2,
                           float* __restrict__ mask, float* __restrict__ dinv) {
  int wid = threadIdx.x >> 6, lane = threadIdx.x & 63;
  int row = blockIdx.x * 4 + wid;       // row = b*64+i
  int b = row >> 6;
  float e = ha1[row] + ha2[b * 64 + lane];
  e = e < 0.f ? 0.2f * e : e;
  float mx = warp_allred_max(e);
  float ex = expf(e - mx);
  float sm = warp_allred_sum(ex);
  float A = ex / sm;
  float mval = (A > THRESH) ? 1.0f : 0.0f;
  mask[(size_t)row * 64 + lane] = mval;
  float cnt = warp_allred_sum(mval);
  if (lane == 0) dinv[row] = 1.0f / sqrtf(cnt + 1.0f);
}

// ---- mega pack kernel: gcnW0/1/2 + wihT into MFMA B-fragment layout; whh for k_gru ----
// Fragment decode (N16 = N/16): w=idx&3, l=(idx>>2)&63, n=(idx>>8)%N16, c=(idx>>8)/N16.
// k0 = c*32 + ((l>>4)<<3) + 2w; col = n*16 + (l&15). Matches mfma_f32_16x16x32_f16 B-frag.
__global__ void k_packall(const float* __restrict__ gcnW0, const float* __restrict__ gcnW1,
                          const float* __restrict__ gcnW2, const float* __restrict__ wih,
                          const float* __restrict__ whh,
                          unsigned int* gw1h, unsigned int* gw2h, unsigned int* gw3h,
                          unsigned int* wihTh, unsigned int* wpk) {
  int idx = blockIdx.x * 256 + threadIdx.x;
  if (idx < 32768) {
    // gcnW0 [512][128] row-major [k][n], N16=8
    int w_ = idx & 3, l = (idx >> 2) & 63, n = (idx >> 8) & 7, c = idx >> 11;
    int k0 = c * 32 + ((l >> 4) << 3) + 2 * w_;
    int col = n * 16 + (l & 15);
    gw1h[idx] = packh(gcnW0[k0 * 128 + col], gcnW0[(k0 + 1) * 128 + col]);
  } else if (idx < 40960) {
    int t = idx - 32768;
    int w_ = t & 3, l = (t >> 2) & 63, n = (t >> 8) & 7, c = t >> 11;
    int k0 = c * 32 + ((l >> 4) << 3) + 2 * w_;
    int col = n * 16 + (l & 15);
    gw2h[t] = packh(gcnW1[k0 * 128 + col], gcnW1[(k0 + 1) * 128 + col]);
  } else if (idx < 49152) {
    int t = idx - 40960;
    int w_ = t & 3, l = (t >> 2) & 63, n = (t >> 8) & 7, c = t >> 11;
    int k0 = c * 32 + ((l >> 4) << 3) + 2 * w_;
    int col = n * 16 + (l & 15);
    gw3h[t] = packh(gcnW2[k0 * 128 + col], gcnW2[(k0 + 1) * 128 + col]);
  } else if (idx < 147456) {
    // B = wih^T: B[k][n] = wih[n][k]; wih [384][512]; N16=24
    int t = idx - 49152;
    int w_ = t & 3, l = (t >> 2) & 63;
    int nfc = t >> 8;
    int n = nfc % 24, c = nfc / 24;
    int k0 = c * 32 + ((l >> 4) << 3) + 2 * w_;
    int col = n * 16 + (l & 15);
    wihTh[t] = packh(wih[col * 512 + k0], wih[col * 512 + k0 + 1]);
  } else if (idx < 172032) {
    int t = idx - 147456; int j = t & 127, rk = t >> 7;
    int r = rk >> 6, k2 = rk & 63;
    const float* src = whh + (size_t)(j + 128 * r) * 128 + 2 * k2;
    wpk[t] = packh(src[0], src[1]);
  }
}

// conv weights -> MFMA B-fragment-linear layout (with tap decode).
__device__ inline void packw_one(const float* __restrict__ W, unsigned int* __restrict__ out,
                                 int idx, int cinlog, int KS) {
  int w_ = idx & 3, l = (idx >> 2) & 63, n = (idx >> 8) & 7, c = idx >> 11;
  int CIN = 1 << cinlog;
  int oc = n * 16 + (l & 15);
  int k0 = c * 32 + ((l >> 4) << 3) + 2 * w_;
  int t0 = k0 >> cinlog, ci0 = k0 & (CIN - 1);
  int t1 = (k0 + 1) >> cinlog, ci1 = (k0 + 1) & (CIN - 1);
  out[idx] = packh(W[(size_t)oc * CIN * KS + ci0 * KS + t0],
                   W[(size_t)oc * CIN * KS + ci1 * KS + t1]);
}
__global__ void k_packw_mfma(const float* __restrict__ c1W, const float* __restrict__ c2W,
                             const float* __restrict__ c3W, unsigned int* o1,
                             unsigned int* o2, unsigned int* o3) {
  int idx = blockIdx.x * 256 + threadIdx.x;
  if (idx < 32768) packw_one(c1W, o1, idx, 6, 8);
  else if (idx < 73728) packw_one(c2W, o2, idx - 32768, 7, 5);
  else if (idx < 98304) packw_one(c3W, o3, idx - 73728, 7, 3);
}

// ---------------- MFMA GEMM: C[M,N] = A[M,K](fp32) @ Bf(fragment-packed f16) ----------------
// Block: 256 thr (4 waves), tile 64M x 128N (wave w: n-frags 2w,2w+1). K-tiles of 64,
// A fp32->f16 converted during LDS staging (XOR-swizzled 16B slots), double-buffered,
// ONE barrier per K-tile. B streamed fragment-linear with 1-chunk prefetch (L2-resident).
// Requires M%64==0, N%128==0, K%64==0, grid%8==0 (XCD-chunk swizzle).
__global__ __launch_bounds__(256) void k_gmfma(const float* __restrict__ A,
                                               const uint4* __restrict__ Bf,
                                               float* __restrict__ C,
                                               int M, int N, int K) {
  __shared__ _Float16 as[2][64 * 64];
  int nwg = gridDim.x, bid = blockIdx.x;
  int lb = (bid & 7) * (nwg >> 3) + (bid >> 3);    // bijective: nwg % 8 == 0
  int nbn = N >> 7;
  int bm = lb / nbn, bn = lb - bm * nbn;
  int m0 = bm * 64;
  int tid = threadIdx.x, l = tid & 63, w = tid >> 6;
  int NKT = K >> 6, NC2 = K >> 5, N16 = N >> 4;
  int nf0 = bn * 8 + 2 * w, nf1 = nf0 + 1;
  int ar = tid >> 2;               // A-stage row 0..63
  int ac = (tid & 3) * 16;         // fp32 col offset (16 floats = 2 slots)
  float4 rg[4];
  auto stageA = [&](int kt) {
    const float* src = &A[(size_t)(m0 + ar) * K + kt * 64 + ac];
    rg[0] = *(const float4*)&src[0];
    rg[1] = *(const float4*)&src[4];
    rg[2] = *(const float4*)&src[8];
    rg[3] = *(const float4*)&src[12];
  };
  auto commitA = [&](int buf) {
    int s0 = (tid & 3) * 2;
    int phys0 = (s0 ^ (ar & 7)) * 8;
    int phys1 = ((s0 + 1) ^ (ar & 7)) * 8;
    uint4 v0, v1;
    v0.x = packh(rg[0].x, rg[0].y); v0.y = packh(rg[0].z, rg[0].w);
    v0.z = packh(rg[1].x, rg[1].y); v0.w = packh(rg[1].z, rg[1].w);
    v1.x = packh(rg[2].x, rg[2].y); v1.y = packh(rg[2].z, rg[2].w);
    v1.z = packh(rg[3].x, rg[3].y); v1.w = packh(rg[3].z, rg[3].w);
    *(uint4*)&as[buf][ar * 64 + phys0] = v0;
    *(uint4*)&as[buf][ar * 64 + phys1] = v1;
  };
  f32x4 acc[4][2];
  #pragma unroll
  for (int m = 0; m < 4; m++) {
    acc[m][0] = (f32x4){0.f, 0.f, 0.f, 0.f};
    acc[m][1] = (f32x4){0.f, 0.f, 0.f, 0.f};
  }
  stageA(0); commitA(0);
  uint4 bc0 = Bf[(size_t)nf0 * 64 + l];
  uint4 bc1 = Bf[(size_t)nf1 * 64 + l];
  __syncthreads();
  for (int c = 0; c < NC2; c++) {
    int kt = c >> 1, half = c & 1;
    if (half == 0 && kt + 1 < NKT) stageA(kt + 1);    // A loads in flight over compute
    uint4 pn0 = bc0, pn1 = bc1;
    if (c + 1 < NC2) {
      pn0 = Bf[(size_t)((c + 1) * N16 + nf0) * 64 + l];
      pn1 = Bf[(size_t)((c + 1) * N16 + nf1) * 64 + l];
    }
    int slotbase = half * 4 + (l >> 4);
    f16x8 a[4];
    #pragma unroll
    for (int m = 0; m < 4; m++) {
      int row = m * 16 + (l & 15);
      int phys = slotbase ^ (row & 7);
      a[m] = *(const f16x8*)&as[kt & 1][row * 64 + phys * 8];
    }
    BU u0, u1; u0.u = bc0; u1.u = bc1;
    #pragma unroll
    for (int m = 0; m < 4; m++) {
      acc[m][0] = __builtin_amdgcn_mfma_f32_16x16x32_f16(a[m], u0.h, acc[m][0], 0, 0, 0);
      acc[m][1] = __builtin_amdgcn_mfma_f32_16x16x32_f16(a[m], u1.h, acc[m][1], 0, 0, 0);
    }
    if (half == 1 && kt + 1 < NKT) {
      commitA((kt + 1) & 1);
      __syncthreads();
    }
    bc0 = pn0; bc1 = pn1;
  }
  #pragma unroll
  for (int n = 0; n < 2; n++) {
    int col = (nf0 + n) * 16 + (l & 15);
    #pragma unroll
    for (int m = 0; m < 4; m++) {
      #pragma unroll
      for (int i = 0; i < 4; i++) {
        C[(size_t)(m0 + m * 16 + (l >> 4) * 4 + i) * N + col] = acc[m][n][i];
      }
    }
  }
}

// g[b,i,f] = relu(dinv_i*(dinv_i*xw_if + sum_j m_ij*dinv_j*xw_jf) + bias_f)
__global__ void k_gcnagg(const float* __restrict__ xw, const float* __restrict__ mask,
                         const float* __restrict__ dinv, const float* __restrict__ bias,
                         float* __restrict__ gout, int N) {
  __shared__ float mrow[64], dv[64];
  int b = blockIdx.x / N, i = blockIdx.x % N;
  if (threadIdx.x < N) {
    mrow[threadIdx.x] = mask[(size_t)(b * N + i) * N + threadIdx.x];
    dv[threadIdx.x] = dinv[b * N + threadIdx.x];
  }
  __syncthreads();
  int f = threadIdx.x;
  float di = dv[i];
  float acc = di * xw[(size_t)(b * N + i) * HH + f];
  for (int j = 0; j < N; j++) acc += mrow[j] * dv[j] * xw[(size_t)(b * N + j) * HH + f];
  float y = di * acc + bias[f];
  gout[(size_t)(b * N + i) * HH + f] = y > 0.f ? y : 0.f;
}

// fused SAGPool: LDS-staged g/mask, wave argmax top-k, gather+gate+readout, next dinv
__global__ __launch_bounds__(256) void k_pool(const float* __restrict__ g,
                                              const float* __restrict__ mask,
                                              const float* __restrict__ w1,
                                              const float* __restrict__ w2,
                                              const float* __restrict__ pb, int N, int kk,
                                              float* gp, float* mnext, float* dnext,
                                              float* __restrict__ r) {
  __shared__ float gs[64 * 129];
  __shared__ float ms[64 * 65];
  __shared__ float d1s[64], d2s[64], sv[64], vals[32], tvs[32];
  __shared__ int idxs[32];
  int b = blockIdx.x, tid = threadIdx.x;
  for (int q = tid; q < N * 128; q += 256) {
    int row = q >> 7, d = q & 127;
    gs[row * 129 + d] = g[(size_t)(b * N + row) * 128 + d];
  }
  for (int q = tid; q < N * N; q += 256) {
    int row = q / N, u = q - row * N;
    ms[row * 65 + u] = mask[(size_t)(b * N + row) * N + u];
  }
  __syncthreads();
  if (tid < N) {
    float a = 0.f, c = 0.f;
    const float* gr = &gs[tid * 129];
    for (int d = 0; d < 128; d++) { float v = gr[d]; a += v * w1[d]; c += v * w2[d]; }
    d1s[tid] = a; d2s[tid] = c;
  }
  __syncthreads();
  if (tid < N) {
    const float* mr = &ms[tid * 65];
    float s = d1s[tid] + pb[0];
    for (int j = 0; j < N; j++) s += mr[j] * d2s[j];
    sv[tid] = s;
  }
  __syncthreads();
  if (tid < 64) {
    float myv = (tid < N) ? sv[tid] : -3.4e38f;
    int alive = (tid < N) ? 1 : 0;
    for (int t = 0; t < kk; t++) {
      float cv = alive ? myv : -3.4e38f;
      int ci = tid;
      #pragma unroll
      for (int o = 32; o > 0; o >>= 1) {
        float ov = __shfl_xor(cv, o, 64);
        int oi = __shfl_xor(ci, o, 64);
        if (ov > cv || (ov == cv && oi < ci)) { cv = ov; ci = oi; }
      }
      if (tid == ci) alive = 0;
      if (tid == 0) { idxs[t] = ci; vals[t] = cv; }
    }
  }
  __syncthreads();
  if (tid < kk) tvs[tid] = tanhf(vals[tid]);
  __syncthreads();
  if (tid < HH) {
    float mx = -3.4e38f, sm = 0.f;
    for (int t = 0; t < kk; t++) {
      float v = gs[idxs[t] * 129 + tid] * tvs[t];
      if (gp) gp[(size_t)(b * kk + t) * HH + tid] = v;
      mx = fmaxf(mx, v); sm += v;
    }
    r[b * 256 + tid] += mx;
    r[b * 256 + 128 + tid] += sm / (float)kk;
  }
  for (int q = tid; q < kk * kk; q += 256) {
    int t = q / kk, u = q - t * kk;
    mnext[(size_t)(b * kk + t) * kk + u] = ms[idxs[t] * 65 + idxs[u]];
  }
  if (dnext && tid < kk) {
    float s = 0.f;
    for (int u = 0; u < kk; u++) s += ms[idxs[tid] * 65 + idxs[u]];
    dnext[b * kk + tid] = 1.0f / sqrtf(s + 1.0f);
  }
}

// GRU recurrence: 256 threads/block, K-split pairs; native exp2/rcp gates.
__global__ __launch_bounds__(256, 1) void k_gru(const float* __restrict__ gi,
                                                const unsigned int* __restrict__ wpk,
                                                const float* __restrict__ bhh,
                                                const float* __restrict__ bih,
                                                float* __restrict__ ys) {
  __shared__ _Float16 hb[2][128];
  int c = blockIdx.x;
  int j = threadIdx.x >> 1, half = threadIdx.x & 1;
  int kb = half * 32;
  h2 w0[32], w1[32], w2[32];
  #pragma unroll
  for (int kk = 0; kk < 32; kk++) { HU u; u.u = wpk[(kb + kk) * 128 + j]; w0[kk] = u.h; }
  #pragma unroll
  for (int kk = 0; kk < 32; kk++) { HU u; u.u = wpk[(64 + kb + kk) * 128 + j]; w1[kk] = u.h; }
  #pragma unroll
  for (int kk = 0; kk < 32; kk++) { HU u; u.u = wpk[(128 + kb + kk) * 128 + j]; w2[kk] = u.h; }
  float bh0 = bhh[j], bh1 = bhh[j + 128], bh2 = bhh[j + 256];
  float bi0 = bih[j], bi1 = bih[j + 128], bi2 = bih[j + 256];
  float hprev = 0.f;
  if (half == 0) hb[0][j] = (_Float16)0.f;
  __syncthreads();
  const float* gbase = gi + (size_t)c * G3 + j;
  float g0 = gbase[0], g1 = gbase[128], g2 = gbase[256];
  int cur = 0;
  for (int b = 0; b < BB; b++) {
    float n0 = 0.f, n1 = 0.f, n2 = 0.f;
    if (b + 1 < BB) {
      const float* gn = gbase + (size_t)(b + 1) * CC * G3;
      n0 = gn[0]; n1 = gn[128]; n2 = gn[256];
    }
    float a0a = 0.f, a0b = 0.f, a1a = 0.f, a1b = 0.f, a2a = 0.f, a2b = 0.f;
    #pragma unroll
    for (int q = 0; q < 8; q++) {
      float4 hv = *(const float4*)&hb[cur][half * 64 + q * 8];
      h2 h0 = asH2(hv.x), h1 = asH2(hv.y), h2v = asH2(hv.z), h3 = asH2(hv.w);
      a0a = fdot2f(w0[q * 4 + 0], h0, a0a); a0b = fdot2f(w0[q * 4 + 1], h1, a0b);
      a0a = fdot2f(w0[q * 4 + 2], h2v, a0a); a0b = fdot2f(w0[q * 4 + 3], h3, a0b);
      a1a = fdot2f(w1[q * 4 + 0], h0, a1a); a1b = fdot2f(w1[q * 4 + 1], h1, a1b);
      a1a = fdot2f(w1[q * 4 + 2], h2v, a1a); a1b = fdot2f(w1[q * 4 + 3], h3, a1b);
      a2a = fdot2f(w2[q * 4 + 0], h0, a2a); a2b = fdot2f(w2[q * 4 + 1], h1, a2b);
      a2a = fdot2f(w2[q * 4 + 2], h2v, a2a); a2b = fdot2f(w2[q * 4 + 3], h3, a2b);
    }
    float A0 = a0a + a0b, A1 = a1a + a1b, A2 = a2a + a2b;
    A0 += __shfl_xor(A0, 1, 64);
    A1 += __shfl_xor(A1, 1, 64);
    A2 += __shfl_xor(A2, 1, 64);
    A0 += bh0; A1 += bh1; A2 += bh2;
    float rg = fsigm(g0 + bi0 + A0);
    float zg = fsigm(g1 + bi1 + A1);
    float ng = ftanh(g2 + bi2 + rg * A2);
    float hn = (1.f - zg) * ng + zg * hprev;
    hprev = hn;
    if (half == 0) {
      ys[(size_t)(b * CC + c) * 128 + j] = hn;
      hb[cur ^ 1][j] = (_Float16)hn;
    }
    asm volatile("s_waitcnt lgkmcnt(0)" ::: "memory");
    __builtin_amdgcn_s_barrier();
    cur ^= 1;
    g0 = n0; g1 = n1; g2 = n2;
  }
}

__global__ void k_grumean(const float* __restrict__ ys, float* __restrict__ xgru) {
  int b = blockIdx.x, u = threadIdx.x;
  float acc = 0.f;
  for (int c = 0; c < CC; c++) acc += ys[(size_t)(b * CC + c) * 128 + u];
  xgru[b * 128 + u] = acc / 64.f;
}

// ---------------- MFMA implicit-GEMM conv ----------------
template<int CIN, int KS, int DIL, int PAD, int LIN, int LOUT, int MODE>
__global__ __launch_bounds__(256) void k_cmfma(const void* __restrict__ inv,
                                               const uint4* __restrict__ Bf,
                                               const float* __restrict__ bias,
                                               void* __restrict__ outv, int b0) {
  constexpr int QN = CIN / 32;          // k-chunks per tap
  constexpr int NCH = KS * QN;
  constexpr int SLOTS = CIN / 8;        // 16B slots per row
  constexpr int NT = (LOUT + 63) / 64;
  __shared__ _Float16 xs[72 * CIN];
  int nb = blockIdx.x / NT;
  int p0 = (blockIdx.x % NT) * 64;
  int tid = threadIdx.x;
  int l = tid & 63, w = tid >> 6;

  if constexpr (MODE == 0) {
    const float* src = (const float*)inv + (size_t)nb * CIN * LIN;
    for (int q = tid; q < (CIN / 2) * 72; q += 256) {
      int ci2 = q / 72, r = q % 72;
      int ci = 2 * ci2;
      int p = p0 - PAD + r;
      float v0 = 0.f, v1 = 0.f;
      if (p >= 0 && p < LIN) { v0 = src[ci * LIN + p]; v1 = src[(ci + 1) * LIN + p]; }
      int slot = ci >> 3;
      int phys = slot ^ (r & 7);
      *(unsigned int*)&xs[r * CIN + phys * 8 + (ci & 7)] = packh(v0, v1);
    }
  } else {
    const _Float16* src = (const _Float16*)inv + (size_t)nb * LIN * CIN;
    for (int q = tid; q < 72 * SLOTS; q += 256) {
      int r = q / SLOTS, s = q % SLOTS;
      int p = p0 - PAD + r;
      uint4 v = make_uint4(0u, 0u, 0u, 0u);
      if (p >= 0 && p < LIN) v = *(const uint4*)&src[(size_t)p * CIN + s * 8];
      int phys = s ^ (r & 7);
      *(uint4*)&xs[r * CIN + phys * 8] = v;
    }
  }
  __syncthreads();

  int n0 = 2 * w, n1 = n0 + 1;
  f32x4 acc[4][2];
  #pragma unroll
  for (int m = 0; m < 4; m++) {
    acc[m][0] = (f32x4){0.f, 0.f, 0.f, 0.f};
    acc[m][1] = (f32x4){0.f, 0.f, 0.f, 0.f};
  }
  uint4 bc0 = Bf[(size_t)(0 * 8 + n0) * 64 + l];
  uint4 bc1 = Bf[(size_t)(0 * 8 + n1) * 64 + l];
  for (int c = 0; c < NCH; c++) {
    uint4 bn0 = bc0, bn1 = bc1;
    if (c + 1 < NCH) {
      bn0 = Bf[(size_t)((c + 1) * 8 + n0) * 64 + l];
      bn1 = Bf[(size_t)((c + 1) * 8 + n1) * 64 + l];
    }
    int t = c / QN, q = c % QN;
    int slotbase = q * 4 + (l >> 4);
    f16x8 a[4];
    #pragma unroll
    for (int m = 0; m < 4; m++) {
      int r = m * 16 + (l & 15) + t * DIL;
      int phys = slotbase ^ (r & 7);
      a[m] = *(const f16x8*)&xs[r * CIN + phys * 8];
    }
    BU u0, u1; u0.u = bc0; u1.u = bc1;
    #pragma unroll
    for (int m = 0; m < 4; m++) {
      acc[m][0] = __builtin_amdgcn_mfma_f32_16x16x32_f16(a[m], u0.h, acc[m][0], 0, 0, 0);
      acc[m][1] = __builtin_amdgcn_mfma_f32_16x16x32_f16(a[m], u1.h, acc[m][1], 0, 0, 0);
    }
    bc0 = bn0; bc1 = bn1;
  }

  if constexpr (MODE == 2) {
    float* xcv = (float*)outv;
    #pragma unroll
    for (int n = 0; n < 2; n++) {
      int oc = (2 * w + n) * 16 + (l & 15);
      float bz = bias[oc];
      float s = 0.f;
      #pragma unroll
      for (int m = 0; m < 4; m++) {
        #pragma unroll
        for (int i = 0; i < 4; i++) {
          int pos = p0 + m * 16 + (l >> 4) * 4 + i;
          if (pos < LOUT) { float y = acc[m][n][i] + bz; s += y > 0.f ? y : 0.f; }
        }
      }
      s += __shfl_xor(s, 16, 64);
      s += __shfl_xor(s, 32, 64);
      if (l < 16) atomicAdd(&xcv[(size_t)(b0 + nb) * 128 + oc], s);
    }
  } else {
    _Float16* outp = (_Float16*)outv + (size_t)nb * LOUT * 128;
    #pragma unroll
    for (int n = 0; n < 2; n++) {
      int oc = (2 * w + n) * 16 + (l & 15);
      float bz = bias[oc];
      #pragma unroll
      for (int m = 0; m < 4; m++) {
        #pragma unroll
        for (int i = 0; i < 4; i++) {
          int pos = p0 + m * 16 + (l >> 4) * 4 + i;
          if (pos < LOUT) {
            float y = acc[m][n][i] + bz;
            outp[(size_t)pos * 128 + oc] = (_Float16)(y > 0.f ? y : 0.f);
          }
        }
      }
    }
  }
}

__global__ void k_fc0(const float* __restrict__ xconv, const float* __restrict__ xgru,
                      const float* __restrict__ r, const float* __restrict__ W,
                      const float* __restrict__ bias, float* __restrict__ hm) {
  __shared__ float feat[512];
  int b = blockIdx.x, t = threadIdx.x;
  if (t < 128) { feat[t] = xconv[b * 128 + t] * (1.f / (float)CL3); feat[128 + t] = xgru[b * 128 + t]; }
  feat[256 + t] = r[b * 256 + t];
  __syncthreads();
  float acc = bias[t];
  for (int k = 0; k < 512; k++) acc += feat[k] * W[k * 256 + t];
  hm[b * 256 + t] = acc;
}

__global__ void k_bn(const float* __restrict__ hm, const float* __restrict__ gamma,
                     const float* __restrict__ beta, float* __restrict__ out) {
  __shared__ float red[256];
  int n = blockIdx.x, t = threadIdx.x;
  float v = hm[t * 256 + n];
  red[t] = v; __syncthreads();
  for (int s = 128; s > 0; s >>= 1) { if (t < s) red[t] += red[t + s]; __syncthreads(); }
  float mean = red[0] / 256.f; __syncthreads();
  float dv = v - mean;
  red[t] = dv * dv; __syncthreads();
  for (int s = 128; s > 0; s >>= 1) { if (t < s) red[t] += red[t + s]; __syncthreads(); }
  float var = red[0] / 256.f;
  float y = gamma[n] * dv * (1.f / sqrtf(var + 1e-5f)) + beta[n];
  out[t * 256 + n] = y < 0.f ? 0.01f * y : y;
}

__global__ void k_fc1(const float* __restrict__ hmn, const float* __restrict__ W,
                      const float* __restrict__ bias, float* __restrict__ z) {
  __shared__ float hs[256];
  int b = blockIdx.x, t = threadIdx.x;
  hs[t] = hmn[b * 256 + t]; hs[128 + t] = hmn[b * 256 + 128 + t];
  __syncthreads();
  float acc = bias[t];
  for (int k = 0; k < 256; k++) acc += hs[k] * W[k * 128 + t];
  z[b * 128 + t] = acc;
}

// attention logits: grid (8 classes x 4 sample-tiles of 64)
__global__ __launch_bounds__(256) void k_att1(const float* __restrict__ z,
                                              const float* __restrict__ W1,
                                              const float* __restrict__ b1,
                                              const float* __restrict__ W2,
                                              float* __restrict__ logits) {
  __shared__ float sa[32][64];
  __shared__ float sb[32][64];
  int c = blockIdx.x >> 2;
  int m0 = (blockIdx.x & 3) * 64;
  const float* B = W1 + (size_t)c * 128 * AT;
  int tx = threadIdx.x & 15, ty = threadIdx.x >> 4;
  float acc[4][4];
  #pragma unroll
  for (int i = 0; i < 4; i++)
    #pragma unroll
    for (int j = 0; j < 4; j++) acc[i][j] = 0.f;
  int arow = threadIdx.x >> 2;
  int acol = (threadIdx.x & 3) * 8;
  int brow = threadIdx.x >> 4;
  int bcol = (threadIdx.x & 15) * 4;
  for (int k0 = 0; k0 < 128; k0 += 32) {
    float4 av0 = *(const float4*)&z[(size_t)(m0 + arow) * 128 + k0 + acol];
    float4 av1 = *(const float4*)&z[(size_t)(m0 + arow) * 128 + k0 + acol + 4];
    float4 bv0 = *(const float4*)&B[(size_t)(k0 + brow) * AT + bcol];
    float4 bv1 = *(const float4*)&B[(size_t)(k0 + brow + 16) * AT + bcol];
    __syncthreads();
    sa[acol + 0][arow] = av0.x; sa[acol + 1][arow] = av0.y;
    sa[acol + 2][arow] = av0.z; sa[acol + 3][arow] = av0.w;
    sa[acol + 4][arow] = av1.x; sa[acol + 5][arow] = av1.y;
    sa[acol + 6][arow] = av1.z; sa[acol + 7][arow] = av1.w;
    *(float4*)&sb[brow][bcol] = bv0;
    *(float4*)&sb[brow + 16][bcol] = bv1;
    __syncthreads();
    #pragma unroll
    for (int kk = 0; kk < 32; kk++) {
      float4 a4 = *(const float4*)&sa[kk][ty * 4];
      float4 b4 = *(const float4*)&sb[kk][tx * 4];
      acc[0][0] += a4.x * b4.x; acc[0][1] += a4.x * b4.y; acc[0][2] += a4.x * b4.z; acc[0][3] += a4.x * b4.w;
      acc[1][0] += a4.y * b4.x; acc[1][1] += a4.y * b4.y; acc[1][2] += a4.y * b4.z; acc[1][3] += a4.y * b4.w;
      acc[2][0] += a4.z * b4.x; acc[2][1] += a4.z * b4.y; acc[2][2] += a4.z * b4.z; acc[2][3] += a4.z * b4.w;
      acc[3][0] += a4.w * b4.x; acc[3][1] += a4.w * b4.y; acc[3][2] += a4.w * b4.z; acc[3][3] += a4.w * b4.w;
    }
  }
  const float* b1c = b1 + c * AT;
  const float* w2c = W2 + c * AT;
  float w2v[4], b1v[4];
  #pragma unroll
  for (int j = 0; j < 4; j++) { w2v[j] = w2c[tx * 4 + j]; b1v[j] = b1c[tx * 4 + j]; }
  #pragma unroll
  for (int i = 0; i < 4; i++) {
    float s = 0.f;
    #pragma unroll
    for (int j = 0; j < 4; j++) s += tanhf(acc[i][j] + b1v[j]) * w2v[j];
    #pragma unroll
    for (int o = 8; o > 0; o >>= 1) s += __shfl_xor(s, o, 64);
    if (tx == 0) logits[c * 256 + m0 + ty * 4 + i] = s;
  }
}

// masked softmax over samples + prototype
__global__ void k_att2(const float* __restrict__ z, const int* __restrict__ labels,
                       const int* __restrict__ idx_train, int ntrain,
                       const float* __restrict__ logits, const float* __restrict__ b2,
                       float* __restrict__ protos) {
  __shared__ float wv[256], red[256];
  __shared__ int trainm[256];
  int c = blockIdx.x, n = threadIdx.x;
  trainm[n] = 0; __syncthreads();
  if (n < ntrain) trainm[idx_train[n]] = 1;
  __syncthreads();
  bool keep = trainm[n] && (labels[n] == c);
  float ml = keep ? (logits[c * 256 + n] + b2[c]) : -1e30f;
  red[n] = ml; __syncthreads();
  for (int s = 128; s > 0; s >>= 1) { if (n < s) red[n] = fmaxf(red[n], red[n + s]); __syncthreads(); }
  float mx = red[0]; __syncthreads();
  float e = expf(ml - mx);
  wv[n] = e; red[n] = e; __syncthreads();
  for (int s = 128; s > 0; s >>= 1) { if (n < s) red[n] += red[n + s]; __syncthreads(); }
  float ssum = red[0]; __syncthreads();
  wv[n] = wv[n] / ssum;
  __syncthreads();
  if (n < 128) {
    float p = 0.f;
    for (int q = 0; q < 256; q++) p += wv[q] * z[q * 128 + n];
    protos[c * 128 + n] = p;
  }
}

// distances; block BB does the prototype-pair term
__global__ void k_dist(const float* __restrict__ z, const float* __restrict__ protos,
                       float* __restrict__ dout) {
  if (blockIdx.x == BB) {
    int t = threadIdx.x;
    if (t < 64) {
      int i = t >> 3, jx = t & 7;
      float dot = 0.f, p2i = 0.f, p2j = 0.f;
      for (int d = 0; d < 128; d++) {
        float a = protos[i * 128 + d], bb2 = protos[jx * 128 + d];
        dot += a * bb2; p2i += a * a; p2j += bb2 * bb2;
      }
      float d2 = fmaxf(p2i + p2j - 2.f * dot, 1e-12f);
      float e = expf(-0.5f * sqrtf(d2));
      e = warp_red_sum(e);
      if (t == 0) dout[2048] = e / 28.f;
    }
    return;
  }
  __shared__ float zs[128], red[128];
  int n = blockIdx.x, t = threadIdx.x;
  zs[t] = z[n * 128 + t];
  red[t] = zs[t] * zs[t]; __syncthreads();
  for (int s = 64; s > 0; s >>= 1) { if (t < s) red[t] += red[t + s]; __syncthreads(); }
  float z2 = red[0];
  if (t < NC) {
    float dot = 0.f, p2 = 0.f;
    const float* pr = protos + t * 128;
    for (int d = 0; d < 128; d++) { float pv = pr[d]; dot += pv * zs[d]; p2 += pv * pv; }
    float d2 = fmaxf(z2 + p2 - 2.f * dot, 1e-12f);
    dout[n * NC + t] = expf(-0.5f * sqrtf(d2));
  }
}

extern "C" void kernel_launch(void* const* d_in, const int* in_sizes, int n_in,
                              void* d_out, int out_size, void* d_ws, size_t ws_size,
                              hipStream_t stream) {
  const float* x = (const float*)d_in[0];
  const int* labels = (const int*)d_in[1];
  const int* idx_train = (const int*)d_in[2];
  const float* gat_W = (const float*)d_in[3];
  const float* gat_a1 = (const float*)d_in[4];
  const float* gat_a2 = (const float*)d_in[5];
  const float* gcnW[3] = {(const float*)d_in[6], (const float*)d_in[8], (const float*)d_in[10]};
  const float* gcnB[3] = {(const float*)d_in[7], (const float*)d_in[9], (const float*)d_in[11]};
  const float* pw1[3] = {(const float*)d_in[12], (const float*)d_in[15], (const float*)d_in[18]};
  const float* pw2[3] = {(const float*)d_in[13], (const float*)d_in[16], (const float*)d_in[19]};
  const float* pbb[3] = {(const float*)d_in[14], (const float*)d_in[17], (const float*)d_in[20]};
  const float* wih = (const float*)d_in[21];
  const float* whh = (const float*)d_in[22];
  const float* bih = (const float*)d_in[23];
  const float* bhh = (const float*)d_in[24];
  const float* c1W = (const float*)d_in[25]; const float* c1b = (const float*)d_in[26];
  const float* c2W = (const float*)d_in[27]; const float* c2b = (const float*)d_in[28];
  const float* c3W = (const float*)d_in[29]; const float* c3b = (const float*)d_in[30];
  const float* fc0W = (const float*)d_in[31]; const float* fc0b = (const float*)d_in[32];
  const float* bn0g = (const float*)d_in[33]; const float* bn0b = (const float*)d_in[34];
  const float* fc1W = (const float*)d_in[35]; const float* fc1b = (const float*)d_in[36];
  const float* aW1 = (const float*)d_in[37]; const float* ab1 = (const float*)d_in[38];
  const float* aW2 = (const float*)d_in[39]; const float* ab2 = (const float*)d_in[40];
  float* out = (float*)d_out;
  float* ws = (float*)d_ws;

  // ---- workspace layout (floats). Z region reused by 3 sequential phases. ----
  size_t off = 0;
  auto take = [&](size_t n) { size_t o = off; off += (n + 63) & ~(size_t)63; return o; };
  float* wa1   = ws + take(512);
  float* wa2   = ws + take(512);
  float* ha1   = ws + take(BB * CC);
  float* ha2   = ws + take(BB * CC);
  float* dinv  = ws + take(BB * 64);
  float* rbuf  = ws + take(BB * 256);
  float* xgru  = ws + take(BB * 128);
  float* xconv = ws + take(BB * 128);
  float* hm    = ws + take(BB * 256);
  float* hmn   = ws + take(BB * 256);
  float* zb    = ws + take(BB * 128);
  float* protos = ws + take(NC * 128);
  float* lgts  = ws + take(NC * 256);
  float* gw1h  = ws + take(256 * 128);       // frag-packed gcnW[0]
  float* gw2h  = ws + take(64 * 128);        // frag-packed gcnW[1]
  float* gw3h  = ws + take(64 * 128);        // frag-packed gcnW[2]
  float* wpkf  = ws + take(192 * 128);       // packed h2 whh for k_gru
  float* wslot = ws + take(512 * 384);       // wihT frags (GRU) then conv MFMA frags
  float* Z     = ws + take(8568832);
  // GNN-phase aliases
  float* mA  = Z;
  float* mB  = Z + 1048576;
  float* xw  = Z + 2097152;
  float* gb  = Z + 4194304;
  float* gp1 = Z + 6291456;
  float* gp2 = Z + 7340032;
  // GRU-phase aliases
  float* gi = Z;
  float* ys = Z + 6291456;
  // conv-phase aliases (2 chunks of 128 samples; f16 [pos][128oc] activations)
  float* cv1 = Z;                     // 128*519*128 f16 = 4251648 floats
  float* cv2 = Z + 4251648;           // 128*527*128 f16 = 4317184 floats
  unsigned int* wpk = (unsigned int*)wpkf;
  unsigned int* wihTh = (unsigned int*)wslot;            // 98304 u32 frag-packed wih^T
  unsigned int* wt1h = (unsigned int*)wslot;             // conv frags (after gi GEMM)
  unsigned int* wt2h = wt1h + 32768;
  unsigned int* wt3h = wt2h + 40960;

  hipMemsetAsync(rbuf, 0, BB * 256 * sizeof(float), stream);
  hipMemsetAsync(xconv, 0, BB * 128 * sizeof(float), stream);

  // ---- GAT adjacency (fused dinv for stage 0) + all weight packing ----
  k_wa<<<8, 64, 0, stream>>>(gat_W, gat_a1, gat_a2, wa1, wa2);
  k_packall<<<672, 256, 0, stream>>>(gcnW[0], gcnW[1], gcnW[2], wih, whh,
                                     (unsigned int*)gw1h, (unsigned int*)gw2h,
                                     (unsigned int*)gw3h, wihTh, wpk);
  k_ha<<<BB * CC / 4, 256, 0, stream>>>(x, wa1, wa2, ha1, ha2);
  k_softmask<<<BB * 64 / 4, 256, 0, stream>>>(ha1, ha2, mA, dinv);

  // ---- 3x (GCN + SAGPool); xw via MFMA GEMM at every stage ----
  const int Ns[3] = {64, 32, 16};
  const int ks[3] = {32, 16, 8};
  const int Kin[3] = {512, 128, 128};
  const float* gins[3] = {x, gp1, gp2};
  const unsigned int* gwh[3] = {(unsigned int*)gw1h, (unsigned int*)gw2h, (unsigned int*)gw3h};
  float* mcur[3] = {mA, mB, mA};
  float* mnxt[3] = {mB, mA, mB};
  float* gps[3]  = {gp1, gp2, nullptr};
  for (int s = 0; s < 3; s++) {
    int N = Ns[s];
    k_gmfma<<<(BB * N / 64), 256, 0, stream>>>(
        gins[s], (const uint4*)gwh[s], xw, BB * N, HH, Kin[s]);
    k_gcnagg<<<BB * N, 128, 0, stream>>>(xw, mcur[s], dinv, gcnB[s], gb, N);
    k_pool<<<BB, 256, 0, stream>>>(gb, mcur[s], pw1[s], pw2[s], pbb[s], N, ks[s],
                                   gps[s], mnxt[s], s < 2 ? dinv : nullptr, rbuf);
  }

  // ---- GRU branch: gi via MFMA GEMM (N=384 -> 3 n-blocks), then recurrence ----
  k_gmfma<<<(BB * CC / 64) * 3, 256, 0, stream>>>(
      x, (const uint4*)wihTh, gi, BB * CC, G3, LL);
  k_gru<<<CC, 256, 0, stream>>>(gi, wpk, bhh, bih, ys);
  k_grumean<<<BB, 128, 0, stream>>>(ys, xgru);

  // ---- dilated conv branch: MFMA implicit GEMM, 2 chunks of 128 samples ----
  k_packw_mfma<<<384, 256, 0, stream>>>(c1W, c2W, c3W, wt1h, wt2h, wt3h);
  for (int bc = 0; bc < 2; bc++) {
    int b0 = bc * 128;
    k_cmfma<64, 8, 1, 7, 512, CL1, 0><<<128 * 9, 256, 0, stream>>>(
        x + (size_t)b0 * CC * LL, (const uint4*)wt1h, c1b, cv1, b0);
    k_cmfma<128, 5, 2, 8, CL1, CL2, 1><<<128 * 9, 256, 0, stream>>>(
        cv1, (const uint4*)wt2h, c2b, cv2, b0);
    k_cmfma<128, 3, 4, 8, CL2, CL3, 2><<<128 * 9, 256, 0, stream>>>(
        cv2, (const uint4*)wt3h, c3b, xconv, b0);
  }

  // ---- mapping MLP + BN + attention prototypes + distances ----
  k_fc0<<<BB, 256, 0, stream>>>(xconv, xgru, rbuf, fc0W, fc0b, hm);
  k_bn<<<256, 256, 0, stream>>>(hm, bn0g, bn0b, hmn);
  k_fc1<<<BB, 128, 0, stream>>>(hmn, fc1W, fc1b, zb);
  k_att1<<<NC * 4, 256, 0, stream>>>(zb, aW1, ab1, aW2, lgts);
  k_att2<<<NC, 256, 0, stream>>>(zb, labels, idx_train, in_sizes[2], lgts, ab2, protos);
  k_dist<<<BB + 1, 128, 0, stream>>>(zb, protos, out);
}